// Round 1
// baseline (5633.958 us; speedup 1.0000x reference)
//
#include <hip/hip_runtime.h>
#include <cstddef>
#include <math.h>

// ---------------------------------------------------------------------------
// Bimodal deformable-attention encoder, f32 baseline (round 0: correctness).
//
// Pipeline:
//   src = concat(GN(conv1x1(v)), GN(conv1x1(i)))           [B,800,512]
//   posf = sine_pos + level_embed                           [800,512]
//   6x: value=src@vp; off/aw=(src+posf)@{ow,aww}; sample; y=src+samp@op;
//       src=LN_spec(y); h=relu(src@f1); y=src+h@f2; src=LN_spec(y)
//   out = GN(conv1x1(src[:, :400] + src[:, 400:]))          [B,768,20,20]
//
// Workspace map (floats):
//   src   [16,800,512]  6,553,600
//   tmp1  [16,800,512]  6,553,600   (value, then pre-LN residual y)
//   tmp2  [..,max 1024] 6,553,600   (sampled; ffn hidden chunk; final conv out)
//   offaw [16,800,192]  2,457,600
//   posf  [800,512]       409,600
//   tok   [16,400,512]  3,276,800   (initial conv tmp; final token sum)
//   stats [512*2]           1,024
// Total ~103 MB.
// ---------------------------------------------------------------------------

constexpr int kB   = 16;
constexpr int kCin = 768;
constexpr int kHW  = 400;
constexpr int kWpx = 20;
constexpr int kHpx = 20;
constexpr int kD   = 512;
constexpr int kLen = 800;
constexpr int kHd  = 8;
constexpr int kDff = 1024;
constexpr int kNL  = 6;
constexpr float kEps = 1e-5f;

// ------------------------------ block reduce -------------------------------
__device__ __forceinline__ void breduce2(float& s, float& s2, float* sh) {
#pragma unroll
  for (int o = 32; o > 0; o >>= 1) {
    s  += __shfl_down(s, o);
    s2 += __shfl_down(s2, o);
  }
  const int wid = threadIdx.x >> 6, lane = threadIdx.x & 63;
  if (lane == 0) { sh[wid] = s; sh[4 + wid] = s2; }
  __syncthreads();
  if (threadIdx.x == 0) {
    sh[0] = sh[0] + sh[1] + sh[2] + sh[3];
    sh[4] = sh[4] + sh[5] + sh[6] + sh[7];
  }
  __syncthreads();
  s = sh[0]; s2 = sh[4];
}

// --------------------------------- GEMM ------------------------------------
// C[M,N] = A*B + bias (+epilogue). 64x64 tile, BK=16, 256 thr, 4x4 microtile.
// AMODE 0: A row-major [M,K] (optionally + posf[m%800])
// AMODE 1: A = conv input [B,Cin,HW]: A[m][k] = A[(m/HW)*Cin*HW + k*HW + m%HW]
// BMODE 0: B row-major [K,N];  BMODE 1: B transposed [N,K]
// EPI 0: bias   1: bias+relu   2: bias + res[m*ldc+n]   3: bias, write
//        C[((m/HW)*N + n)*HW + m%HW] (channel-major conv output)
template<int AMODE, bool ADDPOS, int BMODE, int EPI>
__global__ __launch_bounds__(256)
void gemm_k(const float* __restrict__ A, const float* __restrict__ Bm,
            const float* __restrict__ bias, const float* __restrict__ posf,
            const float* __restrict__ res, float* __restrict__ C,
            int M, int N, int K, int ldc)
{
  __shared__ float As[16][68];
  __shared__ float Bs[16][68];
  const int m0 = blockIdx.y * 64;
  const int n0 = blockIdx.x * 64;
  const int tid = threadIdx.x;
  const int tx = tid & 15, ty = tid >> 4;
  float acc[4][4] = {};

  for (int k0 = 0; k0 < K; k0 += 16) {
    if (AMODE == 0) {
      const int row = tid >> 2;
      const int kq  = (tid & 3) << 2;
      float4 av = *(const float4*)(A + (size_t)(m0 + row) * K + k0 + kq);
      if (ADDPOS) {
        const int t8 = (m0 + row) % kLen;
        const float4 pv = *(const float4*)(posf + (size_t)t8 * kD + k0 + kq);
        av.x += pv.x; av.y += pv.y; av.z += pv.z; av.w += pv.w;
      }
      As[kq + 0][row] = av.x; As[kq + 1][row] = av.y;
      As[kq + 2][row] = av.z; As[kq + 3][row] = av.w;
    } else {
      const int mm  = tid & 63;
      const int kk0 = (tid >> 6) << 2;
      const int m = m0 + mm;
      const int b = m / kHW, p = m % kHW;
      const float* ap = A + (size_t)b * kCin * kHW + (size_t)(k0 + kk0) * kHW + p;
#pragma unroll
      for (int i = 0; i < 4; i++) As[kk0 + i][mm] = ap[(size_t)i * kHW];
    }
    if (BMODE == 0) {
      const int kk = tid >> 4, nq = (tid & 15) << 2;
      const float4 bv = *(const float4*)(Bm + (size_t)(k0 + kk) * N + n0 + nq);
      Bs[kk][nq + 0] = bv.x; Bs[kk][nq + 1] = bv.y;
      Bs[kk][nq + 2] = bv.z; Bs[kk][nq + 3] = bv.w;
    } else {
      const int nn = tid >> 2, kq = (tid & 3) << 2;
      const float4 bv = *(const float4*)(Bm + (size_t)(n0 + nn) * K + k0 + kq);
      Bs[kq + 0][nn] = bv.x; Bs[kq + 1][nn] = bv.y;
      Bs[kq + 2][nn] = bv.z; Bs[kq + 3][nn] = bv.w;
    }
    __syncthreads();
#pragma unroll
    for (int kk = 0; kk < 16; kk++) {
      const float4 a4 = *(const float4*)&As[kk][ty << 2];
      const float4 b4 = *(const float4*)&Bs[kk][tx << 2];
      const float a[4] = {a4.x, a4.y, a4.z, a4.w};
      const float b[4] = {b4.x, b4.y, b4.z, b4.w};
#pragma unroll
      for (int i = 0; i < 4; i++)
#pragma unroll
        for (int j = 0; j < 4; j++) acc[i][j] += a[i] * b[j];
    }
    __syncthreads();
  }

  const int mb = m0 + (ty << 2), nb = n0 + (tx << 2);
#pragma unroll
  for (int i = 0; i < 4; i++) {
    const int m = mb + i;
    if (EPI == 3) {
      const int b = m / kHW, p = m % kHW;
#pragma unroll
      for (int j = 0; j < 4; j++) {
        const int n = nb + j;
        C[((size_t)b * N + n) * kHW + p] = acc[i][j] + bias[n];
      }
    } else {
      float v[4];
#pragma unroll
      for (int j = 0; j < 4; j++) {
        float t = acc[i][j] + bias[nb + j];
        if (EPI == 1) t = fmaxf(t, 0.0f);
        if (EPI == 2) t += res[(size_t)m * ldc + nb + j];
        v[j] = t;
      }
      float4 o; o.x = v[0]; o.y = v[1]; o.z = v[2]; o.w = v[3];
      *(float4*)(C + (size_t)m * ldc + nb) = o;
    }
  }
}

// ----------------------- positional encoding + level ------------------------
__global__ void posf_k(float* __restrict__ posf, const float* __restrict__ level_embed)
{
  const int idx = blockIdx.x * 256 + threadIdx.x;   // < 800*512
  const int d = idx & (kD - 1);
  const int t = idx >> 9;
  const int lvl = t / kHW;
  const int tt = t % kHW;
  const int yy = tt / kWpx, xx = tt % kWpx;
  const int dd = (d < 256) ? d : d - 256;
  const float e = (d < 256) ? ((float)(yy + 1) / kHpx * 6.283185307179586f)
                            : ((float)(xx + 1) / kWpx * 6.283185307179586f);
  const float expo = (float)(dd >> 1) / 128.0f;     // 2*(dd/2)/256
  const float dimt = powf(10000.0f, expo);
  const float pp = e / dimt;
  const float val = (dd & 1) ? cosf(pp) : sinf(pp);
  posf[idx] = val + level_embed[lvl * kD + d];
}

// --------------------------- GroupNorm (token-major) ------------------------
// x: [16,400,512]; group g covers channels [16g,16g+16); stats over 400*16.
__global__ __launch_bounds__(256)
void gn_stats_tok_k(const float* __restrict__ x, float* __restrict__ stats)
{
  __shared__ float sh[8];
  const int b = blockIdx.x >> 5;
  const int g = blockIdx.x & 31;
  const float* xb = x + (size_t)b * kHW * kD + g * 16;
  float s = 0.f, s2 = 0.f;
  for (int i = threadIdx.x; i < kHW * 16; i += 256) {
    const int p = i >> 4, j = i & 15;
    const float v = xb[(size_t)p * kD + j];
    s += v; s2 += v * v;
  }
  breduce2(s, s2, sh);
  if (threadIdx.x == 0) {
    const float mean = s / (kHW * 16.0f);
    const float var  = s2 / (kHW * 16.0f) - mean * mean;
    stats[blockIdx.x * 2]     = mean;
    stats[blockIdx.x * 2 + 1] = rsqrtf(var + kEps);
  }
}

__global__ void gn_norm_tok_k(const float* __restrict__ x, float* __restrict__ src,
                              const float* __restrict__ stats,
                              const float* __restrict__ gam, const float* __restrict__ bet,
                              int tokoff)
{
  const int idx = blockIdx.x * 256 + threadIdx.x;   // < 16*400*512
  const int d = idx & (kD - 1);
  const int rest = idx >> 9;
  const int b = rest / kHW, p = rest % kHW;
  const int g = d >> 4;
  const float mean = stats[(b * 32 + g) * 2];
  const float rstd = stats[(b * 32 + g) * 2 + 1];
  src[((size_t)(b * kLen + tokoff + p)) * kD + d] =
      (x[idx] - mean) * rstd * gam[d] + bet[d];
}

// --------------------------- GroupNorm (chan-major) -------------------------
// x: [16,768,400]; group g covers 24 channels -> 9600 contiguous floats.
__global__ __launch_bounds__(256)
void gn_stats_ch_k(const float* __restrict__ x, float* __restrict__ stats)
{
  __shared__ float sh[8];
  const int b = blockIdx.x >> 5;
  const int g = blockIdx.x & 31;
  const float* xb = x + (size_t)b * kCin * kHW + (size_t)g * 24 * kHW;
  float s = 0.f, s2 = 0.f;
  for (int i = threadIdx.x; i < 24 * kHW; i += 256) {
    const float v = xb[i];
    s += v; s2 += v * v;
  }
  breduce2(s, s2, sh);
  if (threadIdx.x == 0) {
    const float mean = s / (24.0f * kHW);
    const float var  = s2 / (24.0f * kHW) - mean * mean;
    stats[blockIdx.x * 2]     = mean;
    stats[blockIdx.x * 2 + 1] = rsqrtf(var + kEps);
  }
}

__global__ void gn_norm_ch_k(const float* __restrict__ x, float* __restrict__ out,
                             const float* __restrict__ stats,
                             const float* __restrict__ gam, const float* __restrict__ bet)
{
  const int idx = blockIdx.x * 256 + threadIdx.x;   // < 16*768*400
  const int p = idx % kHW;
  const int rest = idx / kHW;
  const int c = rest % kCin;
  const int b = rest / kCin;
  const int g = c / 24;
  (void)p;
  const float mean = stats[(b * 32 + g) * 2];
  const float rstd = stats[(b * 32 + g) * 2 + 1];
  out[idx] = (x[idx] - mean) * rstd * gam[c] + bet[c];
}

// ----------------------- modality-specific LayerNorm ------------------------
// one block per row (b*800+t); params [2,512] selected by t<400.
__global__ __launch_bounds__(256)
void ln_spec_k(const float* __restrict__ x, float* __restrict__ out,
               const float* __restrict__ gamma, const float* __restrict__ beta)
{
  __shared__ float sh[8];
  const int row = blockIdx.x;
  const int t = row % kLen;
  const int mod = (t < kHW) ? 0 : 1;
  const float* g  = gamma + mod * kD;
  const float* be = beta  + mod * kD;
  const float* xr = x + (size_t)row * kD;
  const float v0 = xr[threadIdx.x];
  const float v1 = xr[threadIdx.x + 256];
  float s = v0 + v1, s2 = v0 * v0 + v1 * v1;
  breduce2(s, s2, sh);
  const float mean = s * (1.0f / kD);
  const float var  = s2 * (1.0f / kD) - mean * mean;
  const float rstd = rsqrtf(var + kEps);
  out[(size_t)row * kD + threadIdx.x] =
      (v0 - mean) * rstd * g[threadIdx.x] + be[threadIdx.x];
  out[(size_t)row * kD + threadIdx.x + 256] =
      (v1 - mean) * rstd * g[threadIdx.x + 256] + be[threadIdx.x + 256];
}

// ------------------- deformable sampling (softmax + bilinear) ---------------
// one wave per (b, t, head); lane = Dh index. value: [16,800,512] (lvl0=0:400).
// offaw row: [off(8h x 2l x 4p x 2) | aw logits(8h x 8)]
__global__ __launch_bounds__(256)
void sample_k(const float* __restrict__ value, const float* __restrict__ offaw,
              float* __restrict__ out)
{
  const int wid  = threadIdx.x >> 6;
  const int lane = threadIdx.x & 63;
  const int wg = blockIdx.x * 4 + wid;          // < 16*800*8
  const int b = wg / (kLen * kHd);
  const int rem = wg % (kLen * kHd);
  const int t = rem >> 3;
  const int hh = rem & 7;

  const int tt = t % kHW;
  const float refx = ((float)(tt % kWpx) + 0.5f) / kWpx;
  const float refy = ((float)(tt / kWpx) + 0.5f) / kHpx;

  const float* oa = offaw + (size_t)(b * kLen + t) * 192;

  float lg[8], mx = -1e30f;
#pragma unroll
  for (int i = 0; i < 8; i++) {
    lg[i] = oa[128 + hh * 8 + i];
    mx = fmaxf(mx, lg[i]);
  }
  float ssum = 0.f;
#pragma unroll
  for (int i = 0; i < 8; i++) { lg[i] = expf(lg[i] - mx); ssum += lg[i]; }
  const float inv = 1.0f / ssum;

  float acc = 0.f;
#pragma unroll
  for (int l = 0; l < 2; l++) {
    const float* vbase = value + (size_t)(b * kLen + l * kHW) * kD + hh * 64 + lane;
#pragma unroll
    for (int p = 0; p < 4; p++) {
      const float ox = oa[hh * 16 + l * 8 + p * 2];
      const float oy = oa[hh * 16 + l * 8 + p * 2 + 1];
      const float x = (refx + ox * (1.0f / kWpx)) * kWpx - 0.5f;
      const float y = (refy + oy * (1.0f / kHpx)) * kHpx - 0.5f;
      const float x0f = floorf(x), y0f = floorf(y);
      const float wx = x - x0f, wy = y - y0f;
      const int x0 = (int)x0f, y0 = (int)y0f;
      const float aw = lg[l * 4 + p] * inv;
#pragma unroll
      for (int dy = 0; dy < 2; dy++)
#pragma unroll
        for (int dx = 0; dx < 2; dx++) {
          const int ix = x0 + dx, iy = y0 + dy;
          if (ix >= 0 && ix < kWpx && iy >= 0 && iy < kHpx) {
            const float cw = (dx ? wx : 1.0f - wx) * (dy ? wy : 1.0f - wy);
            acc += aw * cw * vbase[(size_t)(iy * kWpx + ix) * kD];
          }
        }
    }
  }
  out[(size_t)(b * kLen + t) * kD + hh * 64 + lane] = acc;
}

// --------------------------- token-sum (final) ------------------------------
__global__ void sumtok_k(const float* __restrict__ src, float* __restrict__ tok)
{
  const int idx = blockIdx.x * 256 + threadIdx.x;   // < 16*400*512
  const int b = idx / (kHW * kD);
  const int r = idx % (kHW * kD);
  tok[idx] = src[(size_t)b * kLen * kD + r] +
             src[(size_t)b * kLen * kD + (size_t)kHW * kD + r];
}

// ------------------------------- launcher -----------------------------------
extern "C" void kernel_launch(void* const* d_in, const int* in_sizes, int n_in,
                              void* d_out, int out_size, void* d_ws, size_t ws_size,
                              hipStream_t stream)
{
  const float* input_v     = (const float*)d_in[0];
  const float* input_i     = (const float*)d_in[1];
  const float* av_w        = (const float*)d_in[2];
  const float* av_b        = (const float*)d_in[3];
  const float* av_g        = (const float*)d_in[4];
  const float* av_be       = (const float*)d_in[5];
  const float* ai_w        = (const float*)d_in[6];
  const float* ai_b        = (const float*)d_in[7];
  const float* ai_g        = (const float*)d_in[8];
  const float* ai_be       = (const float*)d_in[9];
  const float* level_embed = (const float*)d_in[10];
  const float* off_w       = (const float*)d_in[11];
  const float* off_b       = (const float*)d_in[12];
  const float* aw_w        = (const float*)d_in[13];
  const float* aw_b        = (const float*)d_in[14];
  const float* vp_w        = (const float*)d_in[15];
  const float* vp_b        = (const float*)d_in[16];
  const float* op_w        = (const float*)d_in[17];
  const float* op_b        = (const float*)d_in[18];
  const float* ln1_g       = (const float*)d_in[19];
  const float* ln1_b       = (const float*)d_in[20];
  const float* ffn1_w      = (const float*)d_in[21];
  const float* ffn1_b      = (const float*)d_in[22];
  const float* ffn2_w      = (const float*)d_in[23];
  const float* ffn2_b      = (const float*)d_in[24];
  const float* ln2_g       = (const float*)d_in[25];
  const float* ln2_b       = (const float*)d_in[26];
  const float* as_w        = (const float*)d_in[27];
  const float* as_b        = (const float*)d_in[28];
  const float* as_g        = (const float*)d_in[29];
  const float* as_be       = (const float*)d_in[30];

  float* ws    = (float*)d_ws;
  float* src   = ws;
  float* tmp1  = src   + (size_t)kB * kLen * kD;       // 6,553,600
  float* tmp2  = tmp1  + (size_t)kB * kLen * kD;       // 6,553,600
  float* offaw = tmp2  + (size_t)kB * kLen * kD;       // 6,553,600 (uses 1024-wide rows in ffn)
  float* posf  = offaw + (size_t)kB * kLen * 192;      // 2,457,600
  float* tok   = posf  + (size_t)kLen * kD;            //   409,600
  float* stats = tok   + (size_t)kB * kHW * kD;        // 3,276,800

  const int M  = kB * kLen;   // 12800
  const int Mh = kB * kHW;    // 6400

  // positional features
  posf_k<<<dim3(kLen * kD / 256), dim3(256), 0, stream>>>(posf, level_embed);

  // input convs + GN -> src
  for (int mod = 0; mod < 2; mod++) {
    const float* in  = mod ? input_i : input_v;
    const float* cw  = mod ? ai_w  : av_w;
    const float* cb  = mod ? ai_b  : av_b;
    const float* cg  = mod ? ai_g  : av_g;
    const float* cbe = mod ? ai_be : av_be;
    gemm_k<1, false, 1, 0><<<dim3(kD / 64, Mh / 64), 256, 0, stream>>>(
        in, cw, cb, nullptr, nullptr, tok, Mh, kD, kCin, kD);
    gn_stats_tok_k<<<dim3(kB * 32), 256, 0, stream>>>(tok, stats);
    gn_norm_tok_k<<<dim3(kB * kHW * kD / 256), 256, 0, stream>>>(
        tok, src, stats, cg, cbe, mod * kHW);
  }

  for (int l = 0; l < kNL; l++) {
    const float* owl  = off_w  + (size_t)l * kD * 128;
    const float* obl  = off_b  + (size_t)l * 128;
    const float* awl  = aw_w   + (size_t)l * kD * 64;
    const float* awbl = aw_b   + (size_t)l * 64;
    const float* vwl  = vp_w   + (size_t)l * kD * kD;
    const float* vbl  = vp_b   + (size_t)l * kD;
    const float* opwl = op_w   + (size_t)l * kD * kD;
    const float* opbl = op_b   + (size_t)l * kD;
    const float* l1g  = ln1_g  + (size_t)l * 2 * kD;
    const float* l1b  = ln1_b  + (size_t)l * 2 * kD;
    const float* f1w  = ffn1_w + (size_t)l * kD * kDff;
    const float* f1b  = ffn1_b + (size_t)l * kDff;
    const float* f2w  = ffn2_w + (size_t)l * kDff * kD;
    const float* f2b  = ffn2_b + (size_t)l * kD;
    const float* l2g  = ln2_g  + (size_t)l * 2 * kD;
    const float* l2b  = ln2_b  + (size_t)l * 2 * kD;

    // value = src @ vp + vb                       -> tmp1
    gemm_k<0, false, 0, 0><<<dim3(kD / 64, M / 64), 256, 0, stream>>>(
        src, vwl, vbl, nullptr, nullptr, tmp1, M, kD, kD, kD);
    // off = (src+posf) @ ow + ob                  -> offaw[:,0:128]
    gemm_k<0, true, 0, 0><<<dim3(128 / 64, M / 64), 256, 0, stream>>>(
        src, owl, obl, posf, nullptr, offaw, M, 128, kD, 192);
    // aw logits = (src+posf) @ aww + awb          -> offaw[:,128:192]
    gemm_k<0, true, 0, 0><<<dim3(64 / 64, M / 64), 256, 0, stream>>>(
        src, awl, awbl, posf, nullptr, offaw + 128, M, 64, kD, 192);
    // deformable bilinear sampling                 -> tmp2
    sample_k<<<dim3(kB * kLen * kHd / 4), 256, 0, stream>>>(tmp1, offaw, tmp2);
    // y = src + sampled @ op + opb                -> tmp1 (value now dead)
    gemm_k<0, false, 0, 2><<<dim3(kD / 64, M / 64), 256, 0, stream>>>(
        tmp2, opwl, opbl, nullptr, src, tmp1, M, kD, kD, kD);
    // src = LN_spec(y)
    ln_spec_k<<<dim3(M), 256, 0, stream>>>(tmp1, src, l1g, l1b);

    // FFN in two M-chunks (hidden chunk fits tmp2)
    for (int hf = 0; hf < 2; hf++) {
      const float* srch = src  + (size_t)hf * Mh * kD;
      float*       yh   = tmp1 + (size_t)hf * Mh * kD;
      gemm_k<0, false, 0, 1><<<dim3(kDff / 64, Mh / 64), 256, 0, stream>>>(
          srch, f1w, f1b, nullptr, nullptr, tmp2, Mh, kDff, kD, kDff);
      gemm_k<0, false, 0, 2><<<dim3(kD / 64, Mh / 64), 256, 0, stream>>>(
          tmp2, f2w, f2b, nullptr, srch, yh, Mh, kD, kDff, kD);
    }
    ln_spec_k<<<dim3(M), 256, 0, stream>>>(tmp1, src, l2g, l2b);
  }

  // out = GN(conv1x1(src_v + src_i))
  sumtok_k<<<dim3(kB * kHW * kD / 256), 256, 0, stream>>>(src, tok);
  gemm_k<0, false, 1, 3><<<dim3(kCin / 64, Mh / 64), 256, 0, stream>>>(
      tok, as_w, as_b, nullptr, nullptr, tmp2, Mh, kCin, kD, 0);
  gn_stats_ch_k<<<dim3(kB * 32), 256, 0, stream>>>(tmp2, stats);
  gn_norm_ch_k<<<dim3(kB * kCin * kHW / 256), 256, 0, stream>>>(
      tmp2, (float*)d_out, stats, as_g, as_be);
}

// Round 2
// 2131.787 us; speedup vs baseline: 2.6428x; 2.6428x over previous
//
#include <hip/hip_runtime.h>
#include <hip/hip_bf16.h>
#include <cstddef>
#include <math.h>

// ---------------------------------------------------------------------------
// Round 1: all projection GEMMs -> bf16 MFMA (16x16x32), m97-style structure:
// 128x128 tile, BK=32, 4 waves, A+B staged with global_load_lds(16B) from
// PRE-SWIZZLED bf16 buffers (slot-rotation swizzle, conflict-light ds_read).
// Producers (GN/LN/sample/ffn1-epilogue/transpose/weight-convert) write the
// swizzled bf16 mirrors. Residual/LN/GN math stays f32.
// ---------------------------------------------------------------------------

constexpr int kB   = 16;
constexpr int kCin = 768;
constexpr int kHW  = 400;
constexpr int kWpx = 20;
constexpr int kHpx = 20;
constexpr int kD   = 512;
constexpr int kLen = 800;
constexpr int kHd  = 8;
constexpr int kDff = 1024;
constexpr int kNL  = 6;
constexpr float kEps = 1e-5f;

typedef __attribute__((ext_vector_type(8))) short s8v;
typedef __attribute__((ext_vector_type(4))) float f4v;

// k-group swizzle: within each 32-element k-group, rotate 8-element slots by
// (row>>1)&3.  LDS rows (64B) then read conflict-light for MFMA fragments.
__device__ __forceinline__ int swzk(int row, int k) {
  return (k & ~31) | ((((k >> 3) + (row >> 1)) & 3) << 3) | (k & 7);
}

__device__ __forceinline__ unsigned short f2b(float f) {
  union { __hip_bfloat16 h; unsigned short u; } cv;
  cv.h = __float2bfloat16(f);
  return cv.u;
}

__device__ __forceinline__ void gll(const unsigned short* g, unsigned short* l) {
  __builtin_amdgcn_global_load_lds(
      (const __attribute__((address_space(1))) unsigned int*)g,
      (__attribute__((address_space(3))) unsigned int*)l, 16, 0, 0);
}

// ------------------------------ block reduce -------------------------------
__device__ __forceinline__ void breduce2(float& s, float& s2, float* sh) {
#pragma unroll
  for (int o = 32; o > 0; o >>= 1) {
    s  += __shfl_down(s, o);
    s2 += __shfl_down(s2, o);
  }
  const int wid = threadIdx.x >> 6, lane = threadIdx.x & 63;
  if (lane == 0) { sh[wid] = s; sh[4 + wid] = s2; }
  __syncthreads();
  if (threadIdx.x == 0) {
    sh[0] = sh[0] + sh[1] + sh[2] + sh[3];
    sh[4] = sh[4] + sh[5] + sh[6] + sh[7];
  }
  __syncthreads();
  s = sh[0]; s2 = sh[4];
}

// ------------------------------- MFMA GEMM ---------------------------------
// C[M,N] = A(bf16,swz) * B(wbufT bf16,swz)^T-style + bias.
// A: [M][K] bf16 pre-swizzled rows. Bw: [Npad][K] bf16 pre-swizzled rows
// (row n holds original B[:,n]).  Tile 128x128, BK=32, 256 threads.
// EPI 0: f32 C[m*ldc+col] = acc+bias       (NMASK: only col < Nreal)
// EPI 1: bf16 Cb[m*ldc + swzk] = relu(acc+bias)
// EPI 2: f32 C = acc + bias + res[m*ldc+col]
// EPI 3: f32 C[((m/400)*Nreal + col)*400 + m%400] = acc + bias  (conv scatter)
template<int EPI, bool NMASK>
__global__ __launch_bounds__(256)
void mgemm(const unsigned short* __restrict__ Abf,
           const unsigned short* __restrict__ Bw,
           const float* __restrict__ bias,
           const float* __restrict__ res,
           float* __restrict__ Cf, unsigned short* __restrict__ Cb,
           int K, int ldc, int Nreal)
{
  __shared__ unsigned short As[128 * 32];
  __shared__ unsigned short Bs[128 * 32];
  const int tid = threadIdx.x;
  const int w = tid >> 6, l = tid & 63;
  const int m0 = blockIdx.y * 128;
  const int n0 = blockIdx.x * 128;

  f4v acc[4][4] = {};

  // staging addresses: wave w covers tile rows [w*32, w*32+32)
  const int srow = w * 32 + (l >> 2);
  const unsigned short* ga0 = Abf + (size_t)(m0 + srow) * K + (l & 3) * 8;
  const unsigned short* ga1 = ga0 + (size_t)16 * K;
  const unsigned short* gb0 = Bw + (size_t)(n0 + srow) * K + (l & 3) * 8;
  const unsigned short* gb1 = gb0 + (size_t)16 * K;
  unsigned short* la0 = &As[(w * 32) * 32];
  unsigned short* la1 = &As[(w * 32 + 16) * 32];
  unsigned short* lb0 = &Bs[(w * 32) * 32];
  unsigned short* lb1 = &Bs[(w * 32 + 16) * 32];

  // fragment LDS offsets (shorts), swizzle folded in
  int aoff[4], boff[4];
#pragma unroll
  for (int f = 0; f < 4; f++) {
    const int ra = (w >> 1) * 64 + f * 16 + (l & 15);
    aoff[f] = ra * 32 + ((((l >> 4) + (ra >> 1)) & 3) << 3);
    const int rb = (w & 1) * 64 + f * 16 + (l & 15);
    boff[f] = rb * 32 + ((((l >> 4) + (rb >> 1)) & 3) << 3);
  }

  for (int k0 = 0; k0 < K; k0 += 32) {
    gll(ga0 + k0, la0); gll(ga1 + k0, la1);
    gll(gb0 + k0, lb0); gll(gb1 + k0, lb1);
    __syncthreads();
    s8v af[4], bf[4];
#pragma unroll
    for (int f = 0; f < 4; f++) {
      af[f] = *(const s8v*)&As[aoff[f]];
      bf[f] = *(const s8v*)&Bs[boff[f]];
    }
#pragma unroll
    for (int i = 0; i < 4; i++)
#pragma unroll
      for (int j = 0; j < 4; j++)
        acc[i][j] = __builtin_amdgcn_mfma_f32_16x16x32_bf16(af[i], bf[j], acc[i][j], 0, 0, 0);
    __syncthreads();
  }

  // epilogue: C/D layout col=lane&15, row=(lane>>4)*4+reg  [m89/m91]
  const int colb = n0 + (w & 1) * 64;
  const int rowb = m0 + (w >> 1) * 64 + (l >> 4) * 4;
#pragma unroll
  for (int i = 0; i < 4; i++) {
#pragma unroll
    for (int j = 0; j < 4; j++) {
      const int col = colb + j * 16 + (l & 15);
      if (NMASK && col >= Nreal) continue;
      const float bv = bias[col];
#pragma unroll
      for (int r = 0; r < 4; r++) {
        const int row = rowb + i * 16 + r;
        float v = acc[i][j][r] + bv;
        if (EPI == 0) {
          Cf[(size_t)row * ldc + col] = v;
        } else if (EPI == 1) {
          v = fmaxf(v, 0.0f);
          Cb[(size_t)row * ldc + swzk(row, col)] = f2b(v);
        } else if (EPI == 2) {
          Cf[(size_t)row * ldc + col] = v + res[(size_t)row * ldc + col];
        } else {  // EPI == 3
          const int bb = row / kHW, p = row % kHW;
          Cf[((size_t)bb * Nreal + col) * kHW + p] = v;
        }
      }
    }
  }
}

// -------------------------- weight conversions -----------------------------
// W [K][N] f32 row-major -> out [N][K] bf16 pre-swizzled
__global__ void cvtw_t_k(const float* __restrict__ W, unsigned short* __restrict__ out,
                         int K, int N)
{
  const int gid = blockIdx.x * 256 + threadIdx.x;   // N*(K/8)
  const int k8 = gid / N;
  const int n  = gid % N;
  const int k  = k8 * 8;
  s8v p;
#pragma unroll
  for (int j = 0; j < 8; j++) p[j] = (short)f2b(W[(size_t)(k + j) * N + n]);
  const int base = n * K + (k & ~31) + ((((k >> 3) + (n >> 1)) & 3) << 3);
  *(s8v*)&out[base] = p;
}

// combined off(128)+aw(64) weight -> out [256][512] bf16 swz (pad rows zero)
__global__ void cvtw_oaw_k(const float* __restrict__ ow, const float* __restrict__ aw,
                           unsigned short* __restrict__ out)
{
  const int gid = blockIdx.x * 256 + threadIdx.x;   // 64*256
  const int k8 = gid >> 8;
  const int n  = gid & 255;
  const int k  = k8 * 8;
  s8v p;
#pragma unroll
  for (int j = 0; j < 8; j++) {
    float v = 0.0f;
    if (n < 128)      v = ow[(size_t)(k + j) * 128 + n];
    else if (n < 192) v = aw[(size_t)(k + j) * 64 + (n - 128)];
    p[j] = (short)f2b(v);
  }
  const int base = n * 512 + (k & ~31) + ((((k >> 3) + (n >> 1)) & 3) << 3);
  *(s8v*)&out[base] = p;
}

// W already [N][K] f32 -> bf16 swz (conv weights av/ai/as)
__global__ void cvtw_d_k(const float* __restrict__ W, unsigned short* __restrict__ out,
                         int K, int N)
{
  const int gid = blockIdx.x * 256 + threadIdx.x;   // N*(K/8)
  const int K8 = K >> 3;
  const int n  = gid / K8;
  const int k  = (gid % K8) * 8;
  s8v p;
#pragma unroll
  for (int j = 0; j < 8; j++) p[j] = (short)f2b(W[(size_t)n * K + k + j]);
  const int base = n * K + (k & ~31) + ((((k >> 3) + (n >> 1)) & 3) << 3);
  *(s8v*)&out[base] = p;
}

__global__ void fill_bias_k(const float* __restrict__ ob, const float* __restrict__ ab,
                            float* __restrict__ bias)
{
  const int i = threadIdx.x;   // 192
  bias[i] = (i < 128) ? ob[i] : ab[i - 128];
}

// ----------------- input transpose [B,768,400] -> bf16 swz [b*400+p][c] -----
__global__ void tin_k(const float* __restrict__ in, unsigned short* __restrict__ out)
{
  __shared__ float t[16][17];
  const int b = blockIdx.z, c0 = blockIdx.x * 16, p0 = blockIdx.y * 16;
  const int tx = threadIdx.x & 15, ty = threadIdx.x >> 4;
  t[ty][tx] = in[((size_t)b * kCin + c0 + ty) * kHW + p0 + tx];
  __syncthreads();
  const int row = b * kHW + p0 + ty;
  const int c = c0 + tx;
  out[(size_t)row * kCin + swzk(row, c)] = f2b(t[tx][ty]);
}

// ----------------------- positional encoding + level ------------------------
__global__ void posf_k(float* __restrict__ posf, const float* __restrict__ level_embed)
{
  const int idx = blockIdx.x * 256 + threadIdx.x;   // < 800*512
  const int d = idx & (kD - 1);
  const int t = idx >> 9;
  const int lvl = t / kHW;
  const int tt = t % kHW;
  const int yy = tt / kWpx, xx = tt % kWpx;
  const int dd = (d < 256) ? d : d - 256;
  const float e = (d < 256) ? ((float)(yy + 1) / kHpx * 6.283185307179586f)
                            : ((float)(xx + 1) / kWpx * 6.283185307179586f);
  const float expo = (float)(dd >> 1) / 128.0f;
  const float dimt = powf(10000.0f, expo);
  const float pp = e / dimt;
  const float val = (dd & 1) ? cosf(pp) : sinf(pp);
  posf[idx] = val + level_embed[lvl * kD + d];
}

// --------------------------- GroupNorm (token-major) ------------------------
__global__ __launch_bounds__(256)
void gn_stats_tok_k(const float* __restrict__ x, float* __restrict__ stats)
{
  __shared__ float sh[8];
  const int b = blockIdx.x >> 5;
  const int g = blockIdx.x & 31;
  const float* xb = x + (size_t)b * kHW * kD + g * 16;
  float s = 0.f, s2 = 0.f;
  for (int i = threadIdx.x; i < kHW * 16; i += 256) {
    const int p = i >> 4, j = i & 15;
    const float v = xb[(size_t)p * kD + j];
    s += v; s2 += v * v;
  }
  breduce2(s, s2, sh);
  if (threadIdx.x == 0) {
    const float mean = s / (kHW * 16.0f);
    const float var  = s2 / (kHW * 16.0f) - mean * mean;
    stats[blockIdx.x * 2]     = mean;
    stats[blockIdx.x * 2 + 1] = rsqrtf(var + kEps);
  }
}

// writes f32 src row + swizzled bf16 srcb + swizzled bf16 qb (= val + posf)
__global__ void gn_norm_tok_k(const float* __restrict__ x, float* __restrict__ src,
                              unsigned short* __restrict__ srcb, unsigned short* __restrict__ qb,
                              const float* __restrict__ stats,
                              const float* __restrict__ gam, const float* __restrict__ bet,
                              const float* __restrict__ posf, int tokoff)
{
  const int idx = blockIdx.x * 256 + threadIdx.x;   // < 16*400*512
  const int d = idx & (kD - 1);
  const int rest = idx >> 9;
  const int b = rest / kHW, p = rest % kHW;
  const int g = d >> 4;
  const float mean = stats[(b * 32 + g) * 2];
  const float rstd = stats[(b * 32 + g) * 2 + 1];
  const float val = (x[idx] - mean) * rstd * gam[d] + bet[d];
  const int row = b * kLen + tokoff + p;
  src[(size_t)row * kD + d] = val;
  const int sk = swzk(row, d);
  srcb[(size_t)row * kD + sk] = f2b(val);
  qb[(size_t)row * kD + sk] = f2b(val + posf[(size_t)(tokoff + p) * kD + d]);
}

// --------------------------- GroupNorm (chan-major) -------------------------
__global__ __launch_bounds__(256)
void gn_stats_ch_k(const float* __restrict__ x, float* __restrict__ stats)
{
  __shared__ float sh[8];
  const int b = blockIdx.x >> 5;
  const int g = blockIdx.x & 31;
  const float* xb = x + (size_t)b * kCin * kHW + (size_t)g * 24 * kHW;
  float s = 0.f, s2 = 0.f;
  for (int i = threadIdx.x; i < 24 * kHW; i += 256) {
    const float v = xb[i];
    s += v; s2 += v * v;
  }
  breduce2(s, s2, sh);
  if (threadIdx.x == 0) {
    const float mean = s / (24.0f * kHW);
    const float var  = s2 / (24.0f * kHW) - mean * mean;
    stats[blockIdx.x * 2]     = mean;
    stats[blockIdx.x * 2 + 1] = rsqrtf(var + kEps);
  }
}

__global__ void gn_norm_ch_k(const float* __restrict__ x, float* __restrict__ out,
                             const float* __restrict__ stats,
                             const float* __restrict__ gam, const float* __restrict__ bet)
{
  const int idx = blockIdx.x * 256 + threadIdx.x;   // < 16*768*400
  const int rest = idx / kHW;
  const int c = rest % kCin;
  const int b = rest / kCin;
  const int g = c / 24;
  const float mean = stats[(b * 32 + g) * 2];
  const float rstd = stats[(b * 32 + g) * 2 + 1];
  out[idx] = (x[idx] - mean) * rstd * gam[c] + bet[c];
}

// ----------------------- modality-specific LayerNorm ------------------------
template<bool WQ>
__global__ __launch_bounds__(256)
void ln_spec_k(const float* __restrict__ x, float* __restrict__ out,
               unsigned short* __restrict__ outb, unsigned short* __restrict__ qb,
               const float* __restrict__ gamma, const float* __restrict__ beta,
               const float* __restrict__ posf)
{
  __shared__ float sh[8];
  const int row = blockIdx.x;
  const int t = row % kLen;
  const int mod = (t < kHW) ? 0 : 1;
  const float* g  = gamma + mod * kD;
  const float* be = beta  + mod * kD;
  const float* xr = x + (size_t)row * kD;
  const int d0 = threadIdx.x, d1 = threadIdx.x + 256;
  const float v0 = xr[d0];
  const float v1 = xr[d1];
  float s = v0 + v1, s2 = v0 * v0 + v1 * v1;
  breduce2(s, s2, sh);
  const float mean = s * (1.0f / kD);
  const float var  = s2 * (1.0f / kD) - mean * mean;
  const float rstd = rsqrtf(var + kEps);
  const float o0 = (v0 - mean) * rstd * g[d0] + be[d0];
  const float o1 = (v1 - mean) * rstd * g[d1] + be[d1];
  out[(size_t)row * kD + d0] = o0;
  out[(size_t)row * kD + d1] = o1;
  const int sk0 = swzk(row, d0), sk1 = swzk(row, d1);
  outb[(size_t)row * kD + sk0] = f2b(o0);
  outb[(size_t)row * kD + sk1] = f2b(o1);
  if (WQ) {
    qb[(size_t)row * kD + sk0] = f2b(o0 + posf[(size_t)t * kD + d0]);
    qb[(size_t)row * kD + sk1] = f2b(o1 + posf[(size_t)t * kD + d1]);
  }
}

// ------------------- deformable sampling (softmax + bilinear) ---------------
// one wave per (b, t, head); lane = Dh index. value f32 [16*800][512].
// out: bf16 swizzled [row][swzk(row, hh*64+lane)]
__global__ __launch_bounds__(256)
void sample_k(const float* __restrict__ value, const float* __restrict__ offaw,
              unsigned short* __restrict__ out)
{
  const int wid  = threadIdx.x >> 6;
  const int lane = threadIdx.x & 63;
  const int wg = blockIdx.x * 4 + wid;          // < 16*800*8
  const int b = wg / (kLen * kHd);
  const int rem = wg % (kLen * kHd);
  const int t = rem >> 3;
  const int hh = rem & 7;

  const int tt = t % kHW;
  const float refx = ((float)(tt % kWpx) + 0.5f) / kWpx;
  const float refy = ((float)(tt / kWpx) + 0.5f) / kHpx;

  const float* oa = offaw + (size_t)(b * kLen + t) * 192;

  float lg[8], mx = -1e30f;
#pragma unroll
  for (int i = 0; i < 8; i++) {
    lg[i] = oa[128 + hh * 8 + i];
    mx = fmaxf(mx, lg[i]);
  }
  float ssum = 0.f;
#pragma unroll
  for (int i = 0; i < 8; i++) { lg[i] = expf(lg[i] - mx); ssum += lg[i]; }
  const float inv = 1.0f / ssum;

  float acc = 0.f;
#pragma unroll
  for (int lvl = 0; lvl < 2; lvl++) {
    const float* vbase = value + (size_t)(b * kLen + lvl * kHW) * kD + hh * 64 + lane;
#pragma unroll
    for (int p = 0; p < 4; p++) {
      const float ox = oa[hh * 16 + lvl * 8 + p * 2];
      const float oy = oa[hh * 16 + lvl * 8 + p * 2 + 1];
      const float x = (refx + ox * (1.0f / kWpx)) * kWpx - 0.5f;
      const float y = (refy + oy * (1.0f / kHpx)) * kHpx - 0.5f;
      const float x0f = floorf(x), y0f = floorf(y);
      const float wx = x - x0f, wy = y - y0f;
      const int x0 = (int)x0f, y0 = (int)y0f;
      const float aw = lg[lvl * 4 + p] * inv;
#pragma unroll
      for (int dy = 0; dy < 2; dy++)
#pragma unroll
        for (int dx = 0; dx < 2; dx++) {
          const int ix = x0 + dx, iy = y0 + dy;
          if (ix >= 0 && ix < kWpx && iy >= 0 && iy < kHpx) {
            const float cw = (dx ? wx : 1.0f - wx) * (dy ? wy : 1.0f - wy);
            acc += aw * cw * vbase[(size_t)(iy * kWpx + ix) * kD];
          }
        }
    }
  }
  const int row = b * kLen + t;
  const int col = hh * 64 + lane;
  out[(size_t)row * kD + swzk(row, col)] = f2b(acc);
}

// --------------------------- token-sum -> bf16 swz --------------------------
__global__ void sumtok_k(const float* __restrict__ src, unsigned short* __restrict__ tokb)
{
  const int idx = blockIdx.x * 256 + threadIdx.x;   // < 16*400*512
  const int b = idx / (kHW * kD);
  const int r = idx % (kHW * kD);
  const int p = r >> 9, d = r & (kD - 1);
  const float v = src[(size_t)b * kLen * kD + r] +
                  src[(size_t)b * kLen * kD + (size_t)kHW * kD + r];
  const int row = b * kHW + p;
  tokb[(size_t)row * kD + swzk(row, d)] = f2b(v);
}

// ------------------------------- launcher -----------------------------------
extern "C" void kernel_launch(void* const* d_in, const int* in_sizes, int n_in,
                              void* d_out, int out_size, void* d_ws, size_t ws_size,
                              hipStream_t stream)
{
  const float* input_v     = (const float*)d_in[0];
  const float* input_i     = (const float*)d_in[1];
  const float* av_w        = (const float*)d_in[2];
  const float* av_b        = (const float*)d_in[3];
  const float* av_g        = (const float*)d_in[4];
  const float* av_be       = (const float*)d_in[5];
  const float* ai_w        = (const float*)d_in[6];
  const float* ai_b        = (const float*)d_in[7];
  const float* ai_g        = (const float*)d_in[8];
  const float* ai_be       = (const float*)d_in[9];
  const float* level_embed = (const float*)d_in[10];
  const float* off_w       = (const float*)d_in[11];
  const float* off_b       = (const float*)d_in[12];
  const float* aw_w        = (const float*)d_in[13];
  const float* aw_b        = (const float*)d_in[14];
  const float* vp_w        = (const float*)d_in[15];
  const float* vp_b        = (const float*)d_in[16];
  const float* op_w        = (const float*)d_in[17];
  const float* op_b        = (const float*)d_in[18];
  const float* ln1_g       = (const float*)d_in[19];
  const float* ln1_b       = (const float*)d_in[20];
  const float* ffn1_w      = (const float*)d_in[21];
  const float* ffn1_b      = (const float*)d_in[22];
  const float* ffn2_w      = (const float*)d_in[23];
  const float* ffn2_b      = (const float*)d_in[24];
  const float* ln2_g       = (const float*)d_in[25];
  const float* ln2_b       = (const float*)d_in[26];
  const float* as_w        = (const float*)d_in[27];
  const float* as_b        = (const float*)d_in[28];
  const float* as_g        = (const float*)d_in[29];
  const float* as_be       = (const float*)d_in[30];

  // ------- workspace layout -------
  float* wsf   = (float*)d_ws;
  float* src   = wsf;                                  // 6,553,600 f
  float* tmp1  = src   + (size_t)6553600;              // 6,553,600 f
  float* posf  = tmp1  + (size_t)6553600;              //   409,600 f
  float* offaw = posf  + (size_t)409600;               // 2,457,600 f
  float* biasb = offaw + (size_t)2457600;              //       256 f
  float* stats = biasb + (size_t)256;                  //     1,024 f
  unsigned short* srcb  = (unsigned short*)(stats + 1024);      // 6,553,600 sh
  unsigned short* arena = srcb  + (size_t)6553600;              // 6,553,600 sh
  unsigned short* wbuf0 = arena + (size_t)6553600;              //   524,288 sh
  unsigned short* wbuf1 = wbuf0 + (size_t)524288;               //   524,288 sh
  // inb lives in the tail half of tmp1 (disjoint from conv output head)
  unsigned short* inb   = (unsigned short*)(tmp1 + 3276800);

  const int M  = kB * kLen;   // 12800
  const int Mh = kB * kHW;    // 6400

  posf_k<<<dim3(kLen * kD / 256), 256, 0, stream>>>(posf, level_embed);

  // ---- input convs + GN -> src/srcb/qb ----
  for (int mod = 0; mod < 2; mod++) {
    const float* in  = mod ? input_i : input_v;
    const float* cw  = mod ? ai_w  : av_w;
    const float* cb  = mod ? ai_b  : av_b;
    const float* cg  = mod ? ai_g  : av_g;
    const float* cbe = mod ? ai_be : av_be;
    tin_k<<<dim3(48, 25, 16), 256, 0, stream>>>(in, inb);
    cvtw_d_k<<<dim3(512 * 96 / 256), 256, 0, stream>>>(cw, wbuf0, 768, 512);
    mgemm<0, false><<<dim3(4, 50), 256, 0, stream>>>(
        inb, wbuf0, cb, nullptr, tmp1, nullptr, 768, 512, 512);
    gn_stats_tok_k<<<dim3(kB * 32), 256, 0, stream>>>(tmp1, stats);
    gn_norm_tok_k<<<dim3(kB * kHW * kD / 256), 256, 0, stream>>>(
        tmp1, src, srcb, arena, stats, cg, cbe, posf, mod * kHW);
  }

  for (int l = 0; l < kNL; l++) {
    const float* owl  = off_w  + (size_t)l * kD * 128;
    const float* obl  = off_b  + (size_t)l * 128;
    const float* awl  = aw_w   + (size_t)l * kD * 64;
    const float* awbl = aw_b   + (size_t)l * 64;
    const float* vwl  = vp_w   + (size_t)l * kD * kD;
    const float* vbl  = vp_b   + (size_t)l * kD;
    const float* opwl = op_w   + (size_t)l * kD * kD;
    const float* opbl = op_b   + (size_t)l * kD;
    const float* l1g  = ln1_g  + (size_t)l * 2 * kD;
    const float* l1b  = ln1_b  + (size_t)l * 2 * kD;
    const float* f1w  = ffn1_w + (size_t)l * kD * kDff;
    const float* f1b  = ffn1_b + (size_t)l * kDff;
    const float* f2w  = ffn2_w + (size_t)l * kDff * kD;
    const float* f2b_ = ffn2_b + (size_t)l * kD;
    const float* l2g  = ln2_g  + (size_t)l * 2 * kD;
    const float* l2b  = ln2_b  + (size_t)l * 2 * kD;

    // value = srcb @ vp + vb -> tmp1 (f32)
    cvtw_t_k<<<dim3(512 * 64 / 256), 256, 0, stream>>>(vwl, wbuf0, 512, 512);
    mgemm<0, false><<<dim3(4, 100), 256, 0, stream>>>(
        srcb, wbuf0, vbl, nullptr, tmp1, nullptr, 512, 512, 512);

    // offaw = qb @ [ow|aww] + [ob|awb] -> offaw (f32, 192-wide)
    fill_bias_k<<<dim3(1), 192, 0, stream>>>(obl, awbl, biasb);
    cvtw_oaw_k<<<dim3(64), 256, 0, stream>>>(owl, awl, wbuf0);
    mgemm<0, true><<<dim3(2, 100), 256, 0, stream>>>(
        arena /*qb*/, wbuf0, biasb, nullptr, offaw, nullptr, 512, 192, 192);

    // sampling -> sampb (arena, bf16 swz)
    sample_k<<<dim3(kB * kLen * kHd / 4), 256, 0, stream>>>(tmp1, offaw, arena);

    // y = src + sampb @ op + opb -> tmp1
    cvtw_t_k<<<dim3(512 * 64 / 256), 256, 0, stream>>>(opwl, wbuf0, 512, 512);
    mgemm<2, false><<<dim3(4, 100), 256, 0, stream>>>(
        arena, wbuf0, opbl, src, tmp1, nullptr, 512, 512, 512);

    // src = LN_spec(y)  (no q needed mid-layer)
    ln_spec_k<false><<<dim3(M), 256, 0, stream>>>(tmp1, src, srcb, nullptr, l1g, l1b, posf);

    // FFN in two M-halves; hidden (bf16 swz) lives in arena
    cvtw_t_k<<<dim3(1024 * 64 / 256), 256, 0, stream>>>(f1w, wbuf0, 512, 1024);
    cvtw_t_k<<<dim3(512 * 128 / 256), 256, 0, stream>>>(f2w, wbuf1, 1024, 512);
    for (int hf = 0; hf < 2; hf++) {
      const size_t o = (size_t)hf * Mh * kD;
      mgemm<1, false><<<dim3(8, 50), 256, 0, stream>>>(
          srcb + o, wbuf0, f1b, nullptr, nullptr, arena, 512, 1024, 1024);
      mgemm<2, false><<<dim3(4, 50), 256, 0, stream>>>(
          arena, wbuf1, f2b_, src + o, tmp1 + o, nullptr, 1024, 512, 512);
    }

    // src = LN_spec(y); produce qb for next layer (not needed after last)
    if (l < kNL - 1)
      ln_spec_k<true><<<dim3(M), 256, 0, stream>>>(tmp1, src, srcb, arena, l2g, l2b, posf);
    else
      ln_spec_k<false><<<dim3(M), 256, 0, stream>>>(tmp1, src, srcb, nullptr, l2g, l2b, posf);
  }

  // out = GN(conv1x1(src_v + src_i))
  sumtok_k<<<dim3(kB * kHW * kD / 256), 256, 0, stream>>>(src, arena);
  cvtw_d_k<<<dim3(768 * 64 / 256), 256, 0, stream>>>(as_w, wbuf0, 512, 768);
  mgemm<3, false><<<dim3(6, 50), 256, 0, stream>>>(
      arena, wbuf0, as_b, nullptr, tmp1, nullptr, 512, 0, 768);
  gn_stats_ch_k<<<dim3(kB * 32), 256, 0, stream>>>(tmp1, stats);
  gn_norm_ch_k<<<dim3(kB * kCin * kHW / 256), 256, 0, stream>>>(
      tmp1, (float*)d_out, stats, as_g, as_be);
}

// Round 3
// 1464.186 us; speedup vs baseline: 3.8478x; 1.4560x over previous
//
#include <hip/hip_runtime.h>
#include <hip/hip_bf16.h>
#include <cstddef>
#include <math.h>

// ---------------------------------------------------------------------------
// Round 2: sample_k restructured (phase A: 1 lane = 1 (head,lvl,pt) combo,
// weights+indices staged in LDS; phase B: 4-ch float4 gather-accumulate).
// Per-layer weight conversions fused into one dispatch.
// GEMMs: bf16 MFMA 16x16x32, 128x128 tile, global_load_lds(16B), pre-swizzled.
// ---------------------------------------------------------------------------

constexpr int kB   = 16;
constexpr int kCin = 768;
constexpr int kHW  = 400;
constexpr int kWpx = 20;
constexpr int kHpx = 20;
constexpr int kD   = 512;
constexpr int kLen = 800;
constexpr int kHd  = 8;
constexpr int kDff = 1024;
constexpr int kNL  = 6;
constexpr float kEps = 1e-5f;

typedef __attribute__((ext_vector_type(8))) short s8v;
typedef __attribute__((ext_vector_type(4))) short s4v;
typedef __attribute__((ext_vector_type(4))) float f4v;

// k-group swizzle: within each 32-element k-group, rotate 8-element slots by
// (row>>1)&3.
__device__ __forceinline__ int swzk(int row, int k) {
  return (k & ~31) | ((((k >> 3) + (row >> 1)) & 3) << 3) | (k & 7);
}

__device__ __forceinline__ unsigned short f2b(float f) {
  union { __hip_bfloat16 h; unsigned short u; } cv;
  cv.h = __float2bfloat16(f);
  return cv.u;
}

__device__ __forceinline__ void gll(const unsigned short* g, unsigned short* l) {
  __builtin_amdgcn_global_load_lds(
      (const __attribute__((address_space(1))) unsigned int*)g,
      (__attribute__((address_space(3))) unsigned int*)l, 16, 0, 0);
}

// ------------------------------ block reduce -------------------------------
__device__ __forceinline__ void breduce2(float& s, float& s2, float* sh) {
#pragma unroll
  for (int o = 32; o > 0; o >>= 1) {
    s  += __shfl_down(s, o);
    s2 += __shfl_down(s2, o);
  }
  const int wid = threadIdx.x >> 6, lane = threadIdx.x & 63;
  if (lane == 0) { sh[wid] = s; sh[4 + wid] = s2; }
  __syncthreads();
  if (threadIdx.x == 0) {
    sh[0] = sh[0] + sh[1] + sh[2] + sh[3];
    sh[4] = sh[4] + sh[5] + sh[6] + sh[7];
  }
  __syncthreads();
  s = sh[0]; s2 = sh[4];
}

// ------------------------------- MFMA GEMM ---------------------------------
// EPI 0: f32 C[m*ldc+col] = acc+bias       (NMASK: only col < Nreal)
// EPI 1: bf16 Cb[m*ldc + swzk] = relu(acc+bias)
// EPI 2: f32 C = acc + bias + res[m*ldc+col]
// EPI 3: f32 C[((m/400)*Nreal + col)*400 + m%400] = acc + bias  (conv scatter)
template<int EPI, bool NMASK>
__global__ __launch_bounds__(256)
void mgemm(const unsigned short* __restrict__ Abf,
           const unsigned short* __restrict__ Bw,
           const float* __restrict__ bias,
           const float* __restrict__ res,
           float* __restrict__ Cf, unsigned short* __restrict__ Cb,
           int K, int ldc, int Nreal)
{
  __shared__ unsigned short As[128 * 32];
  __shared__ unsigned short Bs[128 * 32];
  const int tid = threadIdx.x;
  const int w = tid >> 6, l = tid & 63;
  const int m0 = blockIdx.y * 128;
  const int n0 = blockIdx.x * 128;

  f4v acc[4][4] = {};

  const int srow = w * 32 + (l >> 2);
  const unsigned short* ga0 = Abf + (size_t)(m0 + srow) * K + (l & 3) * 8;
  const unsigned short* ga1 = ga0 + (size_t)16 * K;
  const unsigned short* gb0 = Bw + (size_t)(n0 + srow) * K + (l & 3) * 8;
  const unsigned short* gb1 = gb0 + (size_t)16 * K;
  unsigned short* la0 = &As[(w * 32) * 32];
  unsigned short* la1 = &As[(w * 32 + 16) * 32];
  unsigned short* lb0 = &Bs[(w * 32) * 32];
  unsigned short* lb1 = &Bs[(w * 32 + 16) * 32];

  int aoff[4], boff[4];
#pragma unroll
  for (int f = 0; f < 4; f++) {
    const int ra = (w >> 1) * 64 + f * 16 + (l & 15);
    aoff[f] = ra * 32 + ((((l >> 4) + (ra >> 1)) & 3) << 3);
    const int rb = (w & 1) * 64 + f * 16 + (l & 15);
    boff[f] = rb * 32 + ((((l >> 4) + (rb >> 1)) & 3) << 3);
  }

  for (int k0 = 0; k0 < K; k0 += 32) {
    gll(ga0 + k0, la0); gll(ga1 + k0, la1);
    gll(gb0 + k0, lb0); gll(gb1 + k0, lb1);
    __syncthreads();
    s8v af[4], bf[4];
#pragma unroll
    for (int f = 0; f < 4; f++) {
      af[f] = *(const s8v*)&As[aoff[f]];
      bf[f] = *(const s8v*)&Bs[boff[f]];
    }
#pragma unroll
    for (int i = 0; i < 4; i++)
#pragma unroll
      for (int j = 0; j < 4; j++)
        acc[i][j] = __builtin_amdgcn_mfma_f32_16x16x32_bf16(af[i], bf[j], acc[i][j], 0, 0, 0);
    __syncthreads();
  }

  const int colb = n0 + (w & 1) * 64;
  const int rowb = m0 + (w >> 1) * 64 + (l >> 4) * 4;
#pragma unroll
  for (int i = 0; i < 4; i++) {
#pragma unroll
    for (int j = 0; j < 4; j++) {
      const int col = colb + j * 16 + (l & 15);
      if (NMASK && col >= Nreal) continue;
      const float bv = bias[col];
#pragma unroll
      for (int r = 0; r < 4; r++) {
        const int row = rowb + i * 16 + r;
        float v = acc[i][j][r] + bv;
        if (EPI == 0) {
          Cf[(size_t)row * ldc + col] = v;
        } else if (EPI == 1) {
          v = fmaxf(v, 0.0f);
          Cb[(size_t)row * ldc + swzk(row, col)] = f2b(v);
        } else if (EPI == 2) {
          Cf[(size_t)row * ldc + col] = v + res[(size_t)row * ldc + col];
        } else {  // EPI == 3
          const int bb = row / kHW, p = row % kHW;
          Cf[((size_t)bb * Nreal + col) * kHW + p] = v;
        }
      }
    }
  }
}

// -------------------------- weight conversions -----------------------------
// one 8-elem k-group: W [K][N] f32 -> out [N][K] bf16 swz
__device__ __forceinline__ void cvt8t(const float* __restrict__ W,
                                      unsigned short* __restrict__ out,
                                      int K, int N, int g)
{
  const int n = g % N;
  const int k = (g / N) * 8;
  s8v p;
#pragma unroll
  for (int j = 0; j < 8; j++) p[j] = (short)f2b(W[(size_t)(k + j) * N + n]);
  const int base = n * K + (k & ~31) + ((((k >> 3) + (n >> 1)) & 3) << 3);
  *(s8v*)&out[base] = p;
}

// all layer-l weight conversions in one dispatch (213,184 work items)
__global__ __launch_bounds__(256)
void cvt_layer_k(const float* __restrict__ vw, const float* __restrict__ opw,
                 const float* __restrict__ ow, const float* __restrict__ aww,
                 const float* __restrict__ f1w, const float* __restrict__ f2w,
                 const float* __restrict__ ob, const float* __restrict__ awb,
                 unsigned short* __restrict__ wvp, unsigned short* __restrict__ wop,
                 unsigned short* __restrict__ woaw, unsigned short* __restrict__ wf1,
                 unsigned short* __restrict__ wf2, float* __restrict__ biasb)
{
  int g = blockIdx.x * 256 + threadIdx.x;
  if (g < 32768) { cvt8t(vw, wvp, 512, 512, g); return; }
  g -= 32768;
  if (g < 32768) { cvt8t(opw, wop, 512, 512, g); return; }
  g -= 32768;
  if (g < 16384) {                       // oaw: [256][512], pad n>=192 zero
    const int n = g & 255;
    const int k = (g >> 8) * 8;
    s8v p;
#pragma unroll
    for (int j = 0; j < 8; j++) {
      float v = 0.0f;
      if (n < 128)      v = ow[(size_t)(k + j) * 128 + n];
      else if (n < 192) v = aww[(size_t)(k + j) * 64 + (n - 128)];
      p[j] = (short)f2b(v);
    }
    const int base = n * 512 + (k & ~31) + ((((k >> 3) + (n >> 1)) & 3) << 3);
    *(s8v*)&woaw[base] = p;
    return;
  }
  g -= 16384;
  if (g < 65536) { cvt8t(f1w, wf1, 512, 1024, g); return; }
  g -= 65536;
  if (g < 65536) { cvt8t(f2w, wf2, 1024, 512, g); return; }
  g -= 65536;
  if (g < 192) biasb[g] = (g < 128) ? ob[g] : awb[g - 128];
}

// W already [N][K] f32 -> bf16 swz (conv weights av/ai/as)
__global__ void cvtw_d_k(const float* __restrict__ W, unsigned short* __restrict__ out,
                         int K, int N)
{
  const int gid = blockIdx.x * 256 + threadIdx.x;   // N*(K/8)
  const int K8 = K >> 3;
  const int n  = gid / K8;
  const int k  = (gid % K8) * 8;
  s8v p;
#pragma unroll
  for (int j = 0; j < 8; j++) p[j] = (short)f2b(W[(size_t)n * K + k + j]);
  const int base = n * K + (k & ~31) + ((((k >> 3) + (n >> 1)) & 3) << 3);
  *(s8v*)&out[base] = p;
}

// ----------------- input transpose [B,768,400] -> bf16 swz [b*400+p][c] -----
__global__ void tin_k(const float* __restrict__ in, unsigned short* __restrict__ out)
{
  __shared__ float t[16][17];
  const int b = blockIdx.z, c0 = blockIdx.x * 16, p0 = blockIdx.y * 16;
  const int tx = threadIdx.x & 15, ty = threadIdx.x >> 4;
  t[ty][tx] = in[((size_t)b * kCin + c0 + ty) * kHW + p0 + tx];
  __syncthreads();
  const int row = b * kHW + p0 + ty;
  const int c = c0 + tx;
  out[(size_t)row * kCin + swzk(row, c)] = f2b(t[tx][ty]);
}

// ----------------------- positional encoding + level ------------------------
__global__ void posf_k(float* __restrict__ posf, const float* __restrict__ level_embed)
{
  const int idx = blockIdx.x * 256 + threadIdx.x;   // < 800*512
  const int d = idx & (kD - 1);
  const int t = idx >> 9;
  const int lvl = t / kHW;
  const int tt = t % kHW;
  const int yy = tt / kWpx, xx = tt % kWpx;
  const int dd = (d < 256) ? d : d - 256;
  const float e = (d < 256) ? ((float)(yy + 1) / kHpx * 6.283185307179586f)
                            : ((float)(xx + 1) / kWpx * 6.283185307179586f);
  const float expo = (float)(dd >> 1) / 128.0f;
  const float dimt = powf(10000.0f, expo);
  const float pp = e / dimt;
  const float val = (dd & 1) ? cosf(pp) : sinf(pp);
  posf[idx] = val + level_embed[lvl * kD + d];
}

// --------------------------- GroupNorm (token-major) ------------------------
__global__ __launch_bounds__(256)
void gn_stats_tok_k(const float* __restrict__ x, float* __restrict__ stats)
{
  __shared__ float sh[8];
  const int b = blockIdx.x >> 5;
  const int g = blockIdx.x & 31;
  const float* xb = x + (size_t)b * kHW * kD + g * 16;
  float s = 0.f, s2 = 0.f;
  for (int i = threadIdx.x; i < kHW * 16; i += 256) {
    const int p = i >> 4, j = i & 15;
    const float v = xb[(size_t)p * kD + j];
    s += v; s2 += v * v;
  }
  breduce2(s, s2, sh);
  if (threadIdx.x == 0) {
    const float mean = s / (kHW * 16.0f);
    const float var  = s2 / (kHW * 16.0f) - mean * mean;
    stats[blockIdx.x * 2]     = mean;
    stats[blockIdx.x * 2 + 1] = rsqrtf(var + kEps);
  }
}

__global__ void gn_norm_tok_k(const float* __restrict__ x, float* __restrict__ src,
                              unsigned short* __restrict__ srcb, unsigned short* __restrict__ qb,
                              const float* __restrict__ stats,
                              const float* __restrict__ gam, const float* __restrict__ bet,
                              const float* __restrict__ posf, int tokoff)
{
  const int idx = blockIdx.x * 256 + threadIdx.x;   // < 16*400*512
  const int d = idx & (kD - 1);
  const int rest = idx >> 9;
  const int b = rest / kHW, p = rest % kHW;
  const int g = d >> 4;
  const float mean = stats[(b * 32 + g) * 2];
  const float rstd = stats[(b * 32 + g) * 2 + 1];
  const float val = (x[idx] - mean) * rstd * gam[d] + bet[d];
  const int row = b * kLen + tokoff + p;
  src[(size_t)row * kD + d] = val;
  const int sk = swzk(row, d);
  srcb[(size_t)row * kD + sk] = f2b(val);
  qb[(size_t)row * kD + sk] = f2b(val + posf[(size_t)(tokoff + p) * kD + d]);
}

// --------------------------- GroupNorm (chan-major) -------------------------
__global__ __launch_bounds__(256)
void gn_stats_ch_k(const float* __restrict__ x, float* __restrict__ stats)
{
  __shared__ float sh[8];
  const int b = blockIdx.x >> 5;
  const int g = blockIdx.x & 31;
  const float* xb = x + (size_t)b * kCin * kHW + (size_t)g * 24 * kHW;
  float s = 0.f, s2 = 0.f;
  for (int i = threadIdx.x; i < 24 * kHW; i += 256) {
    const float v = xb[i];
    s += v; s2 += v * v;
  }
  breduce2(s, s2, sh);
  if (threadIdx.x == 0) {
    const float mean = s / (24.0f * kHW);
    const float var  = s2 / (24.0f * kHW) - mean * mean;
    stats[blockIdx.x * 2]     = mean;
    stats[blockIdx.x * 2 + 1] = rsqrtf(var + kEps);
  }
}

__global__ void gn_norm_ch_k(const float* __restrict__ x, float* __restrict__ out,
                             const float* __restrict__ stats,
                             const float* __restrict__ gam, const float* __restrict__ bet)
{
  const int idx = blockIdx.x * 256 + threadIdx.x;   // < 16*768*400
  const int rest = idx / kHW;
  const int c = rest % kCin;
  const int b = rest / kCin;
  const int g = c / 24;
  const float mean = stats[(b * 32 + g) * 2];
  const float rstd = stats[(b * 32 + g) * 2 + 1];
  out[idx] = (x[idx] - mean) * rstd * gam[c] + bet[c];
}

// ----------------------- modality-specific LayerNorm ------------------------
template<bool WQ>
__global__ __launch_bounds__(256)
void ln_spec_k(const float* __restrict__ x, float* __restrict__ out,
               unsigned short* __restrict__ outb, unsigned short* __restrict__ qb,
               const float* __restrict__ gamma, const float* __restrict__ beta,
               const float* __restrict__ posf)
{
  __shared__ float sh[8];
  const int row = blockIdx.x;
  const int t = row % kLen;
  const int mod = (t < kHW) ? 0 : 1;
  const float* g  = gamma + mod * kD;
  const float* be = beta  + mod * kD;
  const float* xr = x + (size_t)row * kD;
  const int d0 = threadIdx.x, d1 = threadIdx.x + 256;
  const float v0 = xr[d0];
  const float v1 = xr[d1];
  float s = v0 + v1, s2 = v0 * v0 + v1 * v1;
  breduce2(s, s2, sh);
  const float mean = s * (1.0f / kD);
  const float var  = s2 * (1.0f / kD) - mean * mean;
  const float rstd = rsqrtf(var + kEps);
  const float o0 = (v0 - mean) * rstd * g[d0] + be[d0];
  const float o1 = (v1 - mean) * rstd * g[d1] + be[d1];
  out[(size_t)row * kD + d0] = o0;
  out[(size_t)row * kD + d1] = o1;
  const int sk0 = swzk(row, d0), sk1 = swzk(row, d1);
  outb[(size_t)row * kD + sk0] = f2b(o0);
  outb[(size_t)row * kD + sk1] = f2b(o1);
  if (WQ) {
    qb[(size_t)row * kD + sk0] = f2b(o0 + posf[(size_t)t * kD + d0]);
    qb[(size_t)row * kD + sk1] = f2b(o1 + posf[(size_t)t * kD + d1]);
  }
}

// ------------------- deformable sampling (softmax + bilinear) ---------------
// block = 256 thr = 2 tokens x 128 workers (4 channels each).
// Phase A: 64 lanes = 64 (head,lvl,pt) combos -> (weight, row-idx) x4 in LDS.
// Phase B: float4 gather-accumulate; out bf16 swizzled.
__global__ __launch_bounds__(256)
void sample_k(const float* __restrict__ value, const float* __restrict__ offaw,
              unsigned short* __restrict__ out)
{
  __shared__ float wls[2][64][8];   // [tok][combo][w0,i0,w1,i1,w2,i2,w3,i3]
  const int tid = threadIdx.x;
  const int tok = tid >> 7;
  const int wt  = tid & 127;
  const int token = blockIdx.x * 2 + tok;       // < 12800
  const int b = token / kLen;
  const int t = token % kLen;
  const int tt = t % kHW;

  if (wt < 64) {
    const int h = wt >> 3, lp = wt & 7, lvl = lp >> 2, p = lp & 3;
    const float* oa = offaw + (size_t)token * 192;
    const float lg = oa[128 + h * 8 + lp];
    // softmax over 8-lane group
    float mx = lg;
#pragma unroll
    for (int msk = 1; msk < 8; msk <<= 1) mx = fmaxf(mx, __shfl_xor(mx, msk));
    const float ex = __expf(lg - mx);
    float ssum = ex;
#pragma unroll
    for (int msk = 1; msk < 8; msk <<= 1) ssum += __shfl_xor(ssum, msk);
    const float aw = ex / ssum;

    const float x = (float)(tt % kWpx) + oa[h * 16 + lvl * 8 + p * 2];
    const float y = (float)(tt / kWpx) + oa[h * 16 + lvl * 8 + p * 2 + 1];
    const float x0f = floorf(x), y0f = floorf(y);
    const float wx = x - x0f, wy = y - y0f;
    const int x0 = (int)x0f, y0 = (int)y0f;
    const int rowbase = b * kLen + lvl * kHW;
#pragma unroll
    for (int dy = 0; dy < 2; dy++) {
#pragma unroll
      for (int dx = 0; dx < 2; dx++) {
        const int ix = x0 + dx, iy = y0 + dy;
        const bool valid = (ix >= 0) & (ix < kWpx) & (iy >= 0) & (iy < kHpx);
        const float cw = (dx ? wx : 1.0f - wx) * (dy ? wy : 1.0f - wy);
        const float w = valid ? aw * cw : 0.0f;
        const int ixc = min(max(ix, 0), kWpx - 1);
        const int iyc = min(max(iy, 0), kHpx - 1);
        const int r = rowbase + iyc * kWpx + ixc;
        const int cn = dy * 2 + dx;
        wls[tok][wt][cn * 2]     = w;
        wls[tok][wt][cn * 2 + 1] = __int_as_float(r);
      }
    }
  }
  __syncthreads();

  const int c0 = wt * 4;
  const int h = wt >> 4;
  float acc0 = 0.f, acc1 = 0.f, acc2 = 0.f, acc3 = 0.f;
  const float* vb = value + c0;
#pragma unroll
  for (int pp = 0; pp < 8; pp++) {
    const float* wl = wls[tok][h * 8 + pp];
#pragma unroll
    for (int cn = 0; cn < 4; cn++) {
      const float w = wl[cn * 2];
      const int r = __float_as_int(wl[cn * 2 + 1]);
      const float4 v = *(const float4*)(vb + (size_t)r * kD);
      acc0 += w * v.x; acc1 += w * v.y; acc2 += w * v.z; acc3 += w * v.w;
    }
  }
  const int sk = swzk(token, c0);
  s4v o;
  o[0] = (short)f2b(acc0); o[1] = (short)f2b(acc1);
  o[2] = (short)f2b(acc2); o[3] = (short)f2b(acc3);
  *(s4v*)&out[(size_t)token * kD + sk] = o;
}

// --------------------------- token-sum -> bf16 swz --------------------------
__global__ void sumtok_k(const float* __restrict__ src, unsigned short* __restrict__ tokb)
{
  const int idx = blockIdx.x * 256 + threadIdx.x;   // < 16*400*512
  const int b = idx / (kHW * kD);
  const int r = idx % (kHW * kD);
  const int p = r >> 9, d = r & (kD - 1);
  const float v = src[(size_t)b * kLen * kD + r] +
                  src[(size_t)b * kLen * kD + (size_t)kHW * kD + r];
  const int row = b * kHW + p;
  tokb[(size_t)row * kD + swzk(row, d)] = f2b(v);
}

// ------------------------------- launcher -----------------------------------
extern "C" void kernel_launch(void* const* d_in, const int* in_sizes, int n_in,
                              void* d_out, int out_size, void* d_ws, size_t ws_size,
                              hipStream_t stream)
{
  const float* input_v     = (const float*)d_in[0];
  const float* input_i     = (const float*)d_in[1];
  const float* av_w        = (const float*)d_in[2];
  const float* av_b        = (const float*)d_in[3];
  const float* av_g        = (const float*)d_in[4];
  const float* av_be       = (const float*)d_in[5];
  const float* ai_w        = (const float*)d_in[6];
  const float* ai_b        = (const float*)d_in[7];
  const float* ai_g        = (const float*)d_in[8];
  const float* ai_be       = (const float*)d_in[9];
  const float* level_embed = (const float*)d_in[10];
  const float* off_w       = (const float*)d_in[11];
  const float* off_b       = (const float*)d_in[12];
  const float* aw_w        = (const float*)d_in[13];
  const float* aw_b        = (const float*)d_in[14];
  const float* vp_w        = (const float*)d_in[15];
  const float* vp_b        = (const float*)d_in[16];
  const float* op_w        = (const float*)d_in[17];
  const float* op_b        = (const float*)d_in[18];
  const float* ln1_g       = (const float*)d_in[19];
  const float* ln1_b       = (const float*)d_in[20];
  const float* ffn1_w      = (const float*)d_in[21];
  const float* ffn1_b      = (const float*)d_in[22];
  const float* ffn2_w      = (const float*)d_in[23];
  const float* ffn2_b      = (const float*)d_in[24];
  const float* ln2_g       = (const float*)d_in[25];
  const float* ln2_b       = (const float*)d_in[26];
  const float* as_w        = (const float*)d_in[27];
  const float* as_b        = (const float*)d_in[28];
  const float* as_g        = (const float*)d_in[29];
  const float* as_be       = (const float*)d_in[30];

  // ------- workspace layout -------
  float* wsf   = (float*)d_ws;
  float* src   = wsf;                                  // 6,553,600 f
  float* tmp1  = src   + (size_t)6553600;              // 6,553,600 f
  float* posf  = tmp1  + (size_t)6553600;              //   409,600 f
  float* offaw = posf  + (size_t)409600;               // 2,457,600 f
  float* biasb = offaw + (size_t)2457600;              //       256 f
  float* stats = biasb + (size_t)256;                  //     1,024 f
  unsigned short* srcb  = (unsigned short*)(stats + 1024);      // 6,553,600 sh
  unsigned short* arena = srcb  + (size_t)6553600;              // 6,553,600 sh
  unsigned short* wvp   = arena + (size_t)6553600;              //   262,144 sh
  unsigned short* wop   = wvp   + (size_t)262144;               //   262,144 sh
  unsigned short* woaw  = wop   + (size_t)262144;               //   131,072 sh
  unsigned short* wf1   = woaw  + (size_t)131072;               //   524,288 sh
  unsigned short* wf2   = wf1   + (size_t)524288;               //   524,288 sh
  // inb lives in the tail half of tmp1 (disjoint from conv output head)
  unsigned short* inb   = (unsigned short*)(tmp1 + 3276800);

  const int M  = kB * kLen;   // 12800
  const int Mh = kB * kHW;    // 6400

  posf_k<<<dim3(kLen * kD / 256), 256, 0, stream>>>(posf, level_embed);

  // ---- input convs + GN -> src/srcb/qb ----
  for (int mod = 0; mod < 2; mod++) {
    const float* in  = mod ? input_i : input_v;
    const float* cw  = mod ? ai_w  : av_w;
    const float* cb  = mod ? ai_b  : av_b;
    const float* cg  = mod ? ai_g  : av_g;
    const float* cbe = mod ? ai_be : av_be;
    tin_k<<<dim3(48, 25, 16), 256, 0, stream>>>(in, inb);
    cvtw_d_k<<<dim3(512 * 96 / 256), 256, 0, stream>>>(cw, wf1, 768, 512);
    mgemm<0, false><<<dim3(4, 50), 256, 0, stream>>>(
        inb, wf1, cb, nullptr, tmp1, nullptr, 768, 512, 512);
    gn_stats_tok_k<<<dim3(kB * 32), 256, 0, stream>>>(tmp1, stats);
    gn_norm_tok_k<<<dim3(kB * kHW * kD / 256), 256, 0, stream>>>(
        tmp1, src, srcb, arena, stats, cg, cbe, posf, mod * kHW);
  }

  for (int l = 0; l < kNL; l++) {
    const float* owl  = off_w  + (size_t)l * kD * 128;
    const float* obl  = off_b  + (size_t)l * 128;
    const float* awl  = aw_w   + (size_t)l * kD * 64;
    const float* awbl = aw_b   + (size_t)l * 64;
    const float* vwl  = vp_w   + (size_t)l * kD * kD;
    const float* vbl  = vp_b   + (size_t)l * kD;
    const float* opwl = op_w   + (size_t)l * kD * kD;
    const float* opbl = op_b   + (size_t)l * kD;
    const float* l1g  = ln1_g  + (size_t)l * 2 * kD;
    const float* l1b  = ln1_b  + (size_t)l * 2 * kD;
    const float* f1w  = ffn1_w + (size_t)l * kD * kDff;
    const float* f1b  = ffn1_b + (size_t)l * kDff;
    const float* f2w  = ffn2_w + (size_t)l * kDff * kD;
    const float* f2b_ = ffn2_b + (size_t)l * kD;
    const float* l2g  = ln2_g  + (size_t)l * 2 * kD;
    const float* l2b  = ln2_b  + (size_t)l * 2 * kD;

    // all weight conversions for this layer (1 dispatch)
    cvt_layer_k<<<dim3(833), 256, 0, stream>>>(
        vwl, opwl, owl, awl, f1w, f2w, obl, awbl,
        wvp, wop, woaw, wf1, wf2, biasb);

    // value = srcb @ vp + vb -> tmp1 (f32)
    mgemm<0, false><<<dim3(4, 100), 256, 0, stream>>>(
        srcb, wvp, vbl, nullptr, tmp1, nullptr, 512, 512, 512);

    // offaw = qb @ [ow|aww] + [ob|awb] -> offaw (f32, 192-wide)
    mgemm<0, true><<<dim3(2, 100), 256, 0, stream>>>(
        arena /*qb*/, woaw, biasb, nullptr, offaw, nullptr, 512, 192, 192);

    // sampling -> sampb (arena, bf16 swz)
    sample_k<<<dim3(kB * kLen / 2), 256, 0, stream>>>(tmp1, offaw, arena);

    // y = src + sampb @ op + opb -> tmp1
    mgemm<2, false><<<dim3(4, 100), 256, 0, stream>>>(
        arena, wop, opbl, src, tmp1, nullptr, 512, 512, 512);

    // src = LN_spec(y)
    ln_spec_k<false><<<dim3(M), 256, 0, stream>>>(tmp1, src, srcb, nullptr, l1g, l1b, posf);

    // FFN in two M-halves; hidden (bf16 swz) lives in arena
    for (int hf = 0; hf < 2; hf++) {
      const size_t o = (size_t)hf * Mh * kD;
      mgemm<1, false><<<dim3(8, 50), 256, 0, stream>>>(
          srcb + o, wf1, f1b, nullptr, nullptr, arena, 512, 1024, 1024);
      mgemm<2, false><<<dim3(4, 50), 256, 0, stream>>>(
          arena, wf2, f2b_, src + o, tmp1 + o, nullptr, 1024, 512, 512);
    }

    // src = LN_spec(y); produce qb for next layer (not needed after last)
    if (l < kNL - 1)
      ln_spec_k<true><<<dim3(M), 256, 0, stream>>>(tmp1, src, srcb, arena, l2g, l2b, posf);
    else
      ln_spec_k<false><<<dim3(M), 256, 0, stream>>>(tmp1, src, srcb, nullptr, l2g, l2b, posf);
  }

  // out = GN(conv1x1(src_v + src_i))
  sumtok_k<<<dim3(kB * kHW * kD / 256), 256, 0, stream>>>(src, arena);
  cvtw_d_k<<<dim3(768 * 64 / 256), 256, 0, stream>>>(as_w, wf1, 512, 768);
  mgemm<3, false><<<dim3(6, 50), 256, 0, stream>>>(
      arena, wf1, as_b, nullptr, tmp1, nullptr, 512, 0, 768);
  gn_stats_ch_k<<<dim3(kB * 32), 256, 0, stream>>>(tmp1, stats);
  gn_norm_ch_k<<<dim3(kB * kCin * kHW / 256), 256, 0, stream>>>(
      tmp1, (float*)d_out, stats, as_g, as_be);
}

// Round 4
// 1376.622 us; speedup vs baseline: 4.0926x; 1.0636x over previous
//
#include <hip/hip_runtime.h>
#include <hip/hip_bf16.h>
#include <cstddef>
#include <math.h>

// ---------------------------------------------------------------------------
// Round 3: qb eliminated via posW = posf@[ow|aww] (precomputed once);
// value+offaw fused into one N=768 GEMM (EPI 4); f32 src mirror dropped
// (bf16 swizzled srcb is the canonical residual); wave-per-row LN; s8v
// vectorized GN-norm / token-sum.  GEMMs: bf16 MFMA 16x16x32, 128x128 tile,
// global_load_lds(16B), pre-swizzled operands.
// ---------------------------------------------------------------------------

constexpr int kB   = 16;
constexpr int kCin = 768;
constexpr int kHW  = 400;
constexpr int kWpx = 20;
constexpr int kHpx = 20;
constexpr int kD   = 512;
constexpr int kLen = 800;
constexpr int kDff = 1024;
constexpr int kNL  = 6;
constexpr float kEps = 1e-5f;

typedef __attribute__((ext_vector_type(8))) short s8v;
typedef __attribute__((ext_vector_type(4))) short s4v;
typedef __attribute__((ext_vector_type(4))) float f4v;

// k-group swizzle: within each 32-element k-group, rotate 8-element slots by
// (row>>1)&3.
__device__ __forceinline__ int swzk(int row, int k) {
  return (k & ~31) | ((((k >> 3) + (row >> 1)) & 3) << 3) | (k & 7);
}

__device__ __forceinline__ unsigned short f2b(float f) {
  union { __hip_bfloat16 h; unsigned short u; } cv;
  cv.h = __float2bfloat16(f);
  return cv.u;
}

__device__ __forceinline__ float b2f(unsigned short u) {
  return __uint_as_float(((unsigned)u) << 16);
}

__device__ __forceinline__ void gll(const unsigned short* g, unsigned short* l) {
  __builtin_amdgcn_global_load_lds(
      (const __attribute__((address_space(1))) unsigned int*)g,
      (__attribute__((address_space(3))) unsigned int*)l, 16, 0, 0);
}

// ------------------------------ block reduce -------------------------------
__device__ __forceinline__ void breduce2(float& s, float& s2, float* sh) {
#pragma unroll
  for (int o = 32; o > 0; o >>= 1) {
    s  += __shfl_down(s, o);
    s2 += __shfl_down(s2, o);
  }
  const int wid = threadIdx.x >> 6, lane = threadIdx.x & 63;
  if (lane == 0) { sh[wid] = s; sh[4 + wid] = s2; }
  __syncthreads();
  if (threadIdx.x == 0) {
    sh[0] = sh[0] + sh[1] + sh[2] + sh[3];
    sh[4] = sh[4] + sh[5] + sh[6] + sh[7];
  }
  __syncthreads();
  s = sh[0]; s2 = sh[4];
}

// ------------------------------- MFMA GEMM ---------------------------------
// EPI 0: f32 Cf[row*ldc+col] = acc+bias
// EPI 1: bf16 Cb[row*ldc + swzk] = relu(acc+bias)
// EPI 2: f32 Cf[row*ldc+col] = acc+bias + b2f(resb[row*ldc+swzk(row,col)])
// EPI 3: f32 Cf[((row/400)*Nreal + col)*400 + row%400] = acc+bias (conv)
// EPI 4: col<512: Cf[row*512+col]=acc+bias[col];
//        else c=col-512, c<192: Cf2[row*192+c]=acc+aux[(row%800)*1536+c]
template<int EPI>
__global__ __launch_bounds__(256)
void mgemm(const unsigned short* __restrict__ Abf,
           const unsigned short* __restrict__ Bw,
           const float* __restrict__ bias,
           const unsigned short* __restrict__ resb,
           float* __restrict__ Cf, float* __restrict__ Cf2,
           const float* __restrict__ aux,
           unsigned short* __restrict__ Cb,
           int K, int ldc, int Nreal)
{
  __shared__ unsigned short As[128 * 32];
  __shared__ unsigned short Bs[128 * 32];
  const int tid = threadIdx.x;
  const int w = tid >> 6, l = tid & 63;
  const int m0 = blockIdx.y * 128;
  const int n0 = blockIdx.x * 128;

  f4v acc[4][4] = {};

  const int srow = w * 32 + (l >> 2);
  const unsigned short* ga0 = Abf + (size_t)(m0 + srow) * K + (l & 3) * 8;
  const unsigned short* ga1 = ga0 + (size_t)16 * K;
  const unsigned short* gb0 = Bw + (size_t)(n0 + srow) * K + (l & 3) * 8;
  const unsigned short* gb1 = gb0 + (size_t)16 * K;
  unsigned short* la0 = &As[(w * 32) * 32];
  unsigned short* la1 = &As[(w * 32 + 16) * 32];
  unsigned short* lb0 = &Bs[(w * 32) * 32];
  unsigned short* lb1 = &Bs[(w * 32 + 16) * 32];

  int aoff[4], boff[4];
#pragma unroll
  for (int f = 0; f < 4; f++) {
    const int ra = (w >> 1) * 64 + f * 16 + (l & 15);
    aoff[f] = ra * 32 + ((((l >> 4) + (ra >> 1)) & 3) << 3);
    const int rb = (w & 1) * 64 + f * 16 + (l & 15);
    boff[f] = rb * 32 + ((((l >> 4) + (rb >> 1)) & 3) << 3);
  }

  for (int k0 = 0; k0 < K; k0 += 32) {
    gll(ga0 + k0, la0); gll(ga1 + k0, la1);
    gll(gb0 + k0, lb0); gll(gb1 + k0, lb1);
    __syncthreads();
    s8v af[4], bf[4];
#pragma unroll
    for (int f = 0; f < 4; f++) {
      af[f] = *(const s8v*)&As[aoff[f]];
      bf[f] = *(const s8v*)&Bs[boff[f]];
    }
#pragma unroll
    for (int i = 0; i < 4; i++)
#pragma unroll
      for (int j = 0; j < 4; j++)
        acc[i][j] = __builtin_amdgcn_mfma_f32_16x16x32_bf16(af[i], bf[j], acc[i][j], 0, 0, 0);
    __syncthreads();
  }

  // C/D layout: col=lane&15, row=(lane>>4)*4+reg
  const int colb = n0 + (w & 1) * 64;
  const int rowb = m0 + (w >> 1) * 64 + (l >> 4) * 4;
#pragma unroll
  for (int i = 0; i < 4; i++) {
#pragma unroll
    for (int j = 0; j < 4; j++) {
      const int col = colb + j * 16 + (l & 15);
      float bv;
      if (EPI == 4) bv = (col < kD) ? bias[col] : 0.0f;
      else          bv = bias[col];
#pragma unroll
      for (int r = 0; r < 4; r++) {
        const int row = rowb + i * 16 + r;
        float v = acc[i][j][r] + bv;
        if (EPI == 0) {
          Cf[(size_t)row * ldc + col] = v;
        } else if (EPI == 1) {
          v = fmaxf(v, 0.0f);
          Cb[(size_t)row * ldc + swzk(row, col)] = f2b(v);
        } else if (EPI == 2) {
          Cf[(size_t)row * ldc + col] = v + b2f(resb[(size_t)row * ldc + swzk(row, col)]);
        } else if (EPI == 3) {
          const int bb = row / kHW, p = row % kHW;
          Cf[((size_t)bb * Nreal + col) * kHW + p] = v;
        } else {  // EPI == 4: fused value | offaw
          if (col < kD) {
            Cf[(size_t)row * kD + col] = v;
          } else {
            const int c = col - kD;
            if (c < 192)
              Cf2[(size_t)row * 192 + c] = v + aux[(size_t)(row % kLen) * 1536 + c];
          }
        }
      }
    }
  }
}

// -------------------------- weight conversions -----------------------------
// one 8-elem k-group: W [K][N] f32 -> out row n (k-major, swizzled)
__device__ __forceinline__ void cvt8t(const float* __restrict__ W,
                                      unsigned short* __restrict__ out,
                                      int K, int N, int g, int rowoff)
{
  const int n = g % N;
  const int k = (g / N) * 8;
  s8v p;
#pragma unroll
  for (int j = 0; j < 8; j++) p[j] = (short)f2b(W[(size_t)(k + j) * N + n]);
  const int row = rowoff + n;
  const int base = row * K + (k & ~31) + ((((k >> 3) + (row >> 1)) & 3) << 3);
  *(s8v*)&out[base] = p;
}

// per-layer weight conversions, one dispatch (212,992 items -> 832 blocks)
__global__ __launch_bounds__(256)
void cvt_layer_k(const float* __restrict__ vw, const float* __restrict__ opw,
                 const float* __restrict__ ow, const float* __restrict__ aww,
                 const float* __restrict__ f1w, const float* __restrict__ f2w,
                 unsigned short* __restrict__ wcomb, unsigned short* __restrict__ wop,
                 unsigned short* __restrict__ wf1, unsigned short* __restrict__ wf2)
{
  int g = blockIdx.x * 256 + threadIdx.x;
  if (g < 32768) { cvt8t(vw, wcomb, 512, 512, g, 0); return; }
  g -= 32768;
  if (g < 16384) {                       // oaw -> wcomb rows 512..767
    const int n = g & 255;
    const int k = (g >> 8) * 8;
    s8v p;
#pragma unroll
    for (int j = 0; j < 8; j++) {
      float v = 0.0f;
      if (n < 128)      v = ow[(size_t)(k + j) * 128 + n];
      else if (n < 192) v = aww[(size_t)(k + j) * 64 + (n - 128)];
      p[j] = (short)f2b(v);
    }
    const int row = 512 + n;
    const int base = row * 512 + (k & ~31) + ((((k >> 3) + (row >> 1)) & 3) << 3);
    *(s8v*)&wcomb[base] = p;
    return;
  }
  g -= 16384;
  if (g < 32768) { cvt8t(opw, wop, 512, 512, g, 0); return; }
  g -= 32768;
  if (g < 65536) { cvt8t(f1w, wf1, 512, 1024, g, 0); return; }
  g -= 65536;
  cvt8t(f2w, wf2, 1024, 512, g, 0);
}

// upfront: all 6 layers' [ow|aww] -> woaw_all [6*256][512] bf16 swz + biasall
__global__ __launch_bounds__(256)
void cvt_pre_k(const float* __restrict__ off_w, const float* __restrict__ aw_w,
               const float* __restrict__ off_b, const float* __restrict__ aw_b,
               unsigned short* __restrict__ woaw_all, float* __restrict__ biasall)
{
  int g = blockIdx.x * 256 + threadIdx.x;     // < 99840
  if (g < 98304) {
    const int l = g >> 14;
    const int gg = g & 16383;
    const int n = gg & 255;
    const int k = (gg >> 8) * 8;
    const float* ow = off_w + (size_t)l * kD * 128;
    const float* aww = aw_w + (size_t)l * kD * 64;
    s8v p;
#pragma unroll
    for (int j = 0; j < 8; j++) {
      float v = 0.0f;
      if (n < 128)      v = ow[(size_t)(k + j) * 128 + n];
      else if (n < 192) v = aww[(size_t)(k + j) * 64 + (n - 128)];
      p[j] = (short)f2b(v);
    }
    const int row = l * 256 + n;   // rotation uses absolute row (l*256 ≡ 0 mod 4)
    const int base = row * 512 + (k & ~31) + ((((k >> 3) + (row >> 1)) & 3) << 3);
    *(s8v*)&woaw_all[base] = p;
    return;
  }
  g -= 98304;                                 // < 1536
  const int l = g >> 8, c = g & 255;
  float v = 0.0f;
  if (c < 128)      v = off_b[l * 128 + c];
  else if (c < 192) v = aw_b[l * 64 + (c - 128)];
  biasall[l * 256 + c] = v;
}

// W already [N][K] f32 -> bf16 swz (conv weights av/ai/as)
__global__ void cvtw_d_k(const float* __restrict__ W, unsigned short* __restrict__ out,
                         int K, int N)
{
  const int gid = blockIdx.x * 256 + threadIdx.x;   // N*(K/8)
  const int K8 = K >> 3;
  const int n  = gid / K8;
  const int k  = (gid % K8) * 8;
  s8v p;
#pragma unroll
  for (int j = 0; j < 8; j++) p[j] = (short)f2b(W[(size_t)n * K + k + j]);
  const int base = n * K + (k & ~31) + ((((k >> 3) + (n >> 1)) & 3) << 3);
  *(s8v*)&out[base] = p;
}

// ----------------- input transpose [B,768,400] -> bf16 swz [b*400+p][c] -----
__global__ void tin_k(const float* __restrict__ in, unsigned short* __restrict__ out)
{
  __shared__ float t[16][17];
  const int b = blockIdx.z, c0 = blockIdx.x * 16, p0 = blockIdx.y * 16;
  const int tx = threadIdx.x & 15, ty = threadIdx.x >> 4;
  t[ty][tx] = in[((size_t)b * kCin + c0 + ty) * kHW + p0 + tx];
  __syncthreads();
  const int row = b * kHW + p0 + ty;
  const int c = c0 + tx;
  out[(size_t)row * kCin + swzk(row, c)] = f2b(t[tx][ty]);
}

// ---------------- positional features -> bf16 swz [896][512] ----------------
__global__ void posfb_k(unsigned short* __restrict__ posfb,
                        const float* __restrict__ level_embed)
{
  const int gid = blockIdx.x * 256 + threadIdx.x;   // < 896*64
  const int d0 = (gid & 63) * 8;
  const int t  = gid >> 6;
  s8v o;
  if (t >= kLen) {
#pragma unroll
    for (int j = 0; j < 8; j++) o[j] = 0;
  } else {
    const int lvl = t / kHW;
    const int tt = t % kHW;
    const int yy = tt / kWpx, xx = tt % kWpx;
#pragma unroll
    for (int j = 0; j < 8; j++) {
      const int d = d0 + j;
      const int dd = d & 255;
      const float e = (d < 256) ? ((float)(yy + 1) * (6.283185307179586f / kHpx))
                                : ((float)(xx + 1) * (6.283185307179586f / kWpx));
      const float dimt = powf(10000.0f, (float)(dd >> 1) / 128.0f);
      const float pp = e / dimt;
      const float val = (dd & 1) ? cosf(pp) : sinf(pp);
      o[j] = (short)f2b(val + level_embed[lvl * kD + d]);
    }
  }
  *(s8v*)&posfb[(size_t)t * kD + swzk(t, d0)] = o;
}

// --------------------------- GroupNorm (token-major) ------------------------
__global__ __launch_bounds__(256)
void gn_stats_tok_k(const float* __restrict__ x, float* __restrict__ stats)
{
  __shared__ float sh[8];
  const int b = blockIdx.x >> 5;
  const int g = blockIdx.x & 31;
  const float* xb = x + (size_t)b * kHW * kD + g * 16;
  float s = 0.f, s2 = 0.f;
  for (int i = threadIdx.x; i < kHW * 16; i += 256) {
    const int p = i >> 4, j = i & 15;
    const float v = xb[(size_t)p * kD + j];
    s += v; s2 += v * v;
  }
  breduce2(s, s2, sh);
  if (threadIdx.x == 0) {
    const float mean = s / (kHW * 16.0f);
    const float var  = s2 / (kHW * 16.0f) - mean * mean;
    stats[blockIdx.x * 2]     = mean;
    stats[blockIdx.x * 2 + 1] = rsqrtf(var + kEps);
  }
}

__global__ void gn_norm_tok_k(const float* __restrict__ x,
                              unsigned short* __restrict__ srcb,
                              const float* __restrict__ stats,
                              const float* __restrict__ gam, const float* __restrict__ bet,
                              int tokoff)
{
  const int gid = blockIdx.x * 256 + threadIdx.x;   // < 16*400*64
  const int d0 = (gid & 63) * 8;
  const int rest = gid >> 6;
  const int b = rest / kHW, p = rest % kHW;
  const int g = d0 >> 4;
  const float mean = stats[(b * 32 + g) * 2];
  const float rstd = stats[(b * 32 + g) * 2 + 1];
  const float* xr = x + ((size_t)(b * kHW + p)) * kD + d0;
  const int row = b * kLen + tokoff + p;
  s8v o;
#pragma unroll
  for (int j = 0; j < 8; j++)
    o[j] = (short)f2b((xr[j] - mean) * rstd * gam[d0 + j] + bet[d0 + j]);
  *(s8v*)&srcb[(size_t)row * kD + swzk(row, d0)] = o;
}

// --------------------------- GroupNorm (chan-major) -------------------------
__global__ __launch_bounds__(256)
void gn_stats_ch_k(const float* __restrict__ x, float* __restrict__ stats)
{
  __shared__ float sh[8];
  const int b = blockIdx.x >> 5;
  const int g = blockIdx.x & 31;
  const float* xb = x + (size_t)b * kCin * kHW + (size_t)g * 24 * kHW;
  float s = 0.f, s2 = 0.f;
  for (int i = threadIdx.x; i < 24 * kHW; i += 256) {
    const float v = xb[i];
    s += v; s2 += v * v;
  }
  breduce2(s, s2, sh);
  if (threadIdx.x == 0) {
    const float mean = s / (24.0f * kHW);
    const float var  = s2 / (24.0f * kHW) - mean * mean;
    stats[blockIdx.x * 2]     = mean;
    stats[blockIdx.x * 2 + 1] = rsqrtf(var + kEps);
  }
}

__global__ void gn_norm_ch_k(const float* __restrict__ x, float* __restrict__ out,
                             const float* __restrict__ stats,
                             const float* __restrict__ gam, const float* __restrict__ bet)
{
  const int idx = blockIdx.x * 256 + threadIdx.x;   // < 16*768*400
  const int rest = idx / kHW;
  const int c = rest % kCin;
  const int b = rest / kCin;
  const int g = c / 24;
  const float mean = stats[(b * 32 + g) * 2];
  const float rstd = stats[(b * 32 + g) * 2 + 1];
  out[idx] = (x[idx] - mean) * rstd * gam[c] + bet[c];
}

// ------------------ modality-specific LayerNorm (wave/row) ------------------
__global__ __launch_bounds__(256)
void ln4_k(const float* __restrict__ x, unsigned short* __restrict__ outb,
           const float* __restrict__ gamma, const float* __restrict__ beta)
{
  const int row = blockIdx.x * 4 + (threadIdx.x >> 6);
  const int l = threadIdx.x & 63;
  const int t = row % kLen;
  const int mod = (t < kHW) ? 0 : 1;
  const float* xr = x + (size_t)row * kD + l * 8;
  float v[8];
  const float4 a = *(const float4*)xr;
  const float4 bq = *(const float4*)(xr + 4);
  v[0] = a.x; v[1] = a.y; v[2] = a.z; v[3] = a.w;
  v[4] = bq.x; v[5] = bq.y; v[6] = bq.z; v[7] = bq.w;
  float s = 0.f, s2 = 0.f;
#pragma unroll
  for (int j = 0; j < 8; j++) { s += v[j]; s2 += v[j] * v[j]; }
#pragma unroll
  for (int o = 32; o > 0; o >>= 1) {
    s  += __shfl_xor(s, o);
    s2 += __shfl_xor(s2, o);
  }
  const float mean = s * (1.0f / kD);
  const float var  = s2 * (1.0f / kD) - mean * mean;
  const float rstd = rsqrtf(var + kEps);
  const float* g  = gamma + mod * kD + l * 8;
  const float* be = beta  + mod * kD + l * 8;
  s8v o8;
#pragma unroll
  for (int j = 0; j < 8; j++)
    o8[j] = (short)f2b((v[j] - mean) * rstd * g[j] + be[j]);
  *(s8v*)&outb[(size_t)row * kD + swzk(row, l * 8)] = o8;
}

// ------------------- deformable sampling (softmax + bilinear) ---------------
__global__ __launch_bounds__(256)
void sample_k(const float* __restrict__ value, const float* __restrict__ offaw,
              unsigned short* __restrict__ out)
{
  __shared__ float wls[2][64][8];   // [tok][combo][w0,i0,...,w3,i3]
  const int tid = threadIdx.x;
  const int tok = tid >> 7;
  const int wt  = tid & 127;
  const int token = blockIdx.x * 2 + tok;       // < 12800
  const int b = token / kLen;
  const int t = token % kLen;
  const int tt = t % kHW;

  if (wt < 64) {
    const int h = wt >> 3, lp = wt & 7, lvl = lp >> 2, p = lp & 3;
    const float* oa = offaw + (size_t)token * 192;
    const float lg = oa[128 + h * 8 + lp];
    float mx = lg;
#pragma unroll
    for (int msk = 1; msk < 8; msk <<= 1) mx = fmaxf(mx, __shfl_xor(mx, msk));
    const float ex = __expf(lg - mx);
    float ssum = ex;
#pragma unroll
    for (int msk = 1; msk < 8; msk <<= 1) ssum += __shfl_xor(ssum, msk);
    const float aw = ex / ssum;

    const float x = (float)(tt % kWpx) + oa[h * 16 + lvl * 8 + p * 2];
    const float y = (float)(tt / kWpx) + oa[h * 16 + lvl * 8 + p * 2 + 1];
    const float x0f = floorf(x), y0f = floorf(y);
    const float wx = x - x0f, wy = y - y0f;
    const int x0 = (int)x0f, y0 = (int)y0f;
    const int rowbase = b * kLen + lvl * kHW;
#pragma unroll
    for (int dy = 0; dy < 2; dy++) {
#pragma unroll
      for (int dx = 0; dx < 2; dx++) {
        const int ix = x0 + dx, iy = y0 + dy;
        const bool valid = (ix >= 0) & (ix < kWpx) & (iy >= 0) & (iy < kHpx);
        const float cw = (dx ? wx : 1.0f - wx) * (dy ? wy : 1.0f - wy);
        const float w = valid ? aw * cw : 0.0f;
        const int ixc = min(max(ix, 0), kWpx - 1);
        const int iyc = min(max(iy, 0), kHpx - 1);
        const int r = rowbase + iyc * kWpx + ixc;
        const int cn = dy * 2 + dx;
        wls[tok][wt][cn * 2]     = w;
        wls[tok][wt][cn * 2 + 1] = __int_as_float(r);
      }
    }
  }
  __syncthreads();

  const int c0 = wt * 4;
  const int h = wt >> 4;
  float acc0 = 0.f, acc1 = 0.f, acc2 = 0.f, acc3 = 0.f;
  const float* vb = value + c0;
#pragma unroll
  for (int pp = 0; pp < 8; pp++) {
    const float* wl = wls[tok][h * 8 + pp];
#pragma unroll
    for (int cn = 0; cn < 4; cn++) {
      const float w = wl[cn * 2];
      const int r = __float_as_int(wl[cn * 2 + 1]);
      const float4 v = *(const float4*)(vb + (size_t)r * kD);
      acc0 += w * v.x; acc1 += w * v.y; acc2 += w * v.z; acc3 += w * v.w;
    }
  }
  const int sk = swzk(token, c0);
  s4v o;
  o[0] = (short)f2b(acc0); o[1] = (short)f2b(acc1);
  o[2] = (short)f2b(acc2); o[3] = (short)f2b(acc3);
  *(s4v*)&out[(size_t)token * kD + sk] = o;
}

// ---------------- token-sum (bf16 srcb halves -> bf16 swz tokb) -------------
__global__ void sumtok_k(const unsigned short* __restrict__ srcb,
                         unsigned short* __restrict__ tokb)
{
  const int gid = blockIdx.x * 256 + threadIdx.x;   // < 16*400*64
  const int d0 = (gid & 63) * 8;
  const int rest = gid >> 6;
  const int b = rest / kHW, p = rest % kHW;
  const int r1 = b * kLen + p;
  const int r2 = r1 + kHW;
  const int ro = b * kHW + p;
  const s8v u1 = *(const s8v*)&srcb[(size_t)r1 * kD + swzk(r1, d0)];
  const s8v u2 = *(const s8v*)&srcb[(size_t)r2 * kD + swzk(r2, d0)];
  s8v o;
#pragma unroll
  for (int j = 0; j < 8; j++)
    o[j] = (short)f2b(b2f((unsigned short)u1[j]) + b2f((unsigned short)u2[j]));
  *(s8v*)&tokb[(size_t)ro * kD + swzk(ro, d0)] = o;
}

// ------------------------------- launcher -----------------------------------
extern "C" void kernel_launch(void* const* d_in, const int* in_sizes, int n_in,
                              void* d_out, int out_size, void* d_ws, size_t ws_size,
                              hipStream_t stream)
{
  const float* input_v     = (const float*)d_in[0];
  const float* input_i     = (const float*)d_in[1];
  const float* av_w        = (const float*)d_in[2];
  const float* av_b        = (const float*)d_in[3];
  const float* av_g        = (const float*)d_in[4];
  const float* av_be       = (const float*)d_in[5];
  const float* ai_w        = (const float*)d_in[6];
  const float* ai_b        = (const float*)d_in[7];
  const float* ai_g        = (const float*)d_in[8];
  const float* ai_be       = (const float*)d_in[9];
  const float* level_embed = (const float*)d_in[10];
  const float* off_w       = (const float*)d_in[11];
  const float* off_b       = (const float*)d_in[12];
  const float* aw_w        = (const float*)d_in[13];
  const float* aw_b        = (const float*)d_in[14];
  const float* vp_w        = (const float*)d_in[15];
  const float* vp_b        = (const float*)d_in[16];
  const float* op_w        = (const float*)d_in[17];
  const float* op_b        = (const float*)d_in[18];
  const float* ln1_g       = (const float*)d_in[19];
  const float* ln1_b       = (const float*)d_in[20];
  const float* ffn1_w      = (const float*)d_in[21];
  const float* ffn1_b      = (const float*)d_in[22];
  const float* ffn2_w      = (const float*)d_in[23];
  const float* ffn2_b      = (const float*)d_in[24];
  const float* ln2_g       = (const float*)d_in[25];
  const float* ln2_b       = (const float*)d_in[26];
  const float* as_w        = (const float*)d_in[27];
  const float* as_b        = (const float*)d_in[28];
  const float* as_g        = (const float*)d_in[29];
  const float* as_be       = (const float*)d_in[30];

  // ------- workspace layout -------
  float* wsf    = (float*)d_ws;
  float* tmp1   = wsf;                                   // 6,553,600 f
  float* offaw  = tmp1   + (size_t)6553600;              // 2,457,600 f
  float* posW   = offaw  + (size_t)2457600;              // 1,376,256 f (896x1536)
  float* biasall= posW   + (size_t)1376256;              //     1,536 f
  float* stats  = biasall+ (size_t)1536;                 //     1,024 f
  unsigned short* srcb     = (unsigned short*)(stats + 1024);   // 6,553,600 sh
  unsigned short* arena    = srcb     + (size_t)6553600;        // 6,553,600 sh
  unsigned short* wcomb    = arena    + (size_t)6553600;        //   393,216 sh
  unsigned short* wop      = wcomb    + (size_t)393216;         //   262,144 sh
  unsigned short* wf1      = wop      + (size_t)262144;         //   524,288 sh
  unsigned short* wf2      = wf1      + (size_t)524288;         //   524,288 sh
  unsigned short* woaw_all = wf2      + (size_t)524288;         //   786,432 sh
  unsigned short* posfb    = woaw_all + (size_t)786432;         //   458,752 sh
  // inb aliases tmp1 tail (conv GEMM writes only first 3,276,800 floats)
  unsigned short* inb      = (unsigned short*)(tmp1 + 3276800);

  const int M  = kB * kLen;   // 12800
  const int Mh = kB * kHW;    // 6400

  // ---- pre: positional features, oaw weights, posW = posfb @ [ow|aww]+b ----
  posfb_k<<<dim3(896 * 64 / 256), 256, 0, stream>>>(posfb, level_embed);
  cvt_pre_k<<<dim3(390), 256, 0, stream>>>(off_w, aw_w, off_b, aw_b,
                                           woaw_all, biasall);
  mgemm<0><<<dim3(12, 7), 256, 0, stream>>>(
      posfb, woaw_all, biasall, nullptr, posW, nullptr, nullptr, nullptr,
      512, 1536, 1536);

  // ---- input convs + GN -> srcb ----
  for (int mod = 0; mod < 2; mod++) {
    const float* in  = mod ? input_i : input_v;
    const float* cw  = mod ? ai_w  : av_w;
    const float* cb  = mod ? ai_b  : av_b;
    const float* cg  = mod ? ai_g  : av_g;
    const float* cbe = mod ? ai_be : av_be;
    tin_k<<<dim3(48, 25, 16), 256, 0, stream>>>(in, inb);
    cvtw_d_k<<<dim3(512 * 96 / 256), 256, 0, stream>>>(cw, wf1, 768, 512);
    mgemm<0><<<dim3(4, 50), 256, 0, stream>>>(
        inb, wf1, cb, nullptr, tmp1, nullptr, nullptr, nullptr, 768, 512, 512);
    gn_stats_tok_k<<<dim3(kB * 32), 256, 0, stream>>>(tmp1, stats);
    gn_norm_tok_k<<<dim3(kB * kHW * 64 / 256), 256, 0, stream>>>(
        tmp1, srcb, stats, cg, cbe, mod * kHW);
  }

  for (int l = 0; l < kNL; l++) {
    const float* vbl  = vp_b   + (size_t)l * kD;
    const float* opbl = op_b   + (size_t)l * kD;
    const float* l1g  = ln1_g  + (size_t)l * 2 * kD;
    const float* l1b  = ln1_b  + (size_t)l * 2 * kD;
    const float* f1b  = ffn1_b + (size_t)l * kDff;
    const float* f2b_ = ffn2_b + (size_t)l * kD;
    const float* l2g  = ln2_g  + (size_t)l * 2 * kD;
    const float* l2b  = ln2_b  + (size_t)l * 2 * kD;

    cvt_layer_k<<<dim3(832), 256, 0, stream>>>(
        vp_w + (size_t)l * kD * kD, op_w + (size_t)l * kD * kD,
        off_w + (size_t)l * kD * 128, aw_w + (size_t)l * kD * 64,
        ffn1_w + (size_t)l * kD * kDff, ffn2_w + (size_t)l * kDff * kD,
        wcomb, wop, wf1, wf2);

    // fused: value (cols 0..511 -> tmp1 f32) | offaw (cols 512..703 -> offaw)
    mgemm<4><<<dim3(6, 100), 256, 0, stream>>>(
        srcb, wcomb, vbl, nullptr, tmp1, offaw, posW + (size_t)l * 256, nullptr,
        512, 512, 0);

    // sampling -> arena (bf16 swz)
    sample_k<<<dim3(M / 2), 256, 0, stream>>>(tmp1, offaw, arena);

    // y = bf16(src) + samp @ op + opb -> tmp1 (f32)
    mgemm<2><<<dim3(4, 100), 256, 0, stream>>>(
        arena, wop, opbl, srcb, tmp1, nullptr, nullptr, nullptr, 512, 512, 0);

    // srcb = LN_spec(y)
    ln4_k<<<dim3(M / 4), 256, 0, stream>>>(tmp1, srcb, l1g, l1b);

    // FFN in two M-halves; hidden (bf16 swz) lives in arena
    for (int hf = 0; hf < 2; hf++) {
      const size_t o = (size_t)hf * Mh * kD;
      mgemm<1><<<dim3(8, 50), 256, 0, stream>>>(
          srcb + o, wf1, f1b, nullptr, nullptr, nullptr, nullptr, arena,
          512, 1024, 0);
      mgemm<2><<<dim3(4, 50), 256, 0, stream>>>(
          arena, wf2, f2b_, srcb + o, tmp1 + o, nullptr, nullptr, nullptr,
          1024, 512, 0);
    }

    // srcb = LN_spec(y)
    ln4_k<<<dim3(M / 4), 256, 0, stream>>>(tmp1, srcb, l2g, l2b);
  }

  // out = GN(conv1x1(src_v + src_i))
  sumtok_k<<<dim3(kB * kHW * 64 / 256), 256, 0, stream>>>(srcb, arena);
  cvtw_d_k<<<dim3(768 * 64 / 256), 256, 0, stream>>>(as_w, wf1, 512, 768);
  mgemm<3><<<dim3(6, 50), 256, 0, stream>>>(
      arena, wf1, as_b, nullptr, tmp1, nullptr, nullptr, nullptr, 512, 0, 768);
  gn_stats_ch_k<<<dim3(kB * 32), 256, 0, stream>>>(tmp1, stats);
  gn_norm_ch_k<<<dim3(kB * kCin * kHW / 256), 256, 0, stream>>>(
      tmp1, (float*)d_out, stats, as_g, as_be);
}

// Round 5
// 1116.880 us; speedup vs baseline: 5.0444x; 1.2326x over previous
//
#include <hip/hip_runtime.h>
#include <hip/hip_bf16.h>
#include <cstddef>
#include <math.h>

// ---------------------------------------------------------------------------
// Round 4: value & pre-LN activations in bf16 (halved traffic); FFN halves
// merged; all per-layer weight conversions in ONE upfront dispatch; mgemm
// double-buffered prefetch (1 barrier/K-step, loads overlap MFMA).
// ---------------------------------------------------------------------------

constexpr int kB   = 16;
constexpr int kCin = 768;
constexpr int kHW  = 400;
constexpr int kWpx = 20;
constexpr int kHpx = 20;
constexpr int kD   = 512;
constexpr int kLen = 800;
constexpr int kDff = 1024;
constexpr int kNL  = 6;
constexpr float kEps = 1e-5f;

typedef __attribute__((ext_vector_type(8))) short s8v;
typedef __attribute__((ext_vector_type(4))) short s4v;
typedef __attribute__((ext_vector_type(4))) float f4v;

__device__ __forceinline__ int swzk(int row, int k) {
  return (k & ~31) | ((((k >> 3) + (row >> 1)) & 3) << 3) | (k & 7);
}

__device__ __forceinline__ unsigned short f2b(float f) {
  union { __hip_bfloat16 h; unsigned short u; } cv;
  cv.h = __float2bfloat16(f);
  return cv.u;
}

__device__ __forceinline__ float b2f(unsigned short u) {
  return __uint_as_float(((unsigned)u) << 16);
}

__device__ __forceinline__ void gll(const unsigned short* g, unsigned short* l) {
  __builtin_amdgcn_global_load_lds(
      (const __attribute__((address_space(1))) unsigned int*)g,
      (__attribute__((address_space(3))) unsigned int*)l, 16, 0, 0);
}

// ------------------------------ block reduce -------------------------------
__device__ __forceinline__ void breduce2(float& s, float& s2, float* sh) {
#pragma unroll
  for (int o = 32; o > 0; o >>= 1) {
    s  += __shfl_down(s, o);
    s2 += __shfl_down(s2, o);
  }
  const int wid = threadIdx.x >> 6, lane = threadIdx.x & 63;
  if (lane == 0) { sh[wid] = s; sh[4 + wid] = s2; }
  __syncthreads();
  if (threadIdx.x == 0) {
    sh[0] = sh[0] + sh[1] + sh[2] + sh[3];
    sh[4] = sh[4] + sh[5] + sh[6] + sh[7];
  }
  __syncthreads();
  s = sh[0]; s2 = sh[4];
}

// ------------------------------- MFMA GEMM ---------------------------------
// Double-buffered: stage tile t+1 while computing tile t; 1 barrier/K-step.
// EPI 0: f32 Cf[row*ldc+col] = acc+bias
// EPI 1: bf16 Cb[row*ldc + swzk] = relu(acc+bias)            (ffn hidden)
// EPI 2: bf16 Cb[row*512+col] = acc+bias + res(srcb swz)     (pre-LN y)
// EPI 3: f32 Cf[((row/400)*Nreal+col)*400 + row%400] = acc+bias (conv out)
// EPI 4: col<512 -> bf16 Cb[row*512+col] (value, plain);
//        col in [512,704) -> f32 Cf2[row*192+c] = acc + posWc[t*192+c]
// EPI 5: posWc writer: Cf[((col>>8)*800 + row)*192 + (col&255)] = acc+bias
template<int EPI>
__global__ __launch_bounds__(256)
void mgemm(const unsigned short* __restrict__ Abf,
           const unsigned short* __restrict__ Bw,
           const float* __restrict__ bias,
           const unsigned short* __restrict__ resb,
           float* __restrict__ Cf, float* __restrict__ Cf2,
           const float* __restrict__ aux,
           unsigned short* __restrict__ Cb,
           int K, int ldc, int Nreal)
{
  __shared__ unsigned short As[2][4096];
  __shared__ unsigned short Bs[2][4096];
  const int tid = threadIdx.x;
  const int w = tid >> 6, l = tid & 63;
  const int m0 = blockIdx.y * 128;
  const int n0 = blockIdx.x * 128;

  f4v acc[4][4] = {};

  const int srow = w * 32 + (l >> 2);
  const unsigned short* ga0 = Abf + (size_t)(m0 + srow) * K + (l & 3) * 8;
  const unsigned short* ga1 = ga0 + (size_t)16 * K;
  const unsigned short* gb0 = Bw + (size_t)(n0 + srow) * K + (l & 3) * 8;
  const unsigned short* gb1 = gb0 + (size_t)16 * K;
  const int lb0 = (w * 32) * 32;
  const int lb1 = (w * 32 + 16) * 32;

  int aoff[4], boff[4];
#pragma unroll
  for (int f = 0; f < 4; f++) {
    const int ra = (w >> 1) * 64 + f * 16 + (l & 15);
    aoff[f] = ra * 32 + ((((l >> 4) + (ra >> 1)) & 3) << 3);
    const int rb = (w & 1) * 64 + f * 16 + (l & 15);
    boff[f] = rb * 32 + ((((l >> 4) + (rb >> 1)) & 3) << 3);
  }

  const int NT = K >> 5;
  // prologue: stage tile 0 into buffer 0
  gll(ga0, &As[0][lb0]); gll(ga1, &As[0][lb1]);
  gll(gb0, &Bs[0][lb0]); gll(gb1, &Bs[0][lb1]);
  __syncthreads();

  for (int t = 0; t < NT; ++t) {
    const int cur = t & 1;
    if (t + 1 < NT) {
      const int ko = (t + 1) * 32;
      const int nb = cur ^ 1;
      gll(ga0 + ko, &As[nb][lb0]); gll(ga1 + ko, &As[nb][lb1]);
      gll(gb0 + ko, &Bs[nb][lb0]); gll(gb1 + ko, &Bs[nb][lb1]);
    }
    s8v af[4], bf4[4];
#pragma unroll
    for (int f = 0; f < 4; f++) {
      af[f]  = *(const s8v*)&As[cur][aoff[f]];
      bf4[f] = *(const s8v*)&Bs[cur][boff[f]];
    }
#pragma unroll
    for (int i = 0; i < 4; i++)
#pragma unroll
      for (int j = 0; j < 4; j++)
        acc[i][j] = __builtin_amdgcn_mfma_f32_16x16x32_bf16(af[i], bf4[j], acc[i][j], 0, 0, 0);
    __syncthreads();   // drains vmcnt (next buffer staged) + lgkm (reads done)
  }

  // C/D layout: col=lane&15, row=(lane>>4)*4+reg
  const int colb = n0 + (w & 1) * 64;
  const int rowb = m0 + (w >> 1) * 64 + (l >> 4) * 4;
#pragma unroll
  for (int i = 0; i < 4; i++) {
#pragma unroll
    for (int j = 0; j < 4; j++) {
      const int col = colb + j * 16 + (l & 15);
      float bv;
      if (EPI == 4) bv = (col < kD) ? bias[col] : 0.0f;
      else          bv = bias[col];
#pragma unroll
      for (int r = 0; r < 4; r++) {
        const int row = rowb + i * 16 + r;
        float v = acc[i][j][r] + bv;
        if (EPI == 0) {
          Cf[(size_t)row * ldc + col] = v;
        } else if (EPI == 1) {
          Cb[(size_t)row * ldc + swzk(row, col)] = f2b(fmaxf(v, 0.0f));
        } else if (EPI == 2) {
          v += b2f(resb[(size_t)row * kD + swzk(row, col)]);
          Cb[(size_t)row * kD + col] = f2b(v);
        } else if (EPI == 3) {
          const int bb = row / kHW, p = row % kHW;
          Cf[((size_t)bb * Nreal + col) * kHW + p] = v;
        } else if (EPI == 4) {
          if (col < kD) {
            Cb[(size_t)row * kD + col] = f2b(v);
          } else {
            const int c = col - kD;
            if (c < 192)
              Cf2[(size_t)row * 192 + c] = v + aux[(size_t)(row % kLen) * 192 + c];
          }
        } else {  // EPI == 5
          if (row < kLen) {
            const int ll = col >> 8, c = col & 255;
            if (c < 192)
              Cf[(((size_t)ll * kLen) + row) * 192 + c] = v;
          }
        }
      }
    }
  }
}

// -------------------------- weight conversions -----------------------------
__device__ __forceinline__ void cvt8t(const float* __restrict__ W,
                                      unsigned short* __restrict__ out,
                                      int K, int N, int g)
{
  const int n = g % N;
  const int k = (g / N) * 8;
  s8v p;
#pragma unroll
  for (int j = 0; j < 8; j++) p[j] = (short)f2b(W[(size_t)(k + j) * N + n]);
  const int base = n * K + (k & ~31) + ((((k >> 3) + (n >> 1)) & 3) << 3);
  *(s8v*)&out[base] = p;
}

// ALL 6 layers' weights in one dispatch: 6 x 212,992 items, 4992 blocks.
__global__ __launch_bounds__(256)
void cvt_all_k(const float* __restrict__ vp_w, const float* __restrict__ op_w,
               const float* __restrict__ off_w, const float* __restrict__ aw_w,
               const float* __restrict__ f1w_a, const float* __restrict__ f2w_a,
               unsigned short* __restrict__ wall)
{
  const int lyr = blockIdx.x / 832;
  int g = (blockIdx.x % 832) * 256 + threadIdx.x;
  unsigned short* wl = wall + (size_t)lyr * 1703936;
  if (g < 32768) { cvt8t(vp_w + (size_t)lyr * kD * kD, wl, 512, 512, g); return; }
  g -= 32768;
  if (g < 16384) {                       // [ow|aww] -> wcomb rows 512..767
    const int n = g & 255;
    const int k = (g >> 8) * 8;
    const float* ow  = off_w + (size_t)lyr * kD * 128;
    const float* aww = aw_w  + (size_t)lyr * kD * 64;
    s8v p;
#pragma unroll
    for (int j = 0; j < 8; j++) {
      float v = 0.0f;
      if (n < 128)      v = ow[(size_t)(k + j) * 128 + n];
      else if (n < 192) v = aww[(size_t)(k + j) * 64 + (n - 128)];
      p[j] = (short)f2b(v);
    }
    const int row = 512 + n;
    const int base = row * 512 + (k & ~31) + ((((k >> 3) + (row >> 1)) & 3) << 3);
    *(s8v*)&wl[base] = p;
    return;
  }
  g -= 16384;
  if (g < 32768) { cvt8t(op_w + (size_t)lyr * kD * kD, wl + 393216, 512, 512, g); return; }
  g -= 32768;
  if (g < 65536) { cvt8t(f1w_a + (size_t)lyr * kD * kDff, wl + 655360, 512, 1024, g); return; }
  g -= 65536;
  cvt8t(f2w_a + (size_t)lyr * kDff * kD, wl + 1179648, 1024, 512, g);
}

// upfront: all 6 layers' [ow|aww] -> woaw_all [6*256][512] swz + biasall
__global__ __launch_bounds__(256)
void cvt_pre_k(const float* __restrict__ off_w, const float* __restrict__ aw_w,
               const float* __restrict__ off_b, const float* __restrict__ aw_b,
               unsigned short* __restrict__ woaw_all, float* __restrict__ biasall)
{
  int g = blockIdx.x * 256 + threadIdx.x;     // < 99840
  if (g < 98304) {
    const int l = g >> 14;
    const int gg = g & 16383;
    const int n = gg & 255;
    const int k = (gg >> 8) * 8;
    const float* ow = off_w + (size_t)l * kD * 128;
    const float* aww = aw_w + (size_t)l * kD * 64;
    s8v p;
#pragma unroll
    for (int j = 0; j < 8; j++) {
      float v = 0.0f;
      if (n < 128)      v = ow[(size_t)(k + j) * 128 + n];
      else if (n < 192) v = aww[(size_t)(k + j) * 64 + (n - 128)];
      p[j] = (short)f2b(v);
    }
    const int row = l * 256 + n;
    const int base = row * 512 + (k & ~31) + ((((k >> 3) + (row >> 1)) & 3) << 3);
    *(s8v*)&woaw_all[base] = p;
    return;
  }
  g -= 98304;                                 // < 1536
  const int l = g >> 8, c = g & 255;
  float v = 0.0f;
  if (c < 128)      v = off_b[l * 128 + c];
  else if (c < 192) v = aw_b[l * 64 + (c - 128)];
  biasall[l * 256 + c] = v;
}

// W already [N][K] f32 -> bf16 swz (conv weights av/ai/as)
__global__ void cvtw_d_k(const float* __restrict__ W, unsigned short* __restrict__ out,
                         int K, int N)
{
  const int gid = blockIdx.x * 256 + threadIdx.x;   // N*(K/8)
  const int K8 = K >> 3;
  const int n  = gid / K8;
  const int k  = (gid % K8) * 8;
  s8v p;
#pragma unroll
  for (int j = 0; j < 8; j++) p[j] = (short)f2b(W[(size_t)n * K + k + j]);
  const int base = n * K + (k & ~31) + ((((k >> 3) + (n >> 1)) & 3) << 3);
  *(s8v*)&out[base] = p;
}

// ----------------- input transpose [B,768,400] -> bf16 swz ------------------
__global__ void tin_k(const float* __restrict__ in, unsigned short* __restrict__ out)
{
  __shared__ float t[16][17];
  const int b = blockIdx.z, c0 = blockIdx.x * 16, p0 = blockIdx.y * 16;
  const int tx = threadIdx.x & 15, ty = threadIdx.x >> 4;
  t[ty][tx] = in[((size_t)b * kCin + c0 + ty) * kHW + p0 + tx];
  __syncthreads();
  const int row = b * kHW + p0 + ty;
  const int c = c0 + tx;
  out[(size_t)row * kCin + swzk(row, c)] = f2b(t[tx][ty]);
}

// ---------------- positional features -> bf16 swz [896][512] ----------------
__global__ void posfb_k(unsigned short* __restrict__ posfb,
                        const float* __restrict__ level_embed)
{
  const int gid = blockIdx.x * 256 + threadIdx.x;   // < 896*64
  const int d0 = (gid & 63) * 8;
  const int t  = gid >> 6;
  s8v o;
  if (t >= kLen) {
#pragma unroll
    for (int j = 0; j < 8; j++) o[j] = 0;
  } else {
    const int lvl = t / kHW;
    const int tt = t % kHW;
    const int yy = tt / kWpx, xx = tt % kWpx;
#pragma unroll
    for (int j = 0; j < 8; j++) {
      const int d = d0 + j;
      const int dd = d & 255;
      const float e = (d < 256) ? ((float)(yy + 1) * (6.283185307179586f / kHpx))
                                : ((float)(xx + 1) * (6.283185307179586f / kWpx));
      const float dimt = powf(10000.0f, (float)(dd >> 1) / 128.0f);
      const float pp = e / dimt;
      const float val = (dd & 1) ? cosf(pp) : sinf(pp);
      o[j] = (short)f2b(val + level_embed[lvl * kD + d]);
    }
  }
  *(s8v*)&posfb[(size_t)t * kD + swzk(t, d0)] = o;
}

// --------------------------- GroupNorm (token-major) ------------------------
__global__ __launch_bounds__(256)
void gn_stats_tok_k(const float* __restrict__ x, float* __restrict__ stats)
{
  __shared__ float sh[8];
  const int b = blockIdx.x >> 5;
  const int g = blockIdx.x & 31;
  const float* xb = x + (size_t)b * kHW * kD + g * 16;
  float s = 0.f, s2 = 0.f;
  for (int i = threadIdx.x; i < kHW * 16; i += 256) {
    const int p = i >> 4, j = i & 15;
    const float v = xb[(size_t)p * kD + j];
    s += v; s2 += v * v;
  }
  breduce2(s, s2, sh);
  if (threadIdx.x == 0) {
    const float mean = s / (kHW * 16.0f);
    const float var  = s2 / (kHW * 16.0f) - mean * mean;
    stats[blockIdx.x * 2]     = mean;
    stats[blockIdx.x * 2 + 1] = rsqrtf(var + kEps);
  }
}

__global__ void gn_norm_tok_k(const float* __restrict__ x,
                              unsigned short* __restrict__ srcb,
                              const float* __restrict__ stats,
                              const float* __restrict__ gam, const float* __restrict__ bet,
                              int tokoff)
{
  const int gid = blockIdx.x * 256 + threadIdx.x;   // < 16*400*64
  const int d0 = (gid & 63) * 8;
  const int rest = gid >> 6;
  const int b = rest / kHW, p = rest % kHW;
  const int g = d0 >> 4;
  const float mean = stats[(b * 32 + g) * 2];
  const float rstd = stats[(b * 32 + g) * 2 + 1];
  const float* xr = x + ((size_t)(b * kHW + p)) * kD + d0;
  const int row = b * kLen + tokoff + p;
  s8v o;
#pragma unroll
  for (int j = 0; j < 8; j++)
    o[j] = (short)f2b((xr[j] - mean) * rstd * gam[d0 + j] + bet[d0 + j]);
  *(s8v*)&srcb[(size_t)row * kD + swzk(row, d0)] = o;
}

// --------------------------- GroupNorm (chan-major) -------------------------
__global__ __launch_bounds__(256)
void gn_stats_ch_k(const float* __restrict__ x, float* __restrict__ stats)
{
  __shared__ float sh[8];
  const int b = blockIdx.x >> 5;
  const int g = blockIdx.x & 31;
  const float* xb = x + (size_t)b * kCin * kHW + (size_t)g * 24 * kHW;
  float s = 0.f, s2 = 0.f;
  for (int i = threadIdx.x; i < 24 * kHW; i += 256) {
    const float v = xb[i];
    s += v; s2 += v * v;
  }
  breduce2(s, s2, sh);
  if (threadIdx.x == 0) {
    const float mean = s / (24.0f * kHW);
    const float var  = s2 / (24.0f * kHW) - mean * mean;
    stats[blockIdx.x * 2]     = mean;
    stats[blockIdx.x * 2 + 1] = rsqrtf(var + kEps);
  }
}

__global__ void gn_norm_ch_k(const float* __restrict__ x, float* __restrict__ out,
                             const float* __restrict__ stats,
                             const float* __restrict__ gam, const float* __restrict__ bet)
{
  const int idx = blockIdx.x * 256 + threadIdx.x;   // < 16*768*400
  const int rest = idx / kHW;
  const int c = rest % kCin;
  const int b = rest / kCin;
  const int g = c / 24;
  const float mean = stats[(b * 32 + g) * 2];
  const float rstd = stats[(b * 32 + g) * 2 + 1];
  out[idx] = (x[idx] - mean) * rstd * gam[c] + bet[c];
}

// ------------- modality-specific LayerNorm (wave/row, bf16 in) --------------
__global__ __launch_bounds__(256)
void ln4_k(const unsigned short* __restrict__ x, unsigned short* __restrict__ outb,
           const float* __restrict__ gamma, const float* __restrict__ beta)
{
  const int row = blockIdx.x * 4 + (threadIdx.x >> 6);
  const int l = threadIdx.x & 63;
  const int mod = ((row % kLen) < kHW) ? 0 : 1;
  const s8v u = *(const s8v*)&x[(size_t)row * kD + l * 8];
  float v[8];
#pragma unroll
  for (int j = 0; j < 8; j++) v[j] = b2f((unsigned short)u[j]);
  float s = 0.f, s2 = 0.f;
#pragma unroll
  for (int j = 0; j < 8; j++) { s += v[j]; s2 += v[j] * v[j]; }
#pragma unroll
  for (int o = 32; o > 0; o >>= 1) {
    s  += __shfl_xor(s, o);
    s2 += __shfl_xor(s2, o);
  }
  const float mean = s * (1.0f / kD);
  const float var  = s2 * (1.0f / kD) - mean * mean;
  const float rstd = rsqrtf(var + kEps);
  const float* g  = gamma + mod * kD + l * 8;
  const float* be = beta  + mod * kD + l * 8;
  s8v o8;
#pragma unroll
  for (int j = 0; j < 8; j++)
    o8[j] = (short)f2b((v[j] - mean) * rstd * g[j] + be[j]);
  *(s8v*)&outb[(size_t)row * kD + swzk(row, l * 8)] = o8;
}

// ------------------- deformable sampling (bf16 value) -----------------------
__global__ __launch_bounds__(256)
void sample_k(const unsigned short* __restrict__ value, const float* __restrict__ offaw,
              unsigned short* __restrict__ out)
{
  __shared__ float wls[2][64][8];   // [tok][combo][w0,i0,...,w3,i3]
  const int tid = threadIdx.x;
  const int tok = tid >> 7;
  const int wt  = tid & 127;
  const int token = blockIdx.x * 2 + tok;       // < 12800
  const int b = token / kLen;
  const int t = token % kLen;
  const int tt = t % kHW;

  if (wt < 64) {
    const int h = wt >> 3, lp = wt & 7, lvl = lp >> 2, p = lp & 3;
    const float* oa = offaw + (size_t)token * 192;
    const float lg = oa[128 + h * 8 + lp];
    float mx = lg;
#pragma unroll
    for (int msk = 1; msk < 8; msk <<= 1) mx = fmaxf(mx, __shfl_xor(mx, msk));
    const float ex = __expf(lg - mx);
    float ssum = ex;
#pragma unroll
    for (int msk = 1; msk < 8; msk <<= 1) ssum += __shfl_xor(ssum, msk);
    const float aw = ex / ssum;

    const float x = (float)(tt % kWpx) + oa[h * 16 + lvl * 8 + p * 2];
    const float y = (float)(tt / kWpx) + oa[h * 16 + lvl * 8 + p * 2 + 1];
    const float x0f = floorf(x), y0f = floorf(y);
    const float wx = x - x0f, wy = y - y0f;
    const int x0 = (int)x0f, y0 = (int)y0f;
    const int rowbase = b * kLen + lvl * kHW;
#pragma unroll
    for (int dy = 0; dy < 2; dy++) {
#pragma unroll
      for (int dx = 0; dx < 2; dx++) {
        const int ix = x0 + dx, iy = y0 + dy;
        const bool valid = (ix >= 0) & (ix < kWpx) & (iy >= 0) & (iy < kHpx);
        const float cw = (dx ? wx : 1.0f - wx) * (dy ? wy : 1.0f - wy);
        const float w = valid ? aw * cw : 0.0f;
        const int ixc = min(max(ix, 0), kWpx - 1);
        const int iyc = min(max(iy, 0), kHpx - 1);
        const int r = rowbase + iyc * kWpx + ixc;
        const int cn = dy * 2 + dx;
        wls[tok][wt][cn * 2]     = w;
        wls[tok][wt][cn * 2 + 1] = __int_as_float(r);
      }
    }
  }
  __syncthreads();

  const int c0 = wt * 4;
  const int h = wt >> 4;
  float acc0 = 0.f, acc1 = 0.f, acc2 = 0.f, acc3 = 0.f;
  const unsigned short* vb = value + c0;
#pragma unroll
  for (int pp = 0; pp < 8; pp++) {
    const float* wl = wls[tok][h * 8 + pp];
#pragma unroll
    for (int cn = 0; cn < 4; cn++) {
      const float w = wl[cn * 2];
      const int r = __float_as_int(wl[cn * 2 + 1]);
      const s4v q = *(const s4v*)(vb + (size_t)r * kD);
      acc0 += w * b2f((unsigned short)q[0]);
      acc1 += w * b2f((unsigned short)q[1]);
      acc2 += w * b2f((unsigned short)q[2]);
      acc3 += w * b2f((unsigned short)q[3]);
    }
  }
  const int sk = swzk(token, c0);
  s4v o;
  o[0] = (short)f2b(acc0); o[1] = (short)f2b(acc1);
  o[2] = (short)f2b(acc2); o[3] = (short)f2b(acc3);
  *(s4v*)&out[(size_t)token * kD + sk] = o;
}

// ---------------- token-sum (bf16 srcb halves -> bf16 swz tokb) -------------
__global__ void sumtok_k(const unsigned short* __restrict__ srcb,
                         unsigned short* __restrict__ tokb)
{
  const int gid = blockIdx.x * 256 + threadIdx.x;   // < 16*400*64
  const int d0 = (gid & 63) * 8;
  const int rest = gid >> 6;
  const int b = rest / kHW, p = rest % kHW;
  const int r1 = b * kLen + p;
  const int r2 = r1 + kHW;
  const int ro = b * kHW + p;
  const s8v u1 = *(const s8v*)&srcb[(size_t)r1 * kD + swzk(r1, d0)];
  const s8v u2 = *(const s8v*)&srcb[(size_t)r2 * kD + swzk(r2, d0)];
  s8v o;
#pragma unroll
  for (int j = 0; j < 8; j++)
    o[j] = (short)f2b(b2f((unsigned short)u1[j]) + b2f((unsigned short)u2[j]));
  *(s8v*)&tokb[(size_t)ro * kD + swzk(ro, d0)] = o;
}

// ------------------------------- launcher -----------------------------------
extern "C" void kernel_launch(void* const* d_in, const int* in_sizes, int n_in,
                              void* d_out, int out_size, void* d_ws, size_t ws_size,
                              hipStream_t stream)
{
  const float* input_v     = (const float*)d_in[0];
  const float* input_i     = (const float*)d_in[1];
  const float* av_w        = (const float*)d_in[2];
  const float* av_b        = (const float*)d_in[3];
  const float* av_g        = (const float*)d_in[4];
  const float* av_be       = (const float*)d_in[5];
  const float* ai_w        = (const float*)d_in[6];
  const float* ai_b        = (const float*)d_in[7];
  const float* ai_g        = (const float*)d_in[8];
  const float* ai_be       = (const float*)d_in[9];
  const float* level_embed = (const float*)d_in[10];
  const float* off_w       = (const float*)d_in[11];
  const float* off_b       = (const float*)d_in[12];
  const float* aw_w        = (const float*)d_in[13];
  const float* aw_b        = (const float*)d_in[14];
  const float* vp_w        = (const float*)d_in[15];
  const float* vp_b        = (const float*)d_in[16];
  const float* op_w        = (const float*)d_in[17];
  const float* op_b        = (const float*)d_in[18];
  const float* ln1_g       = (const float*)d_in[19];
  const float* ln1_b       = (const float*)d_in[20];
  const float* ffn1_w      = (const float*)d_in[21];
  const float* ffn1_b      = (const float*)d_in[22];
  const float* ffn2_w      = (const float*)d_in[23];
  const float* ffn2_b      = (const float*)d_in[24];
  const float* ln2_g       = (const float*)d_in[25];
  const float* ln2_b       = (const float*)d_in[26];
  const float* as_w        = (const float*)d_in[27];
  const float* as_b        = (const float*)d_in[28];
  const float* as_g        = (const float*)d_in[29];
  const float* as_be       = (const float*)d_in[30];

  // ------- workspace layout (~90 MB) -------
  float* wsf     = (float*)d_ws;
  float* offaw   = wsf;                                  // 2,457,600 f
  float* posWc   = offaw   + (size_t)2457600;            //   921,600 f  [6][800][192]
  float* biasall = posWc   + (size_t)921600;             //     1,536 f
  float* stats   = biasall + (size_t)1536;               //     1,024 f
  unsigned short* srcb     = (unsigned short*)(stats + 1024);   //  6,553,600 sh
  unsigned short* bufA     = srcb     + (size_t)6553600;        // 13,107,200 sh
  unsigned short* bufB     = bufA     + (size_t)13107200;       //  6,553,600 sh
  unsigned short* wall     = bufB     + (size_t)6553600;        // 10,223,616 sh
  unsigned short* wcs      = wall     + (size_t)10223616;       //    393,216 sh
  unsigned short* woaw_all = wcs      + (size_t)393216;         //    786,432 sh
  unsigned short* posfb    = woaw_all + (size_t)786432;         //    458,752 sh
  float* wallf = (float*)wall;   // f32 conv scratch (aliases weight arena)

  const int M  = kB * kLen;   // 12800

  // ---- pre: positional features, posWc = (posf @ [ow|aww] + bias) ----
  posfb_k<<<dim3(224), 256, 0, stream>>>(posfb, level_embed);
  cvt_pre_k<<<dim3(390), 256, 0, stream>>>(off_w, aw_w, off_b, aw_b,
                                           woaw_all, biasall);
  mgemm<5><<<dim3(12, 7), 256, 0, stream>>>(
      posfb, woaw_all, biasall, nullptr, posWc, nullptr, nullptr, nullptr,
      512, 0, 0);

  // ---- input convs + GN -> srcb (conv f32 scratch in wallf; inb in bufA) ----
  for (int mod = 0; mod < 2; mod++) {
    const float* in  = mod ? input_i : input_v;
    const float* cw  = mod ? ai_w  : av_w;
    const float* cb  = mod ? ai_b  : av_b;
    const float* cg  = mod ? ai_g  : av_g;
    const float* cbe = mod ? ai_be : av_be;
    tin_k<<<dim3(48, 25, 16), 256, 0, stream>>>(in, bufA);
    cvtw_d_k<<<dim3(192), 256, 0, stream>>>(cw, wcs, 768, 512);
    mgemm<0><<<dim3(4, 50), 256, 0, stream>>>(
        bufA, wcs, cb, nullptr, wallf, nullptr, nullptr, nullptr, 768, 512, 0);
    gn_stats_tok_k<<<dim3(kB * 32), 256, 0, stream>>>(wallf, stats);
    gn_norm_tok_k<<<dim3(1600), 256, 0, stream>>>(
        wallf, srcb, stats, cg, cbe, mod * kHW);
  }

  // ---- all layer weights -> wall (one dispatch; wallf scratch now dead) ----
  cvt_all_k<<<dim3(4992), 256, 0, stream>>>(vp_w, op_w, off_w, aw_w,
                                            ffn1_w, ffn2_w, wall);

  for (int l = 0; l < kNL; l++) {
    unsigned short* wcomb = wall + (size_t)l * 1703936;
    unsigned short* wop   = wcomb + 393216;
    unsigned short* wf1   = wcomb + 655360;
    unsigned short* wf2   = wcomb + 1179648;
    const float* vbl  = vp_b   + (size_t)l * kD;
    const float* opbl = op_b   + (size_t)l * kD;
    const float* l1g  = ln1_g  + (size_t)l * 2 * kD;
    const float* l1b  = ln1_b  + (size_t)l * 2 * kD;
    const float* f1b  = ffn1_b + (size_t)l * kDff;
    const float* f2b_ = ffn2_b + (size_t)l * kD;
    const float* l2g  = ln2_g  + (size_t)l * 2 * kD;
    const float* l2b  = ln2_b  + (size_t)l * 2 * kD;

    // fused: value bf16 (bufA) | offaw f32 (+posWc)
    mgemm<4><<<dim3(6, 100), 256, 0, stream>>>(
        srcb, wcomb, vbl, nullptr, nullptr, offaw, posWc + (size_t)l * 153600,
        bufA, 512, 0, 0);

    // sampling -> bufB (bf16 swz)
    sample_k<<<dim3(M / 2), 256, 0, stream>>>(bufA, offaw, bufB);

    // y = srcb + sampled @ op + opb -> bufA (bf16 plain; value dead)
    mgemm<2><<<dim3(4, 100), 256, 0, stream>>>(
        bufB, wop, opbl, srcb, nullptr, nullptr, nullptr, bufA, 512, 512, 0);

    // srcb = LN_spec(y)
    ln4_k<<<dim3(M / 4), 256, 0, stream>>>(bufA, srcb, l1g, l1b);

    // FFN full-M: hidden -> bufA (swz, relu); y -> bufB (plain; sampled dead)
    mgemm<1><<<dim3(8, 100), 256, 0, stream>>>(
        srcb, wf1, f1b, nullptr, nullptr, nullptr, nullptr, bufA, 512, 1024, 0);
    mgemm<2><<<dim3(4, 100), 256, 0, stream>>>(
        bufA, wf2, f2b_, srcb, nullptr, nullptr, nullptr, bufB, 1024, 512, 0);

    // srcb = LN_spec(y)
    ln4_k<<<dim3(M / 4), 256, 0, stream>>>(bufB, srcb, l2g, l2b);
  }

  // ---- out = GN(conv1x1(src_v + src_i)); f32 scratch back in wallf ----
  sumtok_k<<<dim3(1600), 256, 0, stream>>>(srcb, bufA);
  cvtw_d_k<<<dim3(192), 256, 0, stream>>>(as_w, wcs, 512, 768);
  mgemm<3><<<dim3(6, 50), 256, 0, stream>>>(
      bufA, wcs, as_b, nullptr, wallf, nullptr, nullptr, nullptr, 512, 0, 768);
  gn_stats_ch_k<<<dim3(kB * 32), 256, 0, stream>>>(wallf, stats);
  gn_norm_ch_k<<<dim3(19200), 256, 0, stream>>>(
      wallf, (float*)d_out, stats, as_g, as_be);
}

// Round 6
// 1098.109 us; speedup vs baseline: 5.1306x; 1.0171x over previous
//
#include <hip/hip_runtime.h>
#include <hip/hip_bf16.h>
#include <cstddef>
#include <math.h>

// ---------------------------------------------------------------------------
// Round 5: mgemm K-loop -> 3-buffer, 2-deep prefetch with counted
// s_waitcnt vmcnt(4) + raw s_barrier (no full drain per K-step; T3/T4).
// Input convs merged into one M=12800 GEMM writing bf16; GN reads bf16.
// ---------------------------------------------------------------------------

constexpr int kB   = 16;
constexpr int kCin = 768;
constexpr int kHW  = 400;
constexpr int kWpx = 20;
constexpr int kHpx = 20;
constexpr int kD   = 512;
constexpr int kLen = 800;
constexpr int kDff = 1024;
constexpr int kNL  = 6;
constexpr float kEps = 1e-5f;

typedef __attribute__((ext_vector_type(8))) short s8v;
typedef __attribute__((ext_vector_type(4))) short s4v;
typedef __attribute__((ext_vector_type(4))) float f4v;

__device__ __forceinline__ int swzk(int row, int k) {
  return (k & ~31) | ((((k >> 3) + (row >> 1)) & 3) << 3) | (k & 7);
}

__device__ __forceinline__ unsigned short f2b(float f) {
  union { __hip_bfloat16 h; unsigned short u; } cv;
  cv.h = __float2bfloat16(f);
  return cv.u;
}

__device__ __forceinline__ float b2f(unsigned short u) {
  return __uint_as_float(((unsigned)u) << 16);
}

__device__ __forceinline__ void gll(const unsigned short* g, unsigned short* l) {
  __builtin_amdgcn_global_load_lds(
      (const __attribute__((address_space(1))) unsigned int*)g,
      (__attribute__((address_space(3))) unsigned int*)l, 16, 0, 0);
}

// ------------------------------ block reduce -------------------------------
__device__ __forceinline__ void breduce2(float& s, float& s2, float* sh) {
#pragma unroll
  for (int o = 32; o > 0; o >>= 1) {
    s  += __shfl_down(s, o);
    s2 += __shfl_down(s2, o);
  }
  const int wid = threadIdx.x >> 6, lane = threadIdx.x & 63;
  if (lane == 0) { sh[wid] = s; sh[4 + wid] = s2; }
  __syncthreads();
  if (threadIdx.x == 0) {
    sh[0] = sh[0] + sh[1] + sh[2] + sh[3];
    sh[4] = sh[4] + sh[5] + sh[6] + sh[7];
  }
  __syncthreads();
  s = sh[0]; s2 = sh[4];
}

// ------------------------------- MFMA GEMM ---------------------------------
// 3-buffer 2-deep prefetch; counted vmcnt; raw s_barrier (1 per K-step).
// EPI 1: bf16 Cb[row*ldc + swzk] = relu(acc+bias)            (ffn hidden)
// EPI 2: bf16 Cb[row*512+col] = acc+bias + res(srcb swz)     (pre-LN y)
// EPI 3: f32 Cf[((row/400)*Nreal+col)*400 + row%400] = acc+bias (conv out)
// EPI 4: col<512 -> bf16 Cb[row*512+col] (value, plain);
//        col in [512,704) -> f32 Cf2[row*192+c] = acc + aux[(row%800)*192+c]
// EPI 5: posWc writer: Cf[((col>>8)*800 + row)*192 + (col&255)] = acc+bias
// EPI 6: plain bf16 Cb[row*512+col]; B/bias selected by m0-half
//        (rows >= 6400 use resb as weights, aux as bias)
template<int EPI>
__global__ __launch_bounds__(256)
void mgemm(const unsigned short* __restrict__ Abf,
           const unsigned short* __restrict__ Bw,
           const float* __restrict__ bias,
           const unsigned short* __restrict__ resb,
           float* __restrict__ Cf, float* __restrict__ Cf2,
           const float* __restrict__ aux,
           unsigned short* __restrict__ Cb,
           int K, int ldc, int Nreal)
{
  __shared__ unsigned short As[3][4096];
  __shared__ unsigned short Bs[3][4096];
  const int tid = threadIdx.x;
  const int w = tid >> 6, l = tid & 63;
  const int m0 = blockIdx.y * 128;
  const int n0 = blockIdx.x * 128;

  if (EPI == 6 && m0 >= 6400) { Bw = resb; bias = aux; }

  f4v acc[4][4] = {};

  const int srow = w * 32 + (l >> 2);
  const unsigned short* ga0 = Abf + (size_t)(m0 + srow) * K + (l & 3) * 8;
  const unsigned short* ga1 = ga0 + (size_t)16 * K;
  const unsigned short* gb0 = Bw + (size_t)(n0 + srow) * K + (l & 3) * 8;
  const unsigned short* gb1 = gb0 + (size_t)16 * K;
  const int lb0 = (w * 32) * 32;
  const int lb1 = (w * 32 + 16) * 32;

  int aoff[4], boff[4];
#pragma unroll
  for (int f = 0; f < 4; f++) {
    const int ra = (w >> 1) * 64 + f * 16 + (l & 15);
    aoff[f] = ra * 32 + ((((l >> 4) + (ra >> 1)) & 3) << 3);
    const int rb = (w & 1) * 64 + f * 16 + (l & 15);
    boff[f] = rb * 32 + ((((l >> 4) + (rb >> 1)) & 3) << 3);
  }

#define STAGE(ko, bi) do { \
    gll(ga0 + (ko), &As[bi][lb0]); gll(ga1 + (ko), &As[bi][lb1]); \
    gll(gb0 + (ko), &Bs[bi][lb0]); gll(gb1 + (ko), &Bs[bi][lb1]); } while (0)

  const int NT = K >> 5;
  // prologue: 2 tiles in flight
  STAGE(0, 0);
  STAGE(32, 1);

  int cur = 0;        // buffer of tile t
  int bpre = 2;       // buffer of tile t+2
  int kpre = 64;      // k-offset (shorts) of tile t+2
  for (int t = 0; t < NT; ++t) {
    // own stage(t) complete (stage(t+1) is exactly the 4 newest loads)
    if (t + 1 < NT) asm volatile("s_waitcnt vmcnt(4)" ::: "memory");
    else            asm volatile("s_waitcnt vmcnt(0)" ::: "memory");
    __builtin_amdgcn_s_barrier();       // all waves' tile-t loads landed
    __builtin_amdgcn_sched_barrier(0);
    if (t + 2 < NT) STAGE(kpre, bpre);  // overwrites buf of tile t-1 (done)
    s8v af[4], bf4[4];
#pragma unroll
    for (int f = 0; f < 4; f++) {
      af[f]  = *(const s8v*)&As[cur][aoff[f]];
      bf4[f] = *(const s8v*)&Bs[cur][boff[f]];
    }
#pragma unroll
    for (int i = 0; i < 4; i++)
#pragma unroll
      for (int j = 0; j < 4; j++)
        acc[i][j] = __builtin_amdgcn_mfma_f32_16x16x32_bf16(af[i], bf4[j], acc[i][j], 0, 0, 0);
    kpre += 32;
    bpre = (bpre == 2) ? 0 : bpre + 1;
    cur  = (cur == 2) ? 0 : cur + 1;
  }
#undef STAGE

  // C/D layout: col=lane&15, row=(lane>>4)*4+reg
  const int colb = n0 + (w & 1) * 64;
  const int rowb = m0 + (w >> 1) * 64 + (l >> 4) * 4;
#pragma unroll
  for (int i = 0; i < 4; i++) {
#pragma unroll
    for (int j = 0; j < 4; j++) {
      const int col = colb + j * 16 + (l & 15);
      float bv;
      if (EPI == 4) bv = (col < kD) ? bias[col] : 0.0f;
      else          bv = bias[col];
#pragma unroll
      for (int r = 0; r < 4; r++) {
        const int row = rowb + i * 16 + r;
        float v = acc[i][j][r] + bv;
        if (EPI == 1) {
          Cb[(size_t)row * ldc + swzk(row, col)] = f2b(fmaxf(v, 0.0f));
        } else if (EPI == 2) {
          v += b2f(resb[(size_t)row * kD + swzk(row, col)]);
          Cb[(size_t)row * kD + col] = f2b(v);
        } else if (EPI == 3) {
          const int bb = row / kHW, p = row % kHW;
          Cf[((size_t)bb * Nreal + col) * kHW + p] = v;
        } else if (EPI == 4) {
          if (col < kD) {
            Cb[(size_t)row * kD + col] = f2b(v);
          } else {
            const int c = col - kD;
            if (c < 192)
              Cf2[(size_t)row * 192 + c] = v + aux[(size_t)(row % kLen) * 192 + c];
          }
        } else if (EPI == 5) {
          if (row < kLen) {
            const int ll = col >> 8, c = col & 255;
            if (c < 192)
              Cf[(((size_t)ll * kLen) + row) * 192 + c] = v;
          }
        } else {  // EPI == 6
          Cb[(size_t)row * kD + col] = f2b(v);
        }
      }
    }
  }
}

// -------------------------- weight conversions -----------------------------
__device__ __forceinline__ void cvt8t(const float* __restrict__ W,
                                      unsigned short* __restrict__ out,
                                      int K, int N, int g)
{
  const int n = g % N;
  const int k = (g / N) * 8;
  s8v p;
#pragma unroll
  for (int j = 0; j < 8; j++) p[j] = (short)f2b(W[(size_t)(k + j) * N + n]);
  const int base = n * K + (k & ~31) + ((((k >> 3) + (n >> 1)) & 3) << 3);
  *(s8v*)&out[base] = p;
}

// ALL 6 layers' weights in one dispatch: 6 x 212,992 items, 4992 blocks.
__global__ __launch_bounds__(256)
void cvt_all_k(const float* __restrict__ vp_w, const float* __restrict__ op_w,
               const float* __restrict__ off_w, const float* __restrict__ aw_w,
               const float* __restrict__ f1w_a, const float* __restrict__ f2w_a,
               unsigned short* __restrict__ wall)
{
  const int lyr = blockIdx.x / 832;
  int g = (blockIdx.x % 832) * 256 + threadIdx.x;
  unsigned short* wl = wall + (size_t)lyr * 1703936;
  if (g < 32768) { cvt8t(vp_w + (size_t)lyr * kD * kD, wl, 512, 512, g); return; }
  g -= 32768;
  if (g < 16384) {                       // [ow|aww] -> wcomb rows 512..767
    const int n = g & 255;
    const int k = (g >> 8) * 8;
    const float* ow  = off_w + (size_t)lyr * kD * 128;
    const float* aww = aw_w  + (size_t)lyr * kD * 64;
    s8v p;
#pragma unroll
    for (int j = 0; j < 8; j++) {
      float v = 0.0f;
      if (n < 128)      v = ow[(size_t)(k + j) * 128 + n];
      else if (n < 192) v = aww[(size_t)(k + j) * 64 + (n - 128)];
      p[j] = (short)f2b(v);
    }
    const int row = 512 + n;
    const int base = row * 512 + (k & ~31) + ((((k >> 3) + (row >> 1)) & 3) << 3);
    *(s8v*)&wl[base] = p;
    return;
  }
  g -= 16384;
  if (g < 32768) { cvt8t(op_w + (size_t)lyr * kD * kD, wl + 393216, 512, 512, g); return; }
  g -= 32768;
  if (g < 65536) { cvt8t(f1w_a + (size_t)lyr * kD * kDff, wl + 655360, 512, 1024, g); return; }
  g -= 65536;
  cvt8t(f2w_a + (size_t)lyr * kDff * kD, wl + 1179648, 1024, 512, g);
}

// upfront: all 6 layers' [ow|aww] -> woaw_all [6*256][512] swz + biasall
__global__ __launch_bounds__(256)
void cvt_pre_k(const float* __restrict__ off_w, const float* __restrict__ aw_w,
               const float* __restrict__ off_b, const float* __restrict__ aw_b,
               unsigned short* __restrict__ woaw_all, float* __restrict__ biasall)
{
  int g = blockIdx.x * 256 + threadIdx.x;     // < 99840
  if (g < 98304) {
    const int l = g >> 14;
    const int gg = g & 16383;
    const int n = gg & 255;
    const int k = (gg >> 8) * 8;
    const float* ow = off_w + (size_t)l * kD * 128;
    const float* aww = aw_w + (size_t)l * kD * 64;
    s8v p;
#pragma unroll
    for (int j = 0; j < 8; j++) {
      float v = 0.0f;
      if (n < 128)      v = ow[(size_t)(k + j) * 128 + n];
      else if (n < 192) v = aww[(size_t)(k + j) * 64 + (n - 128)];
      p[j] = (short)f2b(v);
    }
    const int row = l * 256 + n;
    const int base = row * 512 + (k & ~31) + ((((k >> 3) + (row >> 1)) & 3) << 3);
    *(s8v*)&woaw_all[base] = p;
    return;
  }
  g -= 98304;                                 // < 1536
  const int l = g >> 8, c = g & 255;
  float v = 0.0f;
  if (c < 128)      v = off_b[l * 128 + c];
  else if (c < 192) v = aw_b[l * 64 + (c - 128)];
  biasall[l * 256 + c] = v;
}

// W already [N][K] f32 -> bf16 swz (single conv weight, as_w)
__global__ void cvtw_d_k(const float* __restrict__ W, unsigned short* __restrict__ out,
                         int K, int N)
{
  const int gid = blockIdx.x * 256 + threadIdx.x;   // N*(K/8)
  const int K8 = K >> 3;
  const int n  = gid / K8;
  const int k  = (gid % K8) * 8;
  s8v p;
#pragma unroll
  for (int j = 0; j < 8; j++) p[j] = (short)f2b(W[(size_t)n * K + k + j]);
  const int base = n * K + (k & ~31) + ((((k >> 3) + (n >> 1)) & 3) << 3);
  *(s8v*)&out[base] = p;
}

// both input conv weights [512][768] -> wcs (av at 0, ai at 393216)
__global__ void cvtw_dd_k(const float* __restrict__ W0, const float* __restrict__ W1,
                          unsigned short* __restrict__ out)
{
  int gid = blockIdx.x * 256 + threadIdx.x;   // < 2*512*96
  const float* W = W0;
  unsigned short* o = out;
  if (gid >= 49152) { gid -= 49152; W = W1; o = out + 393216; }
  const int n = gid / 96;
  const int k = (gid % 96) * 8;
  s8v p;
#pragma unroll
  for (int j = 0; j < 8; j++) p[j] = (short)f2b(W[(size_t)n * kCin + k + j]);
  const int base = n * kCin + (k & ~31) + ((((k >> 3) + (n >> 1)) & 3) << 3);
  *(s8v*)&o[base] = p;
}

// ------- input transpose [2][B,768,400] -> bf16 swz rows (mod*16+b)*400+p ----
__global__ void tin_k(const float* __restrict__ inv, const float* __restrict__ ini,
                      unsigned short* __restrict__ out)
{
  __shared__ float t[16][17];
  const int z = blockIdx.z;                 // mod*16+b
  const int mod = z >> 4, b = z & 15;
  const float* in = (mod ? ini : inv) + (size_t)b * kCin * kHW;
  const int c0 = blockIdx.x * 16, p0 = blockIdx.y * 16;
  const int tx = threadIdx.x & 15, ty = threadIdx.x >> 4;
  t[ty][tx] = in[((size_t)(c0 + ty)) * kHW + p0 + tx];
  __syncthreads();
  const int row = z * kHW + p0 + ty;
  const int c = c0 + tx;
  out[(size_t)row * kCin + swzk(row, c)] = f2b(t[tx][ty]);
}

// ---------------- positional features -> bf16 swz [896][512] ----------------
__global__ void posfb_k(unsigned short* __restrict__ posfb,
                        const float* __restrict__ level_embed)
{
  const int gid = blockIdx.x * 256 + threadIdx.x;   // < 896*64
  const int d0 = (gid & 63) * 8;
  const int t  = gid >> 6;
  s8v o;
  if (t >= kLen) {
#pragma unroll
    for (int j = 0; j < 8; j++) o[j] = 0;
  } else {
    const int lvl = t / kHW;
    const int tt = t % kHW;
    const int yy = tt / kWpx, xx = tt % kWpx;
#pragma unroll
    for (int j = 0; j < 8; j++) {
      const int d = d0 + j;
      const int dd = d & 255;
      const float e = (d < 256) ? ((float)(yy + 1) * (6.283185307179586f / kHpx))
                                : ((float)(xx + 1) * (6.283185307179586f / kWpx));
      const float dimt = powf(10000.0f, (float)(dd >> 1) / 128.0f);
      const float pp = e / dimt;
      const float val = (dd & 1) ? cosf(pp) : sinf(pp);
      o[j] = (short)f2b(val + level_embed[lvl * kD + d]);
    }
  }
  *(s8v*)&posfb[(size_t)t * kD + swzk(t, d0)] = o;
}

// ------------------ GroupNorm (token-major, bf16 input) ---------------------
__global__ __launch_bounds__(256)
void gn_stats_tok_k(const unsigned short* __restrict__ x, float* __restrict__ stats)
{
  __shared__ float sh[8];
  const int mb = blockIdx.x >> 5;   // mod*16+b
  const int g = blockIdx.x & 31;
  const unsigned short* xb = x + (size_t)mb * kHW * kD + g * 16;
  float s = 0.f, s2 = 0.f;
  for (int i = threadIdx.x; i < 800; i += 256) {
    const int p = i >> 1, half = i & 1;
    const s8v u = *(const s8v*)&xb[(size_t)p * kD + half * 8];
#pragma unroll
    for (int j = 0; j < 8; j++) {
      const float v = b2f((unsigned short)u[j]);
      s += v; s2 += v * v;
    }
  }
  breduce2(s, s2, sh);
  if (threadIdx.x == 0) {
    const float mean = s / (kHW * 16.0f);
    const float var  = s2 / (kHW * 16.0f) - mean * mean;
    stats[blockIdx.x * 2]     = mean;
    stats[blockIdx.x * 2 + 1] = rsqrtf(var + kEps);
  }
}

__global__ void gn_norm_tok_k(const unsigned short* __restrict__ x,
                              unsigned short* __restrict__ srcb,
                              const float* __restrict__ stats,
                              const float* __restrict__ gv, const float* __restrict__ bev,
                              const float* __restrict__ gi, const float* __restrict__ bei)
{
  const int gid = blockIdx.x * 256 + threadIdx.x;   // < 12800*64
  const int d0 = (gid & 63) * 8;
  const int rl = gid >> 6;                          // (mod*16+b)*400+p
  const int mb = rl / kHW;
  const int p  = rl - mb * kHW;
  const int mod = mb >> 4, b = mb & 15;
  const int g = d0 >> 4;
  const float mean = stats[(mb * 32 + g) * 2];
  const float rstd = stats[(mb * 32 + g) * 2 + 1];
  const float* gam = mod ? gi : gv;
  const float* bet = mod ? bei : bev;
  const s8v u = *(const s8v*)&x[(size_t)rl * kD + d0];
  const int row = b * kLen + mod * kHW + p;
  s8v o;
#pragma unroll
  for (int j = 0; j < 8; j++)
    o[j] = (short)f2b((b2f((unsigned short)u[j]) - mean) * rstd * gam[d0 + j] + bet[d0 + j]);
  *(s8v*)&srcb[(size_t)row * kD + swzk(row, d0)] = o;
}

// --------------------------- GroupNorm (chan-major) -------------------------
__global__ __launch_bounds__(256)
void gn_stats_ch_k(const float* __restrict__ x, float* __restrict__ stats)
{
  __shared__ float sh[8];
  const int b = blockIdx.x >> 5;
  const int g = blockIdx.x & 31;
  const float* xb = x + (size_t)b * kCin * kHW + (size_t)g * 24 * kHW;
  float s = 0.f, s2 = 0.f;
  for (int i = threadIdx.x; i < 24 * kHW; i += 256) {
    const float v = xb[i];
    s += v; s2 += v * v;
  }
  breduce2(s, s2, sh);
  if (threadIdx.x == 0) {
    const float mean = s / (24.0f * kHW);
    const float var  = s2 / (24.0f * kHW) - mean * mean;
    stats[blockIdx.x * 2]     = mean;
    stats[blockIdx.x * 2 + 1] = rsqrtf(var + kEps);
  }
}

__global__ void gn_norm_ch_k(const float* __restrict__ x, float* __restrict__ out,
                             const float* __restrict__ stats,
                             const float* __restrict__ gam, const float* __restrict__ bet)
{
  const int idx = blockIdx.x * 256 + threadIdx.x;   // < 16*768*400
  const int rest = idx / kHW;
  const int c = rest % kCin;
  const int b = rest / kCin;
  const int g = c / 24;
  const float mean = stats[(b * 32 + g) * 2];
  const float rstd = stats[(b * 32 + g) * 2 + 1];
  out[idx] = (x[idx] - mean) * rstd * gam[c] + bet[c];
}

// ------------- modality-specific LayerNorm (wave/row, bf16 in) --------------
__global__ __launch_bounds__(256)
void ln4_k(const unsigned short* __restrict__ x, unsigned short* __restrict__ outb,
           const float* __restrict__ gamma, const float* __restrict__ beta)
{
  const int row = blockIdx.x * 4 + (threadIdx.x >> 6);
  const int l = threadIdx.x & 63;
  const int mod = ((row % kLen) < kHW) ? 0 : 1;
  const s8v u = *(const s8v*)&x[(size_t)row * kD + l * 8];
  float v[8];
#pragma unroll
  for (int j = 0; j < 8; j++) v[j] = b2f((unsigned short)u[j]);
  float s = 0.f, s2 = 0.f;
#pragma unroll
  for (int j = 0; j < 8; j++) { s += v[j]; s2 += v[j] * v[j]; }
#pragma unroll
  for (int o = 32; o > 0; o >>= 1) {
    s  += __shfl_xor(s, o);
    s2 += __shfl_xor(s2, o);
  }
  const float mean = s * (1.0f / kD);
  const float var  = s2 * (1.0f / kD) - mean * mean;
  const float rstd = rsqrtf(var + kEps);
  const float* g  = gamma + mod * kD + l * 8;
  const float* be = beta  + mod * kD + l * 8;
  s8v o8;
#pragma unroll
  for (int j = 0; j < 8; j++)
    o8[j] = (short)f2b((v[j] - mean) * rstd * g[j] + be[j]);
  *(s8v*)&outb[(size_t)row * kD + swzk(row, l * 8)] = o8;
}

// ------------------- deformable sampling (bf16 value) -----------------------
__global__ __launch_bounds__(256)
void sample_k(const unsigned short* __restrict__ value, const float* __restrict__ offaw,
              unsigned short* __restrict__ out)
{
  __shared__ float wls[2][64][8];   // [tok][combo][w0,i0,...,w3,i3]
  const int tid = threadIdx.x;
  const int tok = tid >> 7;
  const int wt  = tid & 127;
  const int token = blockIdx.x * 2 + tok;       // < 12800
  const int b = token / kLen;
  const int t = token % kLen;
  const int tt = t % kHW;

  if (wt < 64) {
    const int h = wt >> 3, lp = wt & 7, lvl = lp >> 2, p = lp & 3;
    const float* oa = offaw + (size_t)token * 192;
    const float lg = oa[128 + h * 8 + lp];
    float mx = lg;
#pragma unroll
    for (int msk = 1; msk < 8; msk <<= 1) mx = fmaxf(mx, __shfl_xor(mx, msk));
    const float ex = __expf(lg - mx);
    float ssum = ex;
#pragma unroll
    for (int msk = 1; msk < 8; msk <<= 1) ssum += __shfl_xor(ssum, msk);
    const float aw = ex / ssum;

    const float x = (float)(tt % kWpx) + oa[h * 16 + lvl * 8 + p * 2];
    const float y = (float)(tt / kWpx) + oa[h * 16 + lvl * 8 + p * 2 + 1];
    const float x0f = floorf(x), y0f = floorf(y);
    const float wx = x - x0f, wy = y - y0f;
    const int x0 = (int)x0f, y0 = (int)y0f;
    const int rowbase = b * kLen + lvl * kHW;
#pragma unroll
    for (int dy = 0; dy < 2; dy++) {
#pragma unroll
      for (int dx = 0; dx < 2; dx++) {
        const int ix = x0 + dx, iy = y0 + dy;
        const bool valid = (ix >= 0) & (ix < kWpx) & (iy >= 0) & (iy < kHpx);
        const float cw = (dx ? wx : 1.0f - wx) * (dy ? wy : 1.0f - wy);
        const float w = valid ? aw * cw : 0.0f;
        const int ixc = min(max(ix, 0), kWpx - 1);
        const int iyc = min(max(iy, 0), kHpx - 1);
        const int r = rowbase + iyc * kWpx + ixc;
        const int cn = dy * 2 + dx;
        wls[tok][wt][cn * 2]     = w;
        wls[tok][wt][cn * 2 + 1] = __int_as_float(r);
      }
    }
  }
  __syncthreads();

  const int c0 = wt * 4;
  const int h = wt >> 4;
  float acc0 = 0.f, acc1 = 0.f, acc2 = 0.f, acc3 = 0.f;
  const unsigned short* vb = value + c0;
#pragma unroll
  for (int pp = 0; pp < 8; pp++) {
    const float* wl = wls[tok][h * 8 + pp];
#pragma unroll
    for (int cn = 0; cn < 4; cn++) {
      const float w = wl[cn * 2];
      const int r = __float_as_int(wl[cn * 2 + 1]);
      const s4v q = *(const s4v*)(vb + (size_t)r * kD);
      acc0 += w * b2f((unsigned short)q[0]);
      acc1 += w * b2f((unsigned short)q[1]);
      acc2 += w * b2f((unsigned short)q[2]);
      acc3 += w * b2f((unsigned short)q[3]);
    }
  }
  const int sk = swzk(token, c0);
  s4v o;
  o[0] = (short)f2b(acc0); o[1] = (short)f2b(acc1);
  o[2] = (short)f2b(acc2); o[3] = (short)f2b(acc3);
  *(s4v*)&out[(size_t)token * kD + sk] = o;
}

// ---------------- token-sum (bf16 srcb halves -> bf16 swz tokb) -------------
__global__ void sumtok_k(const unsigned short* __restrict__ srcb,
                         unsigned short* __restrict__ tokb)
{
  const int gid = blockIdx.x * 256 + threadIdx.x;   // < 16*400*64
  const int d0 = (gid & 63) * 8;
  const int rest = gid >> 6;
  const int b = rest / kHW, p = rest % kHW;
  const int r1 = b * kLen + p;
  const int r2 = r1 + kHW;
  const int ro = b * kHW + p;
  const s8v u1 = *(const s8v*)&srcb[(size_t)r1 * kD + swzk(r1, d0)];
  const s8v u2 = *(const s8v*)&srcb[(size_t)r2 * kD + swzk(r2, d0)];
  s8v o;
#pragma unroll
  for (int j = 0; j < 8; j++)
    o[j] = (short)f2b(b2f((unsigned short)u1[j]) + b2f((unsigned short)u2[j]));
  *(s8v*)&tokb[(size_t)ro * kD + swzk(ro, d0)] = o;
}

// ------------------------------- launcher -----------------------------------
extern "C" void kernel_launch(void* const* d_in, const int* in_sizes, int n_in,
                              void* d_out, int out_size, void* d_ws, size_t ws_size,
                              hipStream_t stream)
{
  const float* input_v     = (const float*)d_in[0];
  const float* input_i     = (const float*)d_in[1];
  const float* av_w        = (const float*)d_in[2];
  const float* av_b        = (const float*)d_in[3];
  const float* av_g        = (const float*)d_in[4];
  const float* av_be       = (const float*)d_in[5];
  const float* ai_w        = (const float*)d_in[6];
  const float* ai_b        = (const float*)d_in[7];
  const float* ai_g        = (const float*)d_in[8];
  const float* ai_be       = (const float*)d_in[9];
  const float* level_embed = (const float*)d_in[10];
  const float* off_w       = (const float*)d_in[11];
  const float* off_b       = (const float*)d_in[12];
  const float* aw_w        = (const float*)d_in[13];
  const float* aw_b        = (const float*)d_in[14];
  const float* vp_w        = (const float*)d_in[15];
  const float* vp_b        = (const float*)d_in[16];
  const float* op_w        = (const float*)d_in[17];
  const float* op_b        = (const float*)d_in[18];
  const float* ln1_g       = (const float*)d_in[19];
  const float* ln1_b       = (const float*)d_in[20];
  const float* ffn1_w      = (const float*)d_in[21];
  const float* ffn1_b      = (const float*)d_in[22];
  const float* ffn2_w      = (const float*)d_in[23];
  const float* ffn2_b      = (const float*)d_in[24];
  const float* ln2_g       = (const float*)d_in[25];
  const float* ln2_b       = (const float*)d_in[26];
  const float* as_w        = (const float*)d_in[27];
  const float* as_b        = (const float*)d_in[28];
  const float* as_g        = (const float*)d_in[29];
  const float* as_be       = (const float*)d_in[30];

  // ------- workspace layout (~91 MB) -------
  float* wsf     = (float*)d_ws;
  float* offaw   = wsf;                                  // 2,457,600 f
  float* posWc   = offaw   + (size_t)2457600;            //   921,600 f  [6][800][192]
  float* biasall = posWc   + (size_t)921600;             //     1,536 f
  float* stats   = biasall + (size_t)1536;               //     2,048 f
  unsigned short* srcb     = (unsigned short*)(stats + 2048);   //  6,553,600 sh
  unsigned short* bufA     = srcb     + (size_t)6553600;        // 13,107,200 sh
  unsigned short* bufB     = bufA     + (size_t)13107200;       //  6,553,600 sh
  unsigned short* wall     = bufB     + (size_t)6553600;        // 10,223,616 sh
  unsigned short* wcs      = wall     + (size_t)10223616;       //    786,432 sh
  unsigned short* woaw_all = wcs      + (size_t)786432;         //    786,432 sh
  unsigned short* posfb    = woaw_all + (size_t)786432;         //    458,752 sh
  float* wallf = (float*)wall;   // f32 conv scratch (aliases weight arena, post only)

  const int M = kB * kLen;   // 12800

  // ---- pre: positional features, posWc = (posf @ [ow|aww] + bias) ----
  posfb_k<<<dim3(224), 256, 0, stream>>>(posfb, level_embed);
  cvt_pre_k<<<dim3(390), 256, 0, stream>>>(off_w, aw_w, off_b, aw_b,
                                           woaw_all, biasall);
  mgemm<5><<<dim3(12, 7), 256, 0, stream>>>(
      posfb, woaw_all, biasall, nullptr, posWc, nullptr, nullptr, nullptr,
      512, 0, 0);

  // ---- input convs (both modalities, one GEMM) + GN -> srcb ----
  tin_k<<<dim3(48, 25, 32), 256, 0, stream>>>(input_v, input_i, bufA);
  cvtw_dd_k<<<dim3(384), 256, 0, stream>>>(av_w, ai_w, wcs);
  mgemm<6><<<dim3(4, 100), 256, 0, stream>>>(
      bufA, wcs, av_b, wcs + 393216, nullptr, nullptr, ai_b, bufB, 768, 512, 0);
  gn_stats_tok_k<<<dim3(1024), 256, 0, stream>>>(bufB, stats);
  gn_norm_tok_k<<<dim3(3200), 256, 0, stream>>>(
      bufB, srcb, stats, av_g, av_be, ai_g, ai_be);

  // ---- all layer weights -> wall (one dispatch) ----
  cvt_all_k<<<dim3(4992), 256, 0, stream>>>(vp_w, op_w, off_w, aw_w,
                                            ffn1_w, ffn2_w, wall);

  for (int l = 0; l < kNL; l++) {
    unsigned short* wcomb = wall + (size_t)l * 1703936;
    unsigned short* wop   = wcomb + 393216;
    unsigned short* wf1   = wcomb + 655360;
    unsigned short* wf2   = wcomb + 1179648;
    const float* vbl  = vp_b   + (size_t)l * kD;
    const float* opbl = op_b   + (size_t)l * kD;
    const float* l1g  = ln1_g  + (size_t)l * 2 * kD;
    const float* l1b  = ln1_b  + (size_t)l * 2 * kD;
    const float* f1b  = ffn1_b + (size_t)l * kDff;
    const float* f2b_ = ffn2_b + (size_t)l * kD;
    const float* l2g  = ln2_g  + (size_t)l * 2 * kD;
    const float* l2b  = ln2_b  + (size_t)l * 2 * kD;

    // fused: value bf16 (bufA) | offaw f32 (+posWc)
    mgemm<4><<<dim3(6, 100), 256, 0, stream>>>(
        srcb, wcomb, vbl, nullptr, nullptr, offaw, posWc + (size_t)l * 153600,
        bufA, 512, 0, 0);

    // sampling -> bufB (bf16 swz)
    sample_k<<<dim3(M / 2), 256, 0, stream>>>(bufA, offaw, bufB);

    // y = srcb + sampled @ op + opb -> bufA (bf16 plain)
    mgemm<2><<<dim3(4, 100), 256, 0, stream>>>(
        bufB, wop, opbl, srcb, nullptr, nullptr, nullptr, bufA, 512, 512, 0);

    // srcb = LN_spec(y)
    ln4_k<<<dim3(M / 4), 256, 0, stream>>>(bufA, srcb, l1g, l1b);

    // FFN full-M: hidden -> bufA (swz, relu); y -> bufB (plain)
    mgemm<1><<<dim3(8, 100), 256, 0, stream>>>(
        srcb, wf1, f1b, nullptr, nullptr, nullptr, nullptr, bufA, 512, 1024, 0);
    mgemm<2><<<dim3(4, 100), 256, 0, stream>>>(
        bufA, wf2, f2b_, srcb, nullptr, nullptr, nullptr, bufB, 1024, 512, 0);

    // srcb = LN_spec(y)
    ln4_k<<<dim3(M / 4), 256, 0, stream>>>(bufB, srcb, l2g, l2b);
  }

  // ---- out = GN(conv1x1(src_v + src_i)); f32 scratch in wallf ----
  sumtok_k<<<dim3(1600), 256, 0, stream>>>(srcb, bufA);
  cvtw_d_k<<<dim3(192), 256, 0, stream>>>(as_w, wcs, 512, 768);
  mgemm<3><<<dim3(6, 50), 256, 0, stream>>>(
      bufA, wcs, as_b, nullptr, wallf, nullptr, nullptr, nullptr, 512, 0, 768);
  gn_stats_ch_k<<<dim3(kB * 32), 256, 0, stream>>>(wallf, stats);
  gn_norm_ch_k<<<dim3(19200), 256, 0, stream>>>(
      wallf, (float*)d_out, stats, as_g, as_be);
}

// Round 7
// 1084.864 us; speedup vs baseline: 5.1932x; 1.0122x over previous
//
#include <hip/hip_runtime.h>
#include <hip/hip_bf16.h>
#include <cstddef>
#include <math.h>

// ---------------------------------------------------------------------------
// Round 6: bijective XCD-aware block swizzle on all mgemm grids (T1);
// s_setprio around MFMA cluster (T5); offaw in bf16; pre-kernels fused.
// K-loop: 3-buffer 2-deep prefetch, counted vmcnt(4), raw s_barrier (T3/T4).
// ---------------------------------------------------------------------------

constexpr int kB   = 16;
constexpr int kCin = 768;
constexpr int kHW  = 400;
constexpr int kWpx = 20;
constexpr int kHpx = 20;
constexpr int kD   = 512;
constexpr int kLen = 800;
constexpr int kDff = 1024;
constexpr int kNL  = 6;
constexpr float kEps = 1e-5f;

typedef __attribute__((ext_vector_type(8))) short s8v;
typedef __attribute__((ext_vector_type(4))) short s4v;
typedef __attribute__((ext_vector_type(4))) float f4v;

__device__ __forceinline__ int swzk(int row, int k) {
  return (k & ~31) | ((((k >> 3) + (row >> 1)) & 3) << 3) | (k & 7);
}

__device__ __forceinline__ unsigned short f2b(float f) {
  union { __hip_bfloat16 h; unsigned short u; } cv;
  cv.h = __float2bfloat16(f);
  return cv.u;
}

__device__ __forceinline__ float b2f(unsigned short u) {
  return __uint_as_float(((unsigned)u) << 16);
}

__device__ __forceinline__ void gll(const unsigned short* g, unsigned short* l) {
  __builtin_amdgcn_global_load_lds(
      (const __attribute__((address_space(1))) unsigned int*)g,
      (__attribute__((address_space(3))) unsigned int*)l, 16, 0, 0);
}

// ------------------------------ block reduce -------------------------------
__device__ __forceinline__ void breduce2(float& s, float& s2, float* sh) {
#pragma unroll
  for (int o = 32; o > 0; o >>= 1) {
    s  += __shfl_down(s, o);
    s2 += __shfl_down(s2, o);
  }
  const int wid = threadIdx.x >> 6, lane = threadIdx.x & 63;
  if (lane == 0) { sh[wid] = s; sh[4 + wid] = s2; }
  __syncthreads();
  if (threadIdx.x == 0) {
    sh[0] = sh[0] + sh[1] + sh[2] + sh[3];
    sh[4] = sh[4] + sh[5] + sh[6] + sh[7];
  }
  __syncthreads();
  s = sh[0]; s2 = sh[4];
}

// ------------------------------- MFMA GEMM ---------------------------------
// EPI 1: bf16 Cb[row*ldc + swzk] = relu(acc+bias)            (ffn hidden)
// EPI 2: bf16 Cb[row*512+col] = acc+bias + res(srcb swz)     (pre-LN y)
// EPI 3: f32 Cf[((row/400)*Nreal+col)*400 + row%400] = acc+bias (conv out)
// EPI 4: col<512 -> bf16 Cb[row*512+col] (value, plain);
//        col in [512,704) -> bf16 Cb2[row*192+c] = acc + aux[(row%800)*192+c]
// EPI 5: posWc writer: Cf[((col>>8)*800 + row)*192 + (col&255)] = acc+bias
// EPI 6: plain bf16 Cb[row*512+col]; rows >= 6400 use resb/aux as W/bias
template<int EPI>
__global__ __launch_bounds__(256)
void mgemm(const unsigned short* __restrict__ Abf,
           const unsigned short* __restrict__ Bw,
           const float* __restrict__ bias,
           const unsigned short* __restrict__ resb,
           float* __restrict__ Cf, unsigned short* __restrict__ Cb2,
           const float* __restrict__ aux,
           unsigned short* __restrict__ Cb,
           int K, int ldc, int Nreal)
{
  __shared__ unsigned short As[3][4096];
  __shared__ unsigned short Bs[3][4096];
  const int tid = threadIdx.x;
  const int w = tid >> 6, l = tid & 63;

  // bijective XCD-aware swizzle (m204): chunk grid per XCD, n-fastest inside
  const int gx = gridDim.x;
  const int nwg = gx * gridDim.y;
  const int bid = blockIdx.y * gx + blockIdx.x;
  const int q = nwg >> 3, r = nwg & 7;
  const int xcd = bid & 7, idx = bid >> 3;
  const int wgid = (xcd < r ? xcd * (q + 1) : r * (q + 1) + (xcd - r) * q) + idx;
  const int m0 = (wgid / gx) * 128;
  const int n0 = (wgid % gx) * 128;

  if (EPI == 6 && m0 >= 6400) { Bw = resb; bias = aux; }

  f4v acc[4][4] = {};

  const int srow = w * 32 + (l >> 2);
  const unsigned short* ga0 = Abf + (size_t)(m0 + srow) * K + (l & 3) * 8;
  const unsigned short* ga1 = ga0 + (size_t)16 * K;
  const unsigned short* gb0 = Bw + (size_t)(n0 + srow) * K + (l & 3) * 8;
  const unsigned short* gb1 = gb0 + (size_t)16 * K;
  const int lb0 = (w * 32) * 32;
  const int lb1 = (w * 32 + 16) * 32;

  int aoff[4], boff[4];
#pragma unroll
  for (int f = 0; f < 4; f++) {
    const int ra = (w >> 1) * 64 + f * 16 + (l & 15);
    aoff[f] = ra * 32 + ((((l >> 4) + (ra >> 1)) & 3) << 3);
    const int rb = (w & 1) * 64 + f * 16 + (l & 15);
    boff[f] = rb * 32 + ((((l >> 4) + (rb >> 1)) & 3) << 3);
  }

#define STAGE(ko, bi) do { \
    gll(ga0 + (ko), &As[bi][lb0]); gll(ga1 + (ko), &As[bi][lb1]); \
    gll(gb0 + (ko), &Bs[bi][lb0]); gll(gb1 + (ko), &Bs[bi][lb1]); } while (0)

  const int NT = K >> 5;
  STAGE(0, 0);
  STAGE(32, 1);

  int cur = 0;
  int bpre = 2;
  int kpre = 64;
  for (int t = 0; t < NT; ++t) {
    if (t + 1 < NT) asm volatile("s_waitcnt vmcnt(4)" ::: "memory");
    else            asm volatile("s_waitcnt vmcnt(0)" ::: "memory");
    __builtin_amdgcn_s_barrier();
    __builtin_amdgcn_sched_barrier(0);
    if (t + 2 < NT) STAGE(kpre, bpre);
    s8v af[4], bf4[4];
#pragma unroll
    for (int f = 0; f < 4; f++) {
      af[f]  = *(const s8v*)&As[cur][aoff[f]];
      bf4[f] = *(const s8v*)&Bs[cur][boff[f]];
    }
    __builtin_amdgcn_s_setprio(1);
#pragma unroll
    for (int i = 0; i < 4; i++)
#pragma unroll
      for (int j = 0; j < 4; j++)
        acc[i][j] = __builtin_amdgcn_mfma_f32_16x16x32_bf16(af[i], bf4[j], acc[i][j], 0, 0, 0);
    __builtin_amdgcn_s_setprio(0);
    kpre += 32;
    bpre = (bpre == 2) ? 0 : bpre + 1;
    cur  = (cur == 2) ? 0 : cur + 1;
  }
#undef STAGE

  // C/D layout: col=lane&15, row=(lane>>4)*4+reg
  const int colb = n0 + (w & 1) * 64;
  const int rowb = m0 + (w >> 1) * 64 + (l >> 4) * 4;
#pragma unroll
  for (int i = 0; i < 4; i++) {
#pragma unroll
    for (int j = 0; j < 4; j++) {
      const int col = colb + j * 16 + (l & 15);
      float bv;
      if (EPI == 4) bv = (col < kD) ? bias[col] : 0.0f;
      else          bv = bias[col];
#pragma unroll
      for (int r2 = 0; r2 < 4; r2++) {
        const int row = rowb + i * 16 + r2;
        float v = acc[i][j][r2] + bv;
        if (EPI == 1) {
          Cb[(size_t)row * ldc + swzk(row, col)] = f2b(fmaxf(v, 0.0f));
        } else if (EPI == 2) {
          v += b2f(resb[(size_t)row * kD + swzk(row, col)]);
          Cb[(size_t)row * kD + col] = f2b(v);
        } else if (EPI == 3) {
          const int bb = row / kHW, p = row % kHW;
          Cf[((size_t)bb * Nreal + col) * kHW + p] = v;
        } else if (EPI == 4) {
          if (col < kD) {
            Cb[(size_t)row * kD + col] = f2b(v);
          } else {
            const int c = col - kD;
            if (c < 192)
              Cb2[(size_t)row * 192 + c] = f2b(v + aux[(size_t)(row % kLen) * 192 + c]);
          }
        } else if (EPI == 5) {
          if (row < kLen) {
            const int ll = col >> 8, c = col & 255;
            if (c < 192)
              Cf[(((size_t)ll * kLen) + row) * 192 + c] = v;
          }
        } else {  // EPI == 6
          Cb[(size_t)row * kD + col] = f2b(v);
        }
      }
    }
  }
}

// -------------------------- weight conversions -----------------------------
__device__ __forceinline__ void cvt8t(const float* __restrict__ W,
                                      unsigned short* __restrict__ out,
                                      int K, int N, int g)
{
  const int n = g % N;
  const int k = (g / N) * 8;
  s8v p;
#pragma unroll
  for (int j = 0; j < 8; j++) p[j] = (short)f2b(W[(size_t)(k + j) * N + n]);
  const int base = n * K + (k & ~31) + ((((k >> 3) + (n >> 1)) & 3) << 3);
  *(s8v*)&out[base] = p;
}

// ALL 6 layers' weights in one dispatch: 6 x 212,992 items, 4992 blocks.
__global__ __launch_bounds__(256)
void cvt_all_k(const float* __restrict__ vp_w, const float* __restrict__ op_w,
               const float* __restrict__ off_w, const float* __restrict__ aw_w,
               const float* __restrict__ f1w_a, const float* __restrict__ f2w_a,
               unsigned short* __restrict__ wall)
{
  const int lyr = blockIdx.x / 832;
  int g = (blockIdx.x % 832) * 256 + threadIdx.x;
  unsigned short* wl = wall + (size_t)lyr * 1703936;
  if (g < 32768) { cvt8t(vp_w + (size_t)lyr * kD * kD, wl, 512, 512, g); return; }
  g -= 32768;
  if (g < 16384) {                       // [ow|aww] -> wcomb rows 512..767
    const int n = g & 255;
    const int k = (g >> 8) * 8;
    const float* ow  = off_w + (size_t)lyr * kD * 128;
    const float* aww = aw_w  + (size_t)lyr * kD * 64;
    s8v p;
#pragma unroll
    for (int j = 0; j < 8; j++) {
      float v = 0.0f;
      if (n < 128)      v = ow[(size_t)(k + j) * 128 + n];
      else if (n < 192) v = aww[(size_t)(k + j) * 64 + (n - 128)];
      p[j] = (short)f2b(v);
    }
    const int row = 512 + n;
    const int base = row * 512 + (k & ~31) + ((((k >> 3) + (row >> 1)) & 3) << 3);
    *(s8v*)&wl[base] = p;
    return;
  }
  g -= 16384;
  if (g < 32768) { cvt8t(op_w + (size_t)lyr * kD * kD, wl + 393216, 512, 512, g); return; }
  g -= 32768;
  if (g < 65536) { cvt8t(f1w_a + (size_t)lyr * kD * kDff, wl + 655360, 512, 1024, g); return; }
  g -= 65536;
  cvt8t(f2w_a + (size_t)lyr * kDff * kD, wl + 1179648, 1024, 512, g);
}

// pre: positional features bf16 swz [896][512] + all-layer [ow|aww] + biases
__global__ __launch_bounds__(256)
void pre_k(const float* __restrict__ level_embed,
           const float* __restrict__ off_w, const float* __restrict__ aw_w,
           const float* __restrict__ off_b, const float* __restrict__ aw_b,
           unsigned short* __restrict__ posfb,
           unsigned short* __restrict__ woaw_all, float* __restrict__ biasall)
{
  int g = blockIdx.x * 256 + threadIdx.x;
  if (g < 57344) {                            // posfb: 896*64
    const int d0 = (g & 63) * 8;
    const int t  = g >> 6;
    s8v o;
    if (t >= kLen) {
#pragma unroll
      for (int j = 0; j < 8; j++) o[j] = 0;
    } else {
      const int lvl = t / kHW;
      const int tt = t % kHW;
      const int yy = tt / kWpx, xx = tt % kWpx;
#pragma unroll
      for (int j = 0; j < 8; j++) {
        const int d = d0 + j;
        const int dd = d & 255;
        const float e = (d < 256) ? ((float)(yy + 1) * (6.283185307179586f / kHpx))
                                  : ((float)(xx + 1) * (6.283185307179586f / kWpx));
        const float dimt = powf(10000.0f, (float)(dd >> 1) / 128.0f);
        const float pp = e / dimt;
        const float val = (dd & 1) ? cosf(pp) : sinf(pp);
        o[j] = (short)f2b(val + level_embed[lvl * kD + d]);
      }
    }
    *(s8v*)&posfb[(size_t)t * kD + swzk(t, d0)] = o;
    return;
  }
  g -= 57344;
  if (g < 98304) {                            // woaw_all
    const int l = g >> 14;
    const int gg = g & 16383;
    const int n = gg & 255;
    const int k = (gg >> 8) * 8;
    const float* ow = off_w + (size_t)l * kD * 128;
    const float* aww = aw_w + (size_t)l * kD * 64;
    s8v p;
#pragma unroll
    for (int j = 0; j < 8; j++) {
      float v = 0.0f;
      if (n < 128)      v = ow[(size_t)(k + j) * 128 + n];
      else if (n < 192) v = aww[(size_t)(k + j) * 64 + (n - 128)];
      p[j] = (short)f2b(v);
    }
    const int row = l * 256 + n;
    const int base = row * 512 + (k & ~31) + ((((k >> 3) + (row >> 1)) & 3) << 3);
    *(s8v*)&woaw_all[base] = p;
    return;
  }
  g -= 98304;                                 // biasall < 1536
  if (g < 1536) {
    const int l = g >> 8, c = g & 255;
    float v = 0.0f;
    if (c < 128)      v = off_b[l * 128 + c];
    else if (c < 192) v = aw_b[l * 64 + (c - 128)];
    biasall[l * 256 + c] = v;
  }
}

// W already [N][K] f32 -> bf16 swz (single conv weight, as_w)
__global__ void cvtw_d_k(const float* __restrict__ W, unsigned short* __restrict__ out,
                         int K, int N)
{
  const int gid = blockIdx.x * 256 + threadIdx.x;   // N*(K/8)
  const int K8 = K >> 3;
  const int n  = gid / K8;
  const int k  = (gid % K8) * 8;
  s8v p;
#pragma unroll
  for (int j = 0; j < 8; j++) p[j] = (short)f2b(W[(size_t)n * K + k + j]);
  const int base = n * K + (k & ~31) + ((((k >> 3) + (n >> 1)) & 3) << 3);
  *(s8v*)&out[base] = p;
}

// input transpose (both mods) + both conv weight converts, one dispatch
__global__ void tincvt_k(const float* __restrict__ inv, const float* __restrict__ ini,
                         const float* __restrict__ W0, const float* __restrict__ W1,
                         unsigned short* __restrict__ out, unsigned short* __restrict__ wcs)
{
  __shared__ float t[16][17];
  const int bid = blockIdx.x;
  if (bid < 38400) {                      // transpose: 48 x 25 x 32
    const int z = bid / 1200;             // mod*16+b
    const int rem = bid % 1200;
    const int c0 = (rem % 48) * 16, p0 = (rem / 48) * 16;
    const int mod = z >> 4, b = z & 15;
    const float* in = (mod ? ini : inv) + (size_t)b * kCin * kHW;
    const int tx = threadIdx.x & 15, ty = threadIdx.x >> 4;
    t[ty][tx] = in[((size_t)(c0 + ty)) * kHW + p0 + tx];
    __syncthreads();
    const int row = z * kHW + p0 + ty;
    const int c = c0 + tx;
    out[(size_t)row * kCin + swzk(row, c)] = f2b(t[tx][ty]);
    return;
  }
  int gid = (bid - 38400) * 256 + threadIdx.x;   // < 2*512*96
  const float* W = W0;
  unsigned short* o = wcs;
  if (gid >= 49152) { gid -= 49152; W = W1; o = wcs + 393216; }
  const int n = gid / 96;
  const int k = (gid % 96) * 8;
  s8v p;
#pragma unroll
  for (int j = 0; j < 8; j++) p[j] = (short)f2b(W[(size_t)n * kCin + k + j]);
  const int base = n * kCin + (k & ~31) + ((((k >> 3) + (n >> 1)) & 3) << 3);
  *(s8v*)&o[base] = p;
}

// ------------------ GroupNorm (token-major, bf16 input) ---------------------
__global__ __launch_bounds__(256)
void gn_stats_tok_k(const unsigned short* __restrict__ x, float* __restrict__ stats)
{
  __shared__ float sh[8];
  const int mb = blockIdx.x >> 5;   // mod*16+b
  const int g = blockIdx.x & 31;
  const unsigned short* xb = x + (size_t)mb * kHW * kD + g * 16;
  float s = 0.f, s2 = 0.f;
  for (int i = threadIdx.x; i < 800; i += 256) {
    const int p = i >> 1, half = i & 1;
    const s8v u = *(const s8v*)&xb[(size_t)p * kD + half * 8];
#pragma unroll
    for (int j = 0; j < 8; j++) {
      const float v = b2f((unsigned short)u[j]);
      s += v; s2 += v * v;
    }
  }
  breduce2(s, s2, sh);
  if (threadIdx.x == 0) {
    const float mean = s / (kHW * 16.0f);
    const float var  = s2 / (kHW * 16.0f) - mean * mean;
    stats[blockIdx.x * 2]     = mean;
    stats[blockIdx.x * 2 + 1] = rsqrtf(var + kEps);
  }
}

__global__ void gn_norm_tok_k(const unsigned short* __restrict__ x,
                              unsigned short* __restrict__ srcb,
                              const float* __restrict__ stats,
                              const float* __restrict__ gv, const float* __restrict__ bev,
                              const float* __restrict__ gi, const float* __restrict__ bei)
{
  const int gid = blockIdx.x * 256 + threadIdx.x;   // < 12800*64
  const int d0 = (gid & 63) * 8;
  const int rl = gid >> 6;                          // (mod*16+b)*400+p
  const int mb = rl / kHW;
  const int p  = rl - mb * kHW;
  const int mod = mb >> 4, b = mb & 15;
  const int g = d0 >> 4;
  const float mean = stats[(mb * 32 + g) * 2];
  const float rstd = stats[(mb * 32 + g) * 2 + 1];
  const float* gam = mod ? gi : gv;
  const float* bet = mod ? bei : bev;
  const s8v u = *(const s8v*)&x[(size_t)rl * kD + d0];
  const int row = b * kLen + mod * kHW + p;
  s8v o;
#pragma unroll
  for (int j = 0; j < 8; j++)
    o[j] = (short)f2b((b2f((unsigned short)u[j]) - mean) * rstd * gam[d0 + j] + bet[d0 + j]);
  *(s8v*)&srcb[(size_t)row * kD + swzk(row, d0)] = o;
}

// --------------------------- GroupNorm (chan-major) -------------------------
__global__ __launch_bounds__(256)
void gn_stats_ch_k(const float* __restrict__ x, float* __restrict__ stats)
{
  __shared__ float sh[8];
  const int b = blockIdx.x >> 5;
  const int g = blockIdx.x & 31;
  const float* xb = x + (size_t)b * kCin * kHW + (size_t)g * 24 * kHW;
  float s = 0.f, s2 = 0.f;
  for (int i = threadIdx.x; i < 24 * kHW; i += 256) {
    const float v = xb[i];
    s += v; s2 += v * v;
  }
  breduce2(s, s2, sh);
  if (threadIdx.x == 0) {
    const float mean = s / (24.0f * kHW);
    const float var  = s2 / (24.0f * kHW) - mean * mean;
    stats[blockIdx.x * 2]     = mean;
    stats[blockIdx.x * 2 + 1] = rsqrtf(var + kEps);
  }
}

__global__ void gn_norm_ch_k(const float* __restrict__ x, float* __restrict__ out,
                             const float* __restrict__ stats,
                             const float* __restrict__ gam, const float* __restrict__ bet)
{
  const int idx = blockIdx.x * 256 + threadIdx.x;   // < 16*768*400
  const int rest = idx / kHW;
  const int c = rest % kCin;
  const int b = rest / kCin;
  const int g = c / 24;
  const float mean = stats[(b * 32 + g) * 2];
  const float rstd = stats[(b * 32 + g) * 2 + 1];
  out[idx] = (x[idx] - mean) * rstd * gam[c] + bet[c];
}

// ------------- modality-specific LayerNorm (wave/row, bf16 in) --------------
__global__ __launch_bounds__(256)
void ln4_k(const unsigned short* __restrict__ x, unsigned short* __restrict__ outb,
           const float* __restrict__ gamma, const float* __restrict__ beta)
{
  const int row = blockIdx.x * 4 + (threadIdx.x >> 6);
  const int l = threadIdx.x & 63;
  const int mod = ((row % kLen) < kHW) ? 0 : 1;
  const s8v u = *(const s8v*)&x[(size_t)row * kD + l * 8];
  float v[8];
#pragma unroll
  for (int j = 0; j < 8; j++) v[j] = b2f((unsigned short)u[j]);
  float s = 0.f, s2 = 0.f;
#pragma unroll
  for (int j = 0; j < 8; j++) { s += v[j]; s2 += v[j] * v[j]; }
#pragma unroll
  for (int o = 32; o > 0; o >>= 1) {
    s  += __shfl_xor(s, o);
    s2 += __shfl_xor(s2, o);
  }
  const float mean = s * (1.0f / kD);
  const float var  = s2 * (1.0f / kD) - mean * mean;
  const float rstd = rsqrtf(var + kEps);
  const float* g  = gamma + mod * kD + l * 8;
  const float* be = beta  + mod * kD + l * 8;
  s8v o8;
#pragma unroll
  for (int j = 0; j < 8; j++)
    o8[j] = (short)f2b((v[j] - mean) * rstd * g[j] + be[j]);
  *(s8v*)&outb[(size_t)row * kD + swzk(row, l * 8)] = o8;
}

// ------------------- deformable sampling (bf16 value/offaw) -----------------
__global__ __launch_bounds__(256)
void sample_k(const unsigned short* __restrict__ value,
              const unsigned short* __restrict__ offaw,
              unsigned short* __restrict__ out)
{
  __shared__ float wls[2][64][8];   // [tok][combo][w0,i0,...,w3,i3]
  const int tid = threadIdx.x;
  const int tok = tid >> 7;
  const int wt  = tid & 127;
  const int token = blockIdx.x * 2 + tok;       // < 12800
  const int b = token / kLen;
  const int t = token % kLen;
  const int tt = t % kHW;

  if (wt < 64) {
    const int h = wt >> 3, lp = wt & 7, lvl = lp >> 2, p = lp & 3;
    const unsigned short* oa = offaw + (size_t)token * 192;
    const float lg = b2f(oa[128 + h * 8 + lp]);
    float mx = lg;
#pragma unroll
    for (int msk = 1; msk < 8; msk <<= 1) mx = fmaxf(mx, __shfl_xor(mx, msk));
    const float ex = __expf(lg - mx);
    float ssum = ex;
#pragma unroll
    for (int msk = 1; msk < 8; msk <<= 1) ssum += __shfl_xor(ssum, msk);
    const float aw = ex / ssum;

    const float x = (float)(tt % kWpx) + b2f(oa[h * 16 + lvl * 8 + p * 2]);
    const float y = (float)(tt / kWpx) + b2f(oa[h * 16 + lvl * 8 + p * 2 + 1]);
    const float x0f = floorf(x), y0f = floorf(y);
    const float wx = x - x0f, wy = y - y0f;
    const int x0 = (int)x0f, y0 = (int)y0f;
    const int rowbase = b * kLen + lvl * kHW;
#pragma unroll
    for (int dy = 0; dy < 2; dy++) {
#pragma unroll
      for (int dx = 0; dx < 2; dx++) {
        const int ix = x0 + dx, iy = y0 + dy;
        const bool valid = (ix >= 0) & (ix < kWpx) & (iy >= 0) & (iy < kHpx);
        const float cw = (dx ? wx : 1.0f - wx) * (dy ? wy : 1.0f - wy);
        const float w = valid ? aw * cw : 0.0f;
        const int ixc = min(max(ix, 0), kWpx - 1);
        const int iyc = min(max(iy, 0), kHpx - 1);
        const int r = rowbase + iyc * kWpx + ixc;
        const int cn = dy * 2 + dx;
        wls[tok][wt][cn * 2]     = w;
        wls[tok][wt][cn * 2 + 1] = __int_as_float(r);
      }
    }
  }
  __syncthreads();

  const int c0 = wt * 4;
  const int h = wt >> 4;
  float acc0 = 0.f, acc1 = 0.f, acc2 = 0.f, acc3 = 0.f;
  const unsigned short* vb = value + c0;
#pragma unroll
  for (int pp = 0; pp < 8; pp++) {
    const float* wl = wls[tok][h * 8 + pp];
#pragma unroll
    for (int cn = 0; cn < 4; cn++) {
      const float w = wl[cn * 2];
      const int r = __float_as_int(wl[cn * 2 + 1]);
      const s4v q = *(const s4v*)(vb + (size_t)r * kD);
      acc0 += w * b2f((unsigned short)q[0]);
      acc1 += w * b2f((unsigned short)q[1]);
      acc2 += w * b2f((unsigned short)q[2]);
      acc3 += w * b2f((unsigned short)q[3]);
    }
  }
  const int sk = swzk(token, c0);
  s4v o;
  o[0] = (short)f2b(acc0); o[1] = (short)f2b(acc1);
  o[2] = (short)f2b(acc2); o[3] = (short)f2b(acc3);
  *(s4v*)&out[(size_t)token * kD + sk] = o;
}

// ---------------- token-sum (bf16 srcb halves -> bf16 swz tokb) -------------
__global__ void sumtok_k(const unsigned short* __restrict__ srcb,
                         unsigned short* __restrict__ tokb)
{
  const int gid = blockIdx.x * 256 + threadIdx.x;   // < 16*400*64
  const int d0 = (gid & 63) * 8;
  const int rest = gid >> 6;
  const int b = rest / kHW, p = rest % kHW;
  const int r1 = b * kLen + p;
  const int r2 = r1 + kHW;
  const int ro = b * kHW + p;
  const s8v u1 = *(const s8v*)&srcb[(size_t)r1 * kD + swzk(r1, d0)];
  const s8v u2 = *(const s8v*)&srcb[(size_t)r2 * kD + swzk(r2, d0)];
  s8v o;
#pragma unroll
  for (int j = 0; j < 8; j++)
    o[j] = (short)f2b(b2f((unsigned short)u1[j]) + b2f((unsigned short)u2[j]));
  *(s8v*)&tokb[(size_t)ro * kD + swzk(ro, d0)] = o;
}

// ------------------------------- launcher -----------------------------------
extern "C" void kernel_launch(void* const* d_in, const int* in_sizes, int n_in,
                              void* d_out, int out_size, void* d_ws, size_t ws_size,
                              hipStream_t stream)
{
  const float* input_v     = (const float*)d_in[0];
  const float* input_i     = (const float*)d_in[1];
  const float* av_w        = (const float*)d_in[2];
  const float* av_b        = (const float*)d_in[3];
  const float* av_g        = (const float*)d_in[4];
  const float* av_be       = (const float*)d_in[5];
  const float* ai_w        = (const float*)d_in[6];
  const float* ai_b        = (const float*)d_in[7];
  const float* ai_g        = (const float*)d_in[8];
  const float* ai_be       = (const float*)d_in[9];
  const float* level_embed = (const float*)d_in[10];
  const float* off_w       = (const float*)d_in[11];
  const float* off_b       = (const float*)d_in[12];
  const float* aw_w        = (const float*)d_in[13];
  const float* aw_b        = (const float*)d_in[14];
  const float* vp_w        = (const float*)d_in[15];
  const float* vp_b        = (const float*)d_in[16];
  const float* op_w        = (const float*)d_in[17];
  const float* op_b        = (const float*)d_in[18];
  const float* ln1_g       = (const float*)d_in[19];
  const float* ln1_b       = (const float*)d_in[20];
  const float* ffn1_w      = (const float*)d_in[21];
  const float* ffn1_b      = (const float*)d_in[22];
  const float* ffn2_w      = (const float*)d_in[23];
  const float* ffn2_b      = (const float*)d_in[24];
  const float* ln2_g       = (const float*)d_in[25];
  const float* ln2_b       = (const float*)d_in[26];
  const float* as_w        = (const float*)d_in[27];
  const float* as_b        = (const float*)d_in[28];
  const float* as_g        = (const float*)d_in[29];
  const float* as_be       = (const float*)d_in[30];

  // ------- workspace layout -------
  unsigned short* offawb = (unsigned short*)d_ws;               // 2,457,600 sh
  float* posWc   = (float*)(offawb + 2457600);                  //   921,600 f
  float* biasall = posWc   + (size_t)921600;                    //     1,536 f
  float* stats   = biasall + (size_t)1536;                      //     2,048 f
  unsigned short* srcb     = (unsigned short*)(stats + 2048);   //  6,553,600 sh
  unsigned short* bufA     = srcb     + (size_t)6553600;        // 13,107,200 sh
  unsigned short* bufB     = bufA     + (size_t)13107200;       //  6,553,600 sh
  unsigned short* wall     = bufB     + (size_t)6553600;        // 10,223,616 sh
  unsigned short* wcs      = wall     + (size_t)10223616;       //    786,432 sh
  unsigned short* woaw_all = wcs      + (size_t)786432;         //    786,432 sh
  unsigned short* posfb    = woaw_all + (size_t)786432;         //    458,752 sh
  float* wallf = (float*)wall;   // f32 conv scratch (aliases weight arena)

  const int M = kB * kLen;   // 12800

  // ---- pre: posfb + woaw + biases (1 dispatch), then posWc GEMM ----
  pre_k<<<dim3(614), 256, 0, stream>>>(level_embed, off_w, aw_w, off_b, aw_b,
                                       posfb, woaw_all, biasall);
  mgemm<5><<<dim3(12, 7), 256, 0, stream>>>(
      posfb, woaw_all, biasall, nullptr, posWc, nullptr, nullptr, nullptr,
      512, 0, 0);

  // ---- input convs (both modalities, one GEMM) + GN -> srcb ----
  tincvt_k<<<dim3(38784), 256, 0, stream>>>(input_v, input_i, av_w, ai_w,
                                            bufA, wcs);
  mgemm<6><<<dim3(4, 100), 256, 0, stream>>>(
      bufA, wcs, av_b, wcs + 393216, nullptr, nullptr, ai_b, bufB, 768, 512, 0);
  gn_stats_tok_k<<<dim3(1024), 256, 0, stream>>>(bufB, stats);
  gn_norm_tok_k<<<dim3(3200), 256, 0, stream>>>(
      bufB, srcb, stats, av_g, av_be, ai_g, ai_be);

  // ---- all layer weights -> wall (one dispatch) ----
  cvt_all_k<<<dim3(4992), 256, 0, stream>>>(vp_w, op_w, off_w, aw_w,
                                            ffn1_w, ffn2_w, wall);

  for (int l = 0; l < kNL; l++) {
    unsigned short* wcomb = wall + (size_t)l * 1703936;
    unsigned short* wop   = wcomb + 393216;
    unsigned short* wf1   = wcomb + 655360;
    unsigned short* wf2   = wcomb + 1179648;
    const float* vbl  = vp_b   + (size_t)l * kD;
    const float* opbl = op_b   + (size_t)l * kD;
    const float* l1g  = ln1_g  + (size_t)l * 2 * kD;
    const float* l1b  = ln1_b  + (size_t)l * 2 * kD;
    const float* f1b  = ffn1_b + (size_t)l * kDff;
    const float* f2b_ = ffn2_b + (size_t)l * kD;
    const float* l2g  = ln2_g  + (size_t)l * 2 * kD;
    const float* l2b  = ln2_b  + (size_t)l * 2 * kD;

    // fused: value bf16 (bufA) | offaw bf16 (+posWc)
    mgemm<4><<<dim3(6, 100), 256, 0, stream>>>(
        srcb, wcomb, vbl, nullptr, nullptr, offawb, posWc + (size_t)l * 153600,
        bufA, 512, 0, 0);

    // sampling -> bufB (bf16 swz)
    sample_k<<<dim3(M / 2), 256, 0, stream>>>(bufA, offawb, bufB);

    // y = srcb + sampled @ op + opb -> bufA (bf16 plain)
    mgemm<2><<<dim3(4, 100), 256, 0, stream>>>(
        bufB, wop, opbl, srcb, nullptr, nullptr, nullptr, bufA, 512, 512, 0);

    // srcb = LN_spec(y)
    ln4_k<<<dim3(M / 4), 256, 0, stream>>>(bufA, srcb, l1g, l1b);

    // FFN full-M: hidden -> bufA (swz, relu); y -> bufB (plain)
    mgemm<1><<<dim3(8, 100), 256, 0, stream>>>(
        srcb, wf1, f1b, nullptr, nullptr, nullptr, nullptr, bufA, 512, 1024, 0);
    mgemm<2><<<dim3(4, 100), 256, 0, stream>>>(
        bufA, wf2, f2b_, srcb, nullptr, nullptr, nullptr, bufB, 1024, 512, 0);

    // srcb = LN_spec(y)
    ln4_k<<<dim3(M / 4), 256, 0, stream>>>(bufB, srcb, l2g, l2b);
  }

  // ---- out = GN(conv1x1(src_v + src_i)); f32 scratch in wallf ----
  sumtok_k<<<dim3(1600), 256, 0, stream>>>(srcb, bufA);
  cvtw_d_k<<<dim3(192), 256, 0, stream>>>(as_w, wcs, 512, 768);
  mgemm<3><<<dim3(6, 50), 256, 0, stream>>>(
      bufA, wcs, as_b, nullptr, wallf, nullptr, nullptr, nullptr, 512, 0, 768);
  gn_stats_ch_k<<<dim3(kB * 32), 256, 0, stream>>>(wallf, stats);
  gn_norm_ch_k<<<dim3(19200), 256, 0, stream>>>(
      wallf, (float*)d_out, stats, as_g, as_be);
}